// Round 6
// baseline (1010.558 us; speedup 1.0000x reference)
//
#include <hip/hip_runtime.h>
#include <hip/hip_bf16.h>
#include <math.h>

#define DEV __device__ __forceinline__

constexpr int B  = 8,  N = 16, P = 128, PL = 16;
constexpr int D  = 128, DS = 16, DTR = 8, DFF = 256, EL = 2;
constexpr int L  = N * P + 1;            // 2049
constexpr int BL = B * L;                // 16392
constexpr int CT = 32;                   // scan chunk length
constexpr int NC = (L + CT - 1) / CT;    // 65
constexpr int MT128 = (BL + 127) / 128;  // 129
constexpr int MT64  = (BL + 63) / 64;    // 257
constexpr int KS = 136;                  // LDS row stride (bf16/short units)
constexpr int HS = 264;                  // LDS row stride for H (256+8)

using bf16x8 = __attribute__((ext_vector_type(8))) __bf16;
using f32x4  = __attribute__((ext_vector_type(4))) float;

DEV float sigmoidf_(float x) { return 1.0f / (1.0f + __expf(-x)); }

DEV float wsum(float v) {
#pragma unroll
  for (int m = 32; m; m >>= 1) v += __shfl_xor(v, m, 64);
  return v;
}

// r^(n+1) for n=0..15, depth-4 tree
DEV void pow_tree(float r, float* pw) {
  float r2 = r * r;
  float r3 = r2 * r;
  float r4 = r2 * r2;
  float r8 = r4 * r4;
  float r12 = r8 * r4;
  pw[0] = r;       pw[1] = r2;      pw[2] = r3;      pw[3] = r4;
  pw[4] = r4 * r;  pw[5] = r4 * r2; pw[6] = r4 * r3; pw[7] = r8;
  pw[8] = r8 * r;  pw[9] = r8 * r2; pw[10] = r8 * r3; pw[11] = r12;
  pw[12] = r12 * r; pw[13] = r12 * r2; pw[14] = r12 * r3; pw[15] = r12 * r4;
}

// A_n check: A_init = log(1..16) broadcast -> A_n = -(n+1) exactly.
DEV bool an_is_linear(const float* An) {
  bool ok = true;
#pragma unroll
  for (int n = 0; n < DS; ++n)
    ok = ok && (fabsf(An[n] + (float)(n + 1)) < 1e-3f * (n + 1));
  return ok;
}

DEV float aload(const float* p) {
  return __hip_atomic_load(p, __ATOMIC_RELAXED, __HIP_MEMORY_SCOPE_AGENT);
}

// ---------------- weight prep ----------------
__global__ __launch_bounds__(256) void k_prep(
    const float* __restrict__ in_w, const float* __restrict__ conv_w,
    const float* __restrict__ xproj, const float* __restrict__ out_w,
    const float* __restrict__ w1, const float* __restrict__ w2,
    __bf16* __restrict__ weff, __bf16* __restrict__ xpw_bf,
    __bf16* __restrict__ outw_bf, __bf16* __restrict__ w1_bf,
    __bf16* __restrict__ w2_bf)
{
  int g = blockIdx.x * 256 + threadIdx.x;
  if (g < 262144) {
    int l = g >> 17;
    int r = g & 131071;
    int dir = r >> 16;
    int r2 = r & 65535;
    int col = r2 >> 8;
    int kk = r2 & 255;
    int chunk = kk >> 7, k = kk & 127;
    int ld = l * 2 + dir;
    float v;
    if (col < 128) {
      v = in_w[((size_t)ld * 256 + col) * 128 + k] *
          conv_w[((size_t)ld * 128 + col) * 2 + chunk];
    } else {
      v = chunk ? in_w[((size_t)ld * 256 + col) * 128 + k] : 0.f;
    }
    weff[((size_t)ld * 256 + col) * 256 + chunk * 128 + k] = (__bf16)v;
    return;
  }
  g -= 262144;
  if (g < 20480) { xpw_bf[g] = (__bf16)xproj[g]; return; }
  g -= 20480;
  if (g < 65536) {
    int k = g & 127; int q = g >> 7; int n = q & 127; int q2 = q >> 7;
    int dir = q2 & 1; int l = q2 >> 1;
    outw_bf[((size_t)(l * 128 + n)) * 256 + dir * 128 + k] = (__bf16)out_w[g];
    return;
  }
  g -= 65536;
  if (g < 65536) { w1_bf[g] = (__bf16)w1[g]; return; }
  g -= 65536;
  if (g < 65536) { w2_bf[g] = (__bf16)w2[g]; return; }
}

// ---------------- patch embed + view concat -> U (fp32) + Ubf; zero counters ----------------
__global__ __launch_bounds__(256) void k_embed(
    const float* __restrict__ x, const float* __restrict__ view,
    const float* __restrict__ wp_w, const float* __restrict__ wp_b,
    float* __restrict__ U, __bf16* __restrict__ Ubf, int* __restrict__ cnt)
{
  if (blockIdx.x == 0 && threadIdx.x < 64) cnt[threadIdx.x] = 0;
  int g = blockIdx.x * 256 + threadIdx.x;
  if (g >= BL * D) return;
  int d = g & (D - 1);
  int row = g >> 7;
  int b = row / L, t = row % L;
  float acc;
  if (t < N * P) {
    const float* xr = x + ((size_t)b * N * P + t) * PL;
    acc = wp_b[d];
#pragma unroll
    for (int k = 0; k < PL; ++k) acc += xr[k] * wp_w[d * PL + k];
  } else {
    acc = view[b * D + d];
  }
  U[(size_t)row * D + d] = acc;
  Ubf[(size_t)row * D + d] = (__bf16)acc;
}

// ---------------- fused xz GEMM + conv + silu (bf16 outputs) ----------------
__global__ __launch_bounds__(256) void k_xzc(
    const __bf16* __restrict__ Ubf, const __bf16* __restrict__ Weff,
    const float* __restrict__ conv_b_l,
    __bf16* __restrict__ XCCbf, __bf16* __restrict__ Zbf)
{
  __shared__ short As[128 * KS];
  __shared__ short Bs[64 * KS];
  int bx = blockIdx.x;
  int rdir = bx / MT128;
  int tile = bx % MT128;
  int col0 = blockIdx.y * 64;
  bool isx = col0 < 128;
  int tid = threadIdx.x;
  int m0 = tile * 128;
  const __bf16* Wb = Weff + (size_t)rdir * 256 * 256;
  int wave = tid >> 6, lane = tid & 63, lm = lane & 15, lq = lane >> 4;
  f32x4 zero4 = {0.f, 0.f, 0.f, 0.f};
  f32x4 acc[2][4];
#pragma unroll
  for (int r = 0; r < 2; ++r)
#pragma unroll
    for (int c = 0; c < 4; ++c) acc[r][c] = zero4;
  int kc0 = isx ? 0 : 1;
  for (int kc = kc0; kc < 2; ++kc) {
    if (kc != kc0) __syncthreads();
    for (int q = tid; q < 128 * 16; q += 256) {
      int rr = q >> 4, g = q & 15;
      int m = m0 + rr;
      int4 v = make_int4(0, 0, 0, 0);
      if (m < BL) {
        int b = m / L, s = m - b * L;
        bool ok = true;
        int idx;
        if (kc == 0) { ok = (s >= 1); idx = rdir ? (L - s) : (s - 1); }
        else         { idx = rdir ? (L - 1 - s) : s; }
        if (ok) v = *(const int4*)(Ubf + ((size_t)b * L + idx) * 128 + g * 8);
      }
      *(int4*)&As[rr * KS + g * 8] = v;
    }
    for (int q = tid; q < 64 * 16; q += 256) {
      int rr = q >> 4, g = q & 15;
      int4 v = *(const int4*)(Wb + (size_t)(col0 + rr) * 256 + kc * 128 + g * 8);
      *(int4*)&Bs[rr * KS + g * 8] = v;
    }
    __syncthreads();
    for (int ks = 0; ks < 128; ks += 32) {
      bf16x8 af[2];
#pragma unroll
      for (int r = 0; r < 2; ++r)
        af[r] = *(const bf16x8*)&As[(wave * 32 + r * 16 + lm) * KS + ks + lq * 8];
#pragma unroll
      for (int c = 0; c < 4; ++c) {
        bf16x8 bfr = *(const bf16x8*)&Bs[(c * 16 + lm) * KS + ks + lq * 8];
#pragma unroll
        for (int r = 0; r < 2; ++r)
          acc[r][c] = __builtin_amdgcn_mfma_f32_16x16x32_bf16(af[r], bfr, acc[r][c], 0, 0, 0);
      }
    }
  }
#pragma unroll
  for (int r = 0; r < 2; ++r) {
    int rowb = m0 + wave * 32 + r * 16 + lq * 4;
#pragma unroll
    for (int c = 0; c < 4; ++c) {
      int col = col0 + c * 16 + lm;
      float cb = isx ? conv_b_l[rdir * 128 + col] : 0.f;
#pragma unroll
      for (int e = 0; e < 4; ++e) {
        int m = rowb + e;
        if (m >= BL) continue;
        size_t base = ((size_t)rdir * BL + m) * 128;
        float v = acc[r][c][e];
        if (isx) {
          v += cb;
          XCCbf[base + col] = (__bf16)(v * sigmoidf_(v));
        } else {
          Zbf[base + col - 128] = (__bf16)v;
        }
      }
    }
  }
}

// ---------------- fused xproj GEMM + dt ----------------
__global__ __launch_bounds__(256) void k_xproj_dt(
    const __bf16* __restrict__ XCCbf, const __bf16* __restrict__ Wbf,
    const float* __restrict__ dt_w_l, const float* __restrict__ dt_b_l,
    float* __restrict__ BCb, float* __restrict__ DT)
{
  __shared__ short As[128 * KS];
  __shared__ short Bs[64 * KS];
  __shared__ float dbs[128][9];
  int bx = blockIdx.x;
  int rdir = bx / MT128;
  int tile = bx % MT128;
  int tid = threadIdx.x;
  int m0 = tile * 128;
  const __bf16* Wb = Wbf + (size_t)rdir * 40 * 128;
  for (int q = tid; q < 128 * 16; q += 256) {
    int rr = q >> 4, g = q & 15;
    int m = m0 + rr;
    int4 v = make_int4(0, 0, 0, 0);
    if (m < BL) v = *(const int4*)(XCCbf + ((size_t)rdir * BL + m) * 128 + g * 8);
    *(int4*)&As[rr * KS + g * 8] = v;
  }
  for (int q = tid; q < 64 * 16; q += 256) {
    int rr = q >> 4, g = q & 15;
    int4 v = make_int4(0, 0, 0, 0);
    if (rr < 40) v = *(const int4*)(Wb + (size_t)rr * 128 + g * 8);
    *(int4*)&Bs[rr * KS + g * 8] = v;
  }
  __syncthreads();
  int wave = tid >> 6, lane = tid & 63, lm = lane & 15, lq = lane >> 4;
  f32x4 zero4 = {0.f, 0.f, 0.f, 0.f};
  f32x4 acc[2][3];
#pragma unroll
  for (int r = 0; r < 2; ++r)
#pragma unroll
    for (int c = 0; c < 3; ++c) acc[r][c] = zero4;
  for (int ks = 0; ks < 128; ks += 32) {
    bf16x8 af[2];
#pragma unroll
    for (int r = 0; r < 2; ++r)
      af[r] = *(const bf16x8*)&As[(wave * 32 + r * 16 + lm) * KS + ks + lq * 8];
#pragma unroll
    for (int c = 0; c < 3; ++c) {
      bf16x8 bfr = *(const bf16x8*)&Bs[(c * 16 + lm) * KS + ks + lq * 8];
#pragma unroll
      for (int r = 0; r < 2; ++r)
        acc[r][c] = __builtin_amdgcn_mfma_f32_16x16x32_bf16(af[r], bfr, acc[r][c], 0, 0, 0);
    }
  }
#pragma unroll
  for (int r = 0; r < 2; ++r) {
    int rl = wave * 32 + r * 16 + lq * 4;
    int rowb = m0 + rl;
#pragma unroll
    for (int c = 0; c < 3; ++c) {
      int col = c * 16 + lm;
#pragma unroll
      for (int e = 0; e < 4; ++e) {
        int m = rowb + e;
        float v = acc[r][c][e];
        if (col < DTR) dbs[rl + e][col] = v;
        else if (col < DTR + 2 * DS && m < BL)
          BCb[((size_t)rdir * BL + m) * 32 + (col - DTR)] = v;
      }
    }
  }
  __syncthreads();
  {
    int dloc = tid & 127;
    int rpar = tid >> 7;
    const float* dw = dt_w_l + ((size_t)rdir * 128 + dloc) * 8;
    float dwr[8];
#pragma unroll
    for (int j = 0; j < 8; ++j) dwr[j] = dw[j];
    float db = dt_b_l[rdir * 128 + dloc];
    for (int rr = rpar; rr < 128; rr += 2) {
      int m = m0 + rr;
      if (m >= BL) break;
      float a = db;
#pragma unroll
      for (int j = 0; j < 8; ++j) a = fmaf(dbs[rr][j], dwr[j], a);
      float dtv = (a > 20.f) ? a : log1pf(__expf(a));
      DT[((size_t)rdir * BL + m) * 128 + dloc] = dtv;
    }
  }
}

// ---------------- scan phase A + fused boundary chain (last block per rb) ----------------
__global__ __launch_bounds__(128) void k_scanAB(
    const float* __restrict__ DT, const __bf16* __restrict__ XCCbf,
    const float* __restrict__ BCb, const float* __restrict__ Alog_l,
    float* __restrict__ HC, float* __restrict__ DTS,
    float* __restrict__ HIN, int* __restrict__ cnt)
{
  __shared__ float Bs[CT][DS];
  __shared__ int last_sh;
  int blk = blockIdx.x;
  int c  = blk % NC;
  int rb = blk / NC;
  int rdir = rb / B;
  int d = threadIdx.x;
  int s0 = c * CT;
  int cn = min(CT, L - s0);
  size_t rowbase = (size_t)rb * L + s0;
  for (int q = d; q < cn * DS; q += 128)
    Bs[q >> 4][q & 15] = BCb[(rowbase + (q >> 4)) * 32 + (q & 15)];
  float An[DS];
  const float* Ab = Alog_l + (size_t)rdir * D * DS + (size_t)d * DS;
#pragma unroll
  for (int n = 0; n < DS; ++n) An[n] = -__expf(Ab[n]);
  bool fast = an_is_linear(An);
  __syncthreads();
  float h[DS];
#pragma unroll
  for (int n = 0; n < DS; ++n) h[n] = 0.f;
  float dts = 0.f;
  float dt_nx = DT[rowbase * D + d];
  float xc_nx = (float)XCCbf[rowbase * D + d];
  if (fast) {
    for (int ss = 0; ss < cn; ++ss) {
      float dt = dt_nx, xc = xc_nx;
      if (ss + 1 < cn) {
        size_t ro = (rowbase + ss + 1) * D + d;
        dt_nx = DT[ro]; xc_nx = (float)XCCbf[ro];
      }
      dts += dt;
      float e = dt * xc;
      float pw[DS];
      pow_tree(__expf(-dt), pw);
#pragma unroll
      for (int n = 0; n < DS; ++n)
        h[n] = fmaf(pw[n], h[n], e * Bs[ss][n]);
    }
  } else {
    for (int ss = 0; ss < cn; ++ss) {
      float dt = dt_nx, xc = xc_nx;
      if (ss + 1 < cn) {
        size_t ro = (rowbase + ss + 1) * D + d;
        dt_nx = DT[ro]; xc_nx = (float)XCCbf[ro];
      }
      dts += dt;
      float e = dt * xc;
#pragma unroll
      for (int n = 0; n < DS; ++n)
        h[n] = __expf(dt * An[n]) * h[n] + e * Bs[ss][n];
    }
  }
  float* hp = HC + ((size_t)blk * D + d) * DS;
#pragma unroll
  for (int n = 0; n < DS; ++n) hp[n] = h[n];
  DTS[(size_t)blk * D + d] = dts;

  // last-done block of this rb runs the boundary chain (scanB work)
  __threadfence();
  if (d == 0) {
    int old = __hip_atomic_fetch_add(&cnt[rb], 1, __ATOMIC_ACQ_REL, __HIP_MEMORY_SCOPE_AGENT);
    last_sh = (old == NC - 1);
  }
  __syncthreads();
  if (!last_sh) return;

  float h2[DS];
#pragma unroll
  for (int n = 0; n < DS; ++n) h2[n] = 0.f;
  size_t base0 = ((size_t)(rb * NC) * D + d);
  float dts_nx = aload(&DTS[base0]);
  float hcn[DS];
#pragma unroll
  for (int n = 0; n < DS; ++n) hcn[n] = aload(&HC[base0 * DS + n]);
  for (int cc = 0; cc < NC; ++cc) {
    float dtv = dts_nx;
    float hcv[DS];
#pragma unroll
    for (int n = 0; n < DS; ++n) hcv[n] = hcn[n];
    if (cc + 1 < NC) {
      size_t bn = ((size_t)(rb * NC + cc + 1) * D + d);
      dts_nx = aload(&DTS[bn]);
#pragma unroll
      for (int n = 0; n < DS; ++n) hcn[n] = aload(&HC[bn * DS + n]);
    }
    float* hin = HIN + ((size_t)(rb * NC + cc) * D + d) * DS;
#pragma unroll
    for (int n = 0; n < DS; ++n) hin[n] = h2[n];
    if (fast) {
      float pw[DS];
      pow_tree(__expf(-dtv), pw);
#pragma unroll
      for (int n = 0; n < DS; ++n)
        h2[n] = fmaf(pw[n], h2[n], hcv[n]);
    } else {
#pragma unroll
      for (int n = 0; n < DS; ++n)
        h2[n] = __expf(dtv * An[n]) * h2[n] + hcv[n];
    }
  }
}

// ---------------- scan phase C: full scan seeded with h_in, emit y bf16 ----------------
__global__ __launch_bounds__(128) void k_scanC(
    const float* __restrict__ DT, const __bf16* __restrict__ XCCbf,
    const float* __restrict__ BCb, const __bf16* __restrict__ Zbf,
    const float* __restrict__ HIN, const float* __restrict__ Alog_l,
    const float* __restrict__ Dp_l, __bf16* __restrict__ YMbf)
{
  __shared__ float Bsm[CT][DS];
  __shared__ float Csm[CT][DS];
  int blk = blockIdx.x;
  int c  = blk % NC;
  int rb = blk / NC;
  int rdir = rb / B;
  int b = rb % B;
  int d = threadIdx.x;
  int s0 = c * CT;
  int cn = min(CT, L - s0);
  size_t rowbase = (size_t)rb * L + s0;
  for (int q = d; q < cn * 2 * DS; q += 128) {
    int ss = q >> 5, j = q & 31;
    float vv = BCb[(rowbase + ss) * 32 + j];
    if (j < DS) Bsm[ss][j] = vv; else Csm[ss][j - DS] = vv;
  }
  float An[DS];
  const float* Ab = Alog_l + (size_t)rdir * D * DS + (size_t)d * DS;
#pragma unroll
  for (int n = 0; n < DS; ++n) An[n] = -__expf(Ab[n]);
  bool fast = an_is_linear(An);
  float h[DS];
  const float* hin = HIN + ((size_t)blk * D + d) * DS;
#pragma unroll
  for (int n = 0; n < DS; ++n) h[n] = hin[n];
  float Dpv = Dp_l[rdir * D + d];
  __syncthreads();
  float dt_nx = DT[rowbase * D + d];
  float xc_nx = (float)XCCbf[rowbase * D + d];
  float z_nx  = (float)Zbf[rowbase * D + d];
  if (fast) {
    for (int ss = 0; ss < cn; ++ss) {
      float dt = dt_nx, xc = xc_nx, z = z_nx;
      if (ss + 1 < cn) {
        size_t ro = (rowbase + ss + 1) * D + d;
        dt_nx = DT[ro]; xc_nx = (float)XCCbf[ro]; z_nx = (float)Zbf[ro];
      }
      float e = dt * xc;
      float pw[DS];
      pow_tree(__expf(-dt), pw);
      float y = xc * Dpv;
#pragma unroll
      for (int n = 0; n < DS; ++n) {
        h[n] = fmaf(pw[n], h[n], e * Bsm[ss][n]);
        y = fmaf(h[n], Csm[ss][n], y);
      }
      y *= z * sigmoidf_(z);
      int s = s0 + ss;
      int tt = rdir ? (L - 1 - s) : s;
      YMbf[((size_t)b * L + tt) * 256 + rdir * 128 + d] = (__bf16)y;
    }
  } else {
    for (int ss = 0; ss < cn; ++ss) {
      float dt = dt_nx, xc = xc_nx, z = z_nx;
      if (ss + 1 < cn) {
        size_t ro = (rowbase + ss + 1) * D + d;
        dt_nx = DT[ro]; xc_nx = (float)XCCbf[ro]; z_nx = (float)Zbf[ro];
      }
      float e = dt * xc;
      float y = xc * Dpv;
#pragma unroll
      for (int n = 0; n < DS; ++n) {
        h[n] = __expf(dt * An[n]) * h[n] + e * Bsm[ss][n];
        y = fmaf(h[n], Csm[ss][n], y);
      }
      y *= z * sigmoidf_(z);
      int s = s0 + ss;
      int tt = rdir ? (L - 1 - s) : s;
      YMbf[((size_t)b * L + tt) * 256 + rdir * 128 + d] = (__bf16)y;
    }
  }
}

// ---------------- fused tail: outproj + residual + LN1 + FFN1 + FFN2 + LN2 ----------------
// grid MT64 x 256 threads; 64 rows per block. XR and H never leave LDS.
__global__ __launch_bounds__(256) void k_tail(
    const __bf16* __restrict__ YMbf, const __bf16* __restrict__ Wout,
    const float* __restrict__ g1, const float* __restrict__ be1,
    const __bf16* __restrict__ w1bf, const float* __restrict__ b1,
    const __bf16* __restrict__ w2bf, const float* __restrict__ b2,
    const float* __restrict__ g2, const float* __restrict__ be2,
    float* __restrict__ U, __bf16* __restrict__ Ubf)
{
  __shared__ short AX[64 * KS];    // phase1 As (YM) -> XRbf
  __shared__ short BH[128 * KS];   // phase1 Bs (Wout) -> Hbf (64 x HS)
  __shared__ short Ws[64 * KS];    // w1/w2 staging
  int m0 = blockIdx.x * 64;
  int tid = threadIdx.x;
  int wave = tid >> 6, lane = tid & 63, lm = lane & 15, lq = lane >> 4;
  f32x4 zero4 = {0.f, 0.f, 0.f, 0.f};

  // ---- phase 1: outproj (K=256) ----
  f32x4 acc[8];
#pragma unroll
  for (int c = 0; c < 8; ++c) acc[c] = zero4;
  for (int kc = 0; kc < 2; ++kc) {
    if (kc) __syncthreads();
    for (int q = tid; q < 64 * 16; q += 256) {
      int rr = q >> 4, g = q & 15;
      int m = m0 + rr;
      int4 v = make_int4(0, 0, 0, 0);
      if (m < BL) v = *(const int4*)(YMbf + (size_t)m * 256 + kc * 128 + g * 8);
      *(int4*)&AX[rr * KS + g * 8] = v;
    }
    for (int q = tid; q < 128 * 16; q += 256) {
      int rr = q >> 4, g = q & 15;
      int4 v = *(const int4*)(Wout + (size_t)rr * 256 + kc * 128 + g * 8);
      *(int4*)&BH[rr * KS + g * 8] = v;
    }
    __syncthreads();
    for (int ks = 0; ks < 128; ks += 32) {
      bf16x8 af = *(const bf16x8*)&AX[(wave * 16 + lm) * KS + ks + lq * 8];
#pragma unroll
      for (int c = 0; c < 8; ++c) {
        bf16x8 bfr = *(const bf16x8*)&BH[(c * 16 + lm) * KS + ks + lq * 8];
        acc[c] = __builtin_amdgcn_mfma_f32_16x16x32_bf16(af, bfr, acc[c], 0, 0, 0);
      }
    }
  }
  __syncthreads();   // all phase-1 LDS reads done before overwrite

  // ---- phase 2: residual + LN1 -> XRbf in AX (wave-private rows) ----
  {
    float g1c[8], be1c[8];
#pragma unroll
    for (int c = 0; c < 8; ++c) {
      int col = c * 16 + lm;
      g1c[c] = g1[col]; be1c[c] = be1[col];
    }
#pragma unroll
    for (int r = 0; r < 4; ++r) {
      int row = m0 + wave * 16 + lq * 4 + r;
      bool valid = row < BL;
      float os[8];
      float sum = 0.f;
#pragma unroll
      for (int c = 0; c < 8; ++c) {
        int col = c * 16 + lm;
        float uv = valid ? U[(size_t)row * 128 + col] : 0.f;
        os[c] = acc[c][r] + uv;
        sum += os[c];
      }
#pragma unroll
      for (int mm = 1; mm < 16; mm <<= 1) sum += __shfl_xor(sum, mm, 64);
      float mean = sum * (1.f / 128.f);
      float qv = 0.f;
#pragma unroll
      for (int c = 0; c < 8; ++c) { float dv = os[c] - mean; qv += dv * dv; }
#pragma unroll
      for (int mm = 1; mm < 16; mm <<= 1) qv += __shfl_xor(qv, mm, 64);
      float inv = rsqrtf(qv * (1.f / 128.f) + 1e-5f);
      int rl = wave * 16 + lq * 4 + r;
#pragma unroll
      for (int c = 0; c < 8; ++c) {
        int col = c * 16 + lm;
        float o = (os[c] - mean) * inv * g1c[c] + be1c[c];
        AX[rl * KS + col] = (short)__builtin_bit_cast(unsigned short, (__bf16)o);
      }
    }
  }

  // ---- phase 3: FFN1 (K=128), H -> BH (rows wave-private) ----
  for (int cc = 0; cc < 4; ++cc) {
    __syncthreads();
    for (int q = tid; q < 64 * 16; q += 256) {
      int rr = q >> 4, g = q & 15;
      int4 v = *(const int4*)(w1bf + (size_t)(cc * 64 + rr) * 128 + g * 8);
      *(int4*)&Ws[rr * KS + g * 8] = v;
    }
    __syncthreads();
    f32x4 a1[4];
#pragma unroll
    for (int c = 0; c < 4; ++c) a1[c] = zero4;
    for (int ks = 0; ks < 128; ks += 32) {
      bf16x8 af = *(const bf16x8*)&AX[(wave * 16 + lm) * KS + ks + lq * 8];
#pragma unroll
      for (int c = 0; c < 4; ++c) {
        bf16x8 bfr = *(const bf16x8*)&Ws[(c * 16 + lm) * KS + ks + lq * 8];
        a1[c] = __builtin_amdgcn_mfma_f32_16x16x32_bf16(af, bfr, a1[c], 0, 0, 0);
      }
    }
#pragma unroll
    for (int c = 0; c < 4; ++c) {
      int col = cc * 64 + c * 16 + lm;
      float bb = b1[col];
#pragma unroll
      for (int e = 0; e < 4; ++e) {
        int rl = wave * 16 + lq * 4 + e;
        float hv = fmaxf(a1[c][e] + bb, 0.f);
        BH[rl * HS + col] = (short)__builtin_bit_cast(unsigned short, (__bf16)hv);
      }
    }
  }

  // ---- phase 4: FFN2 (K=256) + residual + LN2 -> U, Ubf ----
  f32x4 a2[2][4];
#pragma unroll
  for (int nc = 0; nc < 2; ++nc)
#pragma unroll
    for (int c = 0; c < 4; ++c) a2[nc][c] = zero4;
  for (int nc = 0; nc < 2; ++nc) {
    for (int kc = 0; kc < 2; ++kc) {
      __syncthreads();
      for (int q = tid; q < 64 * 16; q += 256) {
        int rr = q >> 4, g = q & 15;
        int4 v = *(const int4*)(w2bf + (size_t)(nc * 64 + rr) * 256 + kc * 128 + g * 8);
        *(int4*)&Ws[rr * KS + g * 8] = v;
      }
      __syncthreads();
      for (int ks = 0; ks < 128; ks += 32) {
        bf16x8 af = *(const bf16x8*)&BH[(wave * 16 + lm) * HS + kc * 128 + ks + lq * 8];
#pragma unroll
        for (int c = 0; c < 4; ++c) {
          bf16x8 bfr = *(const bf16x8*)&Ws[(c * 16 + lm) * KS + ks + lq * 8];
          a2[nc][c] = __builtin_amdgcn_mfma_f32_16x16x32_bf16(af, bfr, a2[nc][c], 0, 0, 0);
        }
      }
    }
  }
  {
    float b2c[8], g2c[8], be2c[8];
#pragma unroll
    for (int q = 0; q < 8; ++q) {
      int col = (q >> 2) * 64 + (q & 3) * 16 + lm;
      b2c[q] = b2[col]; g2c[q] = g2[col]; be2c[q] = be2[col];
    }
#pragma unroll
    for (int r = 0; r < 4; ++r) {
      int rl = wave * 16 + lq * 4 + r;
      int row = m0 + rl;
      bool valid = row < BL;
      float os[8];
      float sum = 0.f;
#pragma unroll
      for (int q = 0; q < 8; ++q) {
        int nc = q >> 2, c = q & 3;
        int col = nc * 64 + c * 16 + lm;
        __bf16 xb = __builtin_bit_cast(__bf16, (unsigned short)AX[rl * KS + col]);
        os[q] = a2[nc][c][r] + b2c[q] + (float)xb;
        sum += os[q];
      }
#pragma unroll
      for (int mm = 1; mm < 16; mm <<= 1) sum += __shfl_xor(sum, mm, 64);
      float mean = sum * (1.f / 128.f);
      float qv = 0.f;
#pragma unroll
      for (int q = 0; q < 8; ++q) { float dv = os[q] - mean; qv += dv * dv; }
#pragma unroll
      for (int mm = 1; mm < 16; mm <<= 1) qv += __shfl_xor(qv, mm, 64);
      float inv = rsqrtf(qv * (1.f / 128.f) + 1e-5f);
      if (valid) {
#pragma unroll
        for (int q = 0; q < 8; ++q) {
          int nc = q >> 2, c = q & 3;
          int col = nc * 64 + c * 16 + lm;
          float o = (os[q] - mean) * inv * g2c[q] + be2c[q];
          U[(size_t)row * 128 + col] = o;
          Ubf[(size_t)row * 128 + col] = (__bf16)o;
        }
      }
    }
  }
}

// ---------------- final LN + slice + transpose -> out (B,N,D,P) ----------------
__global__ __launch_bounds__(256) void k_lnf_out(
    const float* __restrict__ U, const float* __restrict__ g,
    const float* __restrict__ be, float* __restrict__ out)
{
  int gg = blockIdx.x * 4 + (threadIdx.x >> 6);   // [0, B*2048)
  int lane = threadIdx.x & 63;
  int b = gg >> 11, t = gg & 2047;
  const float* ur = U + ((size_t)b * L + t) * D;
  float x0 = ur[lane], x1 = ur[lane + 64];
  float mean = wsum(x0 + x1) * (1.f / D);
  float d0 = x0 - mean, d1 = x1 - mean;
  float var = wsum(d0 * d0 + d1 * d1) * (1.f / D);
  float inv = rsqrtf(var + 1e-5f);
  float o0 = d0 * inv * g[lane] + be[lane];
  float o1 = d1 * inv * g[lane + 64] + be[lane + 64];
  int n = t >> 7, p = t & 127;
  size_t obase = (((size_t)b * N + n) * D) * P + p;
  out[obase + (size_t)lane * P] = o0;
  out[obase + (size_t)(lane + 64) * P] = o1;
}

extern "C" void kernel_launch(void* const* d_in, const int* in_sizes, int n_in,
                              void* d_out, int out_size, void* d_ws, size_t ws_size,
                              hipStream_t stream)
{
  (void)in_sizes; (void)n_in; (void)out_size; (void)ws_size;
  const float* x       = (const float*)d_in[0];
  const float* view    = (const float*)d_in[1];
  const float* wp_w    = (const float*)d_in[2];
  const float* wp_b    = (const float*)d_in[3];
  const float* m_in_w  = (const float*)d_in[4];
  const float* m_conv_w= (const float*)d_in[5];
  const float* m_conv_b= (const float*)d_in[6];
  const float* m_xproj = (const float*)d_in[7];
  const float* m_dt_w  = (const float*)d_in[8];
  const float* m_dt_b  = (const float*)d_in[9];
  const float* m_Alog  = (const float*)d_in[10];
  const float* m_Dp    = (const float*)d_in[11];
  const float* m_out_w = (const float*)d_in[12];
  const float* ffn_w1  = (const float*)d_in[13];
  const float* ffn_b1  = (const float*)d_in[14];
  const float* ffn_w2  = (const float*)d_in[15];
  const float* ffn_b2  = (const float*)d_in[16];
  const float* ln1_g   = (const float*)d_in[17];
  const float* ln1_b   = (const float*)d_in[18];
  const float* ln2_g   = (const float*)d_in[19];
  const float* ln2_b   = (const float*)d_in[20];
  const float* lnf_g   = (const float*)d_in[21];
  const float* lnf_b   = (const float*)d_in[22];
  float* out = (float*)d_out;

  float* W = (float*)d_ws;
  size_t off = 0;
  auto alloc = [&](size_t nfl) { float* p = W + off; off += (nfl + 3) & ~(size_t)3; return p; };
  float* U      = alloc((size_t)BL * D);
  float* Ubf_f  = alloc((size_t)BL * D / 2);
  float* XCC_f  = alloc((size_t)BL * D);          // 2*BL*D bf16
  float* Zbf_f  = alloc((size_t)BL * D);          // 2*BL*D bf16
  float* DTb    = alloc((size_t)2 * BL * D);
  float* BCb    = alloc((size_t)2 * BL * 2 * DS);
  float* YM_f   = alloc((size_t)BL * 256 / 2);
  float* HC     = alloc((size_t)2 * B * NC * D * DS);
  float* DTS    = alloc((size_t)2 * B * NC * D);
  float* HIN    = alloc((size_t)2 * B * NC * D * DS);
  float* cnt_f  = alloc(64);
  float* weff_f = alloc(262144 / 2);
  float* xpw_f  = alloc(20480 / 2);
  float* outw_f = alloc(65536 / 2);
  float* w1_f   = alloc(65536 / 2);
  float* w2_f   = alloc(65536 / 2);

  __bf16* Ubf    = (__bf16*)Ubf_f;
  __bf16* XCCbf  = (__bf16*)XCC_f;
  __bf16* Zbf    = (__bf16*)Zbf_f;
  __bf16* YMbf   = (__bf16*)YM_f;
  int*    cnt    = (int*)cnt_f;
  __bf16* weff   = (__bf16*)weff_f;
  __bf16* xpw_bf = (__bf16*)xpw_f;
  __bf16* outw_bf= (__bf16*)outw_f;
  __bf16* w1_bf  = (__bf16*)w1_f;
  __bf16* w2_bf  = (__bf16*)w2_f;

  k_prep<<<1872, 256, 0, stream>>>(m_in_w, m_conv_w, m_xproj, m_out_w, ffn_w1, ffn_w2,
                                   weff, xpw_bf, outw_bf, w1_bf, w2_bf);
  k_embed<<<(BL * D + 255) / 256, 256, 0, stream>>>(x, view, wp_w, wp_b, U, Ubf, cnt);

  for (int l = 0; l < EL; ++l) {
    const float* conv_b_l = m_conv_b + (size_t)l * 2 * D;
    const float* dt_w_l   = m_dt_w   + (size_t)l * 2 * D * DTR;
    const float* dt_b_l   = m_dt_b   + (size_t)l * 2 * D;
    const float* Alog_l   = m_Alog   + (size_t)l * 2 * D * DS;
    const float* Dp_l     = m_Dp     + (size_t)l * 2 * D;

    k_xzc      <<<dim3(2 * MT128, 4), 256, 0, stream>>>(Ubf, weff + (size_t)l * 2 * 256 * 256,
                                                        conv_b_l, XCCbf, Zbf);
    k_xproj_dt <<<2 * MT128, 256, 0, stream>>>(XCCbf, xpw_bf + (size_t)l * 2 * 40 * 128,
                                               dt_w_l, dt_b_l, BCb, DTb);
    k_scanAB   <<<2 * B * NC, 128, 0, stream>>>(DTb, XCCbf, BCb, Alog_l, HC, DTS, HIN,
                                                cnt + l * 16);
    k_scanC    <<<2 * B * NC, 128, 0, stream>>>(DTb, XCCbf, BCb, Zbf, HIN, Alog_l, Dp_l, YMbf);
    k_tail     <<<MT64, 256, 0, stream>>>(YMbf, outw_bf + (size_t)l * 128 * 256,
                                          ln1_g + l * D, ln1_b + l * D,
                                          w1_bf + (size_t)l * 256 * 128, ffn_b1 + l * DFF,
                                          w2_bf + (size_t)l * 128 * 256, ffn_b2 + l * D,
                                          ln2_g + l * D, ln2_b + l * D, U, Ubf);
  }
  k_lnf_out<<<(B * N * P) / 4, 256, 0, stream>>>(U, lnf_g, lnf_b, out);
}

// Round 7
// 452.756 us; speedup vs baseline: 2.2320x; 2.2320x over previous
//
#include <hip/hip_runtime.h>
#include <hip/hip_bf16.h>
#include <math.h>

#define DEV __device__ __forceinline__

constexpr int B  = 8,  N = 16, P = 128, PL = 16;
constexpr int D  = 128, DS = 16, DTR = 8, DFF = 256, EL = 2;
constexpr int L  = N * P + 1;            // 2049
constexpr int BL = B * L;                // 16392
constexpr int CT = 32;                   // scan chunk length
constexpr int NC = (L + CT - 1) / CT;    // 65
constexpr int MT128 = (BL + 127) / 128;  // 129
constexpr int MT64  = (BL + 63) / 64;    // 257
constexpr int KS = 136;                  // LDS row stride (bf16/short units)
constexpr int HS = 264;                  // LDS row stride for H (256+8)

using bf16x8 = __attribute__((ext_vector_type(8))) __bf16;
using f32x4  = __attribute__((ext_vector_type(4))) float;

DEV float sigmoidf_(float x) { return 1.0f / (1.0f + __expf(-x)); }

DEV float wsum(float v) {
#pragma unroll
  for (int m = 32; m; m >>= 1) v += __shfl_xor(v, m, 64);
  return v;
}

// r^(n+1) for n=0..15, depth-4 tree
DEV void pow_tree(float r, float* pw) {
  float r2 = r * r;
  float r3 = r2 * r;
  float r4 = r2 * r2;
  float r8 = r4 * r4;
  float r12 = r8 * r4;
  pw[0] = r;       pw[1] = r2;      pw[2] = r3;      pw[3] = r4;
  pw[4] = r4 * r;  pw[5] = r4 * r2; pw[6] = r4 * r3; pw[7] = r8;
  pw[8] = r8 * r;  pw[9] = r8 * r2; pw[10] = r8 * r3; pw[11] = r12;
  pw[12] = r12 * r; pw[13] = r12 * r2; pw[14] = r12 * r3; pw[15] = r12 * r4;
}

// A_n check: A_init = log(1..16) broadcast -> A_n = -(n+1) exactly.
DEV bool an_is_linear(const float* An) {
  bool ok = true;
#pragma unroll
  for (int n = 0; n < DS; ++n)
    ok = ok && (fabsf(An[n] + (float)(n + 1)) < 1e-3f * (n + 1));
  return ok;
}

// ---------------- weight prep ----------------
__global__ __launch_bounds__(256) void k_prep(
    const float* __restrict__ in_w, const float* __restrict__ conv_w,
    const float* __restrict__ xproj, const float* __restrict__ out_w,
    const float* __restrict__ w1, const float* __restrict__ w2,
    __bf16* __restrict__ weff, __bf16* __restrict__ xpw_bf,
    __bf16* __restrict__ outw_bf, __bf16* __restrict__ w1_bf,
    __bf16* __restrict__ w2_bf)
{
  int g = blockIdx.x * 256 + threadIdx.x;
  if (g < 262144) {
    int l = g >> 17;
    int r = g & 131071;
    int dir = r >> 16;
    int r2 = r & 65535;
    int col = r2 >> 8;
    int kk = r2 & 255;
    int chunk = kk >> 7, k = kk & 127;
    int ld = l * 2 + dir;
    float v;
    if (col < 128) {
      v = in_w[((size_t)ld * 256 + col) * 128 + k] *
          conv_w[((size_t)ld * 128 + col) * 2 + chunk];
    } else {
      v = chunk ? in_w[((size_t)ld * 256 + col) * 128 + k] : 0.f;
    }
    weff[((size_t)ld * 256 + col) * 256 + chunk * 128 + k] = (__bf16)v;
    return;
  }
  g -= 262144;
  if (g < 20480) { xpw_bf[g] = (__bf16)xproj[g]; return; }
  g -= 20480;
  if (g < 65536) {
    int k = g & 127; int q = g >> 7; int n = q & 127; int q2 = q >> 7;
    int dir = q2 & 1; int l = q2 >> 1;
    outw_bf[((size_t)(l * 128 + n)) * 256 + dir * 128 + k] = (__bf16)out_w[g];
    return;
  }
  g -= 65536;
  if (g < 65536) { w1_bf[g] = (__bf16)w1[g]; return; }
  g -= 65536;
  if (g < 65536) { w2_bf[g] = (__bf16)w2[g]; return; }
}

// ---------------- patch embed + view concat -> U (fp32) + Ubf ----------------
__global__ __launch_bounds__(256) void k_embed(
    const float* __restrict__ x, const float* __restrict__ view,
    const float* __restrict__ wp_w, const float* __restrict__ wp_b,
    float* __restrict__ U, __bf16* __restrict__ Ubf)
{
  int g = blockIdx.x * 256 + threadIdx.x;
  if (g >= BL * D) return;
  int d = g & (D - 1);
  int row = g >> 7;
  int b = row / L, t = row % L;
  float acc;
  if (t < N * P) {
    const float* xr = x + ((size_t)b * N * P + t) * PL;
    acc = wp_b[d];
#pragma unroll
    for (int k = 0; k < PL; ++k) acc += xr[k] * wp_w[d * PL + k];
  } else {
    acc = view[b * D + d];
  }
  U[(size_t)row * D + d] = acc;
  Ubf[(size_t)row * D + d] = (__bf16)acc;
}

// ---------------- fused xz GEMM + conv + silu (bf16 outputs) ----------------
__global__ __launch_bounds__(256) void k_xzc(
    const __bf16* __restrict__ Ubf, const __bf16* __restrict__ Weff,
    const float* __restrict__ conv_b_l,
    __bf16* __restrict__ XCCbf, __bf16* __restrict__ Zbf)
{
  __shared__ short As[128 * KS];
  __shared__ short Bs[64 * KS];
  int bx = blockIdx.x;
  int rdir = bx / MT128;
  int tile = bx % MT128;
  int col0 = blockIdx.y * 64;
  bool isx = col0 < 128;
  int tid = threadIdx.x;
  int m0 = tile * 128;
  const __bf16* Wb = Weff + (size_t)rdir * 256 * 256;
  int wave = tid >> 6, lane = tid & 63, lm = lane & 15, lq = lane >> 4;
  f32x4 zero4 = {0.f, 0.f, 0.f, 0.f};
  f32x4 acc[2][4];
#pragma unroll
  for (int r = 0; r < 2; ++r)
#pragma unroll
    for (int c = 0; c < 4; ++c) acc[r][c] = zero4;
  int kc0 = isx ? 0 : 1;
  for (int kc = kc0; kc < 2; ++kc) {
    if (kc != kc0) __syncthreads();
    for (int q = tid; q < 128 * 16; q += 256) {
      int rr = q >> 4, g = q & 15;
      int m = m0 + rr;
      int4 v = make_int4(0, 0, 0, 0);
      if (m < BL) {
        int b = m / L, s = m - b * L;
        bool ok = true;
        int idx;
        if (kc == 0) { ok = (s >= 1); idx = rdir ? (L - s) : (s - 1); }
        else         { idx = rdir ? (L - 1 - s) : s; }
        if (ok) v = *(const int4*)(Ubf + ((size_t)b * L + idx) * 128 + g * 8);
      }
      *(int4*)&As[rr * KS + g * 8] = v;
    }
    for (int q = tid; q < 64 * 16; q += 256) {
      int rr = q >> 4, g = q & 15;
      int4 v = *(const int4*)(Wb + (size_t)(col0 + rr) * 256 + kc * 128 + g * 8);
      *(int4*)&Bs[rr * KS + g * 8] = v;
    }
    __syncthreads();
    for (int ks = 0; ks < 128; ks += 32) {
      bf16x8 af[2];
#pragma unroll
      for (int r = 0; r < 2; ++r)
        af[r] = *(const bf16x8*)&As[(wave * 32 + r * 16 + lm) * KS + ks + lq * 8];
#pragma unroll
      for (int c = 0; c < 4; ++c) {
        bf16x8 bfr = *(const bf16x8*)&Bs[(c * 16 + lm) * KS + ks + lq * 8];
#pragma unroll
        for (int r = 0; r < 2; ++r)
          acc[r][c] = __builtin_amdgcn_mfma_f32_16x16x32_bf16(af[r], bfr, acc[r][c], 0, 0, 0);
      }
    }
  }
#pragma unroll
  for (int r = 0; r < 2; ++r) {
    int rowb = m0 + wave * 32 + r * 16 + lq * 4;
#pragma unroll
    for (int c = 0; c < 4; ++c) {
      int col = col0 + c * 16 + lm;
      float cb = isx ? conv_b_l[rdir * 128 + col] : 0.f;
#pragma unroll
      for (int e = 0; e < 4; ++e) {
        int m = rowb + e;
        if (m >= BL) continue;
        size_t base = ((size_t)rdir * BL + m) * 128;
        float v = acc[r][c][e];
        if (isx) {
          v += cb;
          XCCbf[base + col] = (__bf16)(v * sigmoidf_(v));
        } else {
          Zbf[base + col - 128] = (__bf16)v;
        }
      }
    }
  }
}

// ---------------- fused xproj GEMM + dt ----------------
__global__ __launch_bounds__(256) void k_xproj_dt(
    const __bf16* __restrict__ XCCbf, const __bf16* __restrict__ Wbf,
    const float* __restrict__ dt_w_l, const float* __restrict__ dt_b_l,
    float* __restrict__ BCb, float* __restrict__ DT)
{
  __shared__ short As[128 * KS];
  __shared__ short Bs[64 * KS];
  __shared__ float dbs[128][9];
  int bx = blockIdx.x;
  int rdir = bx / MT128;
  int tile = bx % MT128;
  int tid = threadIdx.x;
  int m0 = tile * 128;
  const __bf16* Wb = Wbf + (size_t)rdir * 40 * 128;
  for (int q = tid; q < 128 * 16; q += 256) {
    int rr = q >> 4, g = q & 15;
    int m = m0 + rr;
    int4 v = make_int4(0, 0, 0, 0);
    if (m < BL) v = *(const int4*)(XCCbf + ((size_t)rdir * BL + m) * 128 + g * 8);
    *(int4*)&As[rr * KS + g * 8] = v;
  }
  for (int q = tid; q < 64 * 16; q += 256) {
    int rr = q >> 4, g = q & 15;
    int4 v = make_int4(0, 0, 0, 0);
    if (rr < 40) v = *(const int4*)(Wb + (size_t)rr * 128 + g * 8);
    *(int4*)&Bs[rr * KS + g * 8] = v;
  }
  __syncthreads();
  int wave = tid >> 6, lane = tid & 63, lm = lane & 15, lq = lane >> 4;
  f32x4 zero4 = {0.f, 0.f, 0.f, 0.f};
  f32x4 acc[2][3];
#pragma unroll
  for (int r = 0; r < 2; ++r)
#pragma unroll
    for (int c = 0; c < 3; ++c) acc[r][c] = zero4;
  for (int ks = 0; ks < 128; ks += 32) {
    bf16x8 af[2];
#pragma unroll
    for (int r = 0; r < 2; ++r)
      af[r] = *(const bf16x8*)&As[(wave * 32 + r * 16 + lm) * KS + ks + lq * 8];
#pragma unroll
    for (int c = 0; c < 3; ++c) {
      bf16x8 bfr = *(const bf16x8*)&Bs[(c * 16 + lm) * KS + ks + lq * 8];
#pragma unroll
      for (int r = 0; r < 2; ++r)
        acc[r][c] = __builtin_amdgcn_mfma_f32_16x16x32_bf16(af[r], bfr, acc[r][c], 0, 0, 0);
    }
  }
#pragma unroll
  for (int r = 0; r < 2; ++r) {
    int rl = wave * 32 + r * 16 + lq * 4;
    int rowb = m0 + rl;
#pragma unroll
    for (int c = 0; c < 3; ++c) {
      int col = c * 16 + lm;
#pragma unroll
      for (int e = 0; e < 4; ++e) {
        int m = rowb + e;
        float v = acc[r][c][e];
        if (col < DTR) dbs[rl + e][col] = v;
        else if (col < DTR + 2 * DS && m < BL)
          BCb[((size_t)rdir * BL + m) * 32 + (col - DTR)] = v;
      }
    }
  }
  __syncthreads();
  {
    int dloc = tid & 127;
    int rpar = tid >> 7;
    const float* dw = dt_w_l + ((size_t)rdir * 128 + dloc) * 8;
    float dwr[8];
#pragma unroll
    for (int j = 0; j < 8; ++j) dwr[j] = dw[j];
    float db = dt_b_l[rdir * 128 + dloc];
    for (int rr = rpar; rr < 128; rr += 2) {
      int m = m0 + rr;
      if (m >= BL) break;
      float a = db;
#pragma unroll
      for (int j = 0; j < 8; ++j) a = fmaf(dbs[rr][j], dwr[j], a);
      float dtv = (a > 20.f) ? a : log1pf(__expf(a));
      DT[((size_t)rdir * BL + m) * 128 + dloc] = dtv;
    }
  }
}

// ---------------- scan phase A: per-chunk local end state + sum(dt) ----------------
__global__ __launch_bounds__(128) void k_scanA(
    const float* __restrict__ DT, const __bf16* __restrict__ XCCbf,
    const float* __restrict__ BCb, const float* __restrict__ Alog_l,
    float* __restrict__ HC, float* __restrict__ DTS)
{
  __shared__ float Bs[CT][DS];
  int blk = blockIdx.x;
  int c  = blk % NC;
  int rb = blk / NC;
  int rdir = rb / B;
  int d = threadIdx.x;
  int s0 = c * CT;
  int cn = min(CT, L - s0);
  size_t rowbase = (size_t)rb * L + s0;
  for (int q = d; q < cn * DS; q += 128)
    Bs[q >> 4][q & 15] = BCb[(rowbase + (q >> 4)) * 32 + (q & 15)];
  float An[DS];
  const float* Ab = Alog_l + (size_t)rdir * D * DS + (size_t)d * DS;
#pragma unroll
  for (int n = 0; n < DS; ++n) An[n] = -__expf(Ab[n]);
  bool fast = an_is_linear(An);
  __syncthreads();
  float h[DS];
#pragma unroll
  for (int n = 0; n < DS; ++n) h[n] = 0.f;
  float dts = 0.f;
  float dt_nx = DT[rowbase * D + d];
  float xc_nx = (float)XCCbf[rowbase * D + d];
  if (fast) {
    for (int ss = 0; ss < cn; ++ss) {
      float dt = dt_nx, xc = xc_nx;
      if (ss + 1 < cn) {
        size_t ro = (rowbase + ss + 1) * D + d;
        dt_nx = DT[ro]; xc_nx = (float)XCCbf[ro];
      }
      dts += dt;
      float e = dt * xc;
      float pw[DS];
      pow_tree(__expf(-dt), pw);
#pragma unroll
      for (int n = 0; n < DS; ++n)
        h[n] = fmaf(pw[n], h[n], e * Bs[ss][n]);
    }
  } else {
    for (int ss = 0; ss < cn; ++ss) {
      float dt = dt_nx, xc = xc_nx;
      if (ss + 1 < cn) {
        size_t ro = (rowbase + ss + 1) * D + d;
        dt_nx = DT[ro]; xc_nx = (float)XCCbf[ro];
      }
      dts += dt;
      float e = dt * xc;
#pragma unroll
      for (int n = 0; n < DS; ++n)
        h[n] = __expf(dt * An[n]) * h[n] + e * Bs[ss][n];
    }
  }
  float* hp = HC + ((size_t)blk * D + d) * DS;
#pragma unroll
  for (int n = 0; n < DS; ++n) hp[n] = h[n];
  DTS[(size_t)blk * D + d] = dts;
}

// ---------------- scan phase B: boundary chain (separate kernel, plain loads) ----------------
__global__ __launch_bounds__(128) void k_scanB(
    const float* __restrict__ HC, const float* __restrict__ DTS,
    const float* __restrict__ Alog_l, float* __restrict__ HIN)
{
  int rb = blockIdx.x;
  int rdir = rb / B;
  int d = threadIdx.x;
  float An[DS];
  const float* Ab = Alog_l + (size_t)rdir * D * DS + (size_t)d * DS;
#pragma unroll
  for (int n = 0; n < DS; ++n) An[n] = -__expf(Ab[n]);
  bool fast = an_is_linear(An);
  float h[DS];
#pragma unroll
  for (int n = 0; n < DS; ++n) h[n] = 0.f;
  size_t i0 = ((size_t)(rb * NC) * D + d) * DS;
  float dts_nx = DTS[(size_t)(rb * NC) * D + d];
  float4 h0 = *(const float4*)(HC + i0);
  float4 h1 = *(const float4*)(HC + i0 + 4);
  float4 h2 = *(const float4*)(HC + i0 + 8);
  float4 h3 = *(const float4*)(HC + i0 + 12);
  for (int c = 0; c < NC; ++c) {
    float* hin = HIN + ((size_t)(rb * NC + c) * D + d) * DS;
    float hc[DS];
    hc[0]=h0.x; hc[1]=h0.y; hc[2]=h0.z; hc[3]=h0.w;
    hc[4]=h1.x; hc[5]=h1.y; hc[6]=h1.z; hc[7]=h1.w;
    hc[8]=h2.x; hc[9]=h2.y; hc[10]=h2.z; hc[11]=h2.w;
    hc[12]=h3.x; hc[13]=h3.y; hc[14]=h3.z; hc[15]=h3.w;
    float dts = dts_nx;
    if (c + 1 < NC) {
      size_t in2 = ((size_t)(rb * NC + c + 1) * D + d) * DS;
      dts_nx = DTS[(size_t)(rb * NC + c + 1) * D + d];
      h0 = *(const float4*)(HC + in2);
      h1 = *(const float4*)(HC + in2 + 4);
      h2 = *(const float4*)(HC + in2 + 8);
      h3 = *(const float4*)(HC + in2 + 12);
    }
#pragma unroll
    for (int n = 0; n < DS; ++n) hin[n] = h[n];
    if (fast) {
      float pw[DS];
      pow_tree(__expf(-dts), pw);
#pragma unroll
      for (int n = 0; n < DS; ++n)
        h[n] = fmaf(pw[n], h[n], hc[n]);
    } else {
#pragma unroll
      for (int n = 0; n < DS; ++n)
        h[n] = __expf(dts * An[n]) * h[n] + hc[n];
    }
  }
}

// ---------------- scan phase C: full scan seeded with h_in, emit y bf16 ----------------
__global__ __launch_bounds__(128) void k_scanC(
    const float* __restrict__ DT, const __bf16* __restrict__ XCCbf,
    const float* __restrict__ BCb, const __bf16* __restrict__ Zbf,
    const float* __restrict__ HIN, const float* __restrict__ Alog_l,
    const float* __restrict__ Dp_l, __bf16* __restrict__ YMbf)
{
  __shared__ float Bsm[CT][DS];
  __shared__ float Csm[CT][DS];
  int blk = blockIdx.x;
  int c  = blk % NC;
  int rb = blk / NC;
  int rdir = rb / B;
  int b = rb % B;
  int d = threadIdx.x;
  int s0 = c * CT;
  int cn = min(CT, L - s0);
  size_t rowbase = (size_t)rb * L + s0;
  for (int q = d; q < cn * 2 * DS; q += 128) {
    int ss = q >> 5, j = q & 31;
    float vv = BCb[(rowbase + ss) * 32 + j];
    if (j < DS) Bsm[ss][j] = vv; else Csm[ss][j - DS] = vv;
  }
  float An[DS];
  const float* Ab = Alog_l + (size_t)rdir * D * DS + (size_t)d * DS;
#pragma unroll
  for (int n = 0; n < DS; ++n) An[n] = -__expf(Ab[n]);
  bool fast = an_is_linear(An);
  float h[DS];
  const float* hin = HIN + ((size_t)blk * D + d) * DS;
#pragma unroll
  for (int n = 0; n < DS; ++n) h[n] = hin[n];
  float Dpv = Dp_l[rdir * D + d];
  __syncthreads();
  float dt_nx = DT[rowbase * D + d];
  float xc_nx = (float)XCCbf[rowbase * D + d];
  float z_nx  = (float)Zbf[rowbase * D + d];
  if (fast) {
    for (int ss = 0; ss < cn; ++ss) {
      float dt = dt_nx, xc = xc_nx, z = z_nx;
      if (ss + 1 < cn) {
        size_t ro = (rowbase + ss + 1) * D + d;
        dt_nx = DT[ro]; xc_nx = (float)XCCbf[ro]; z_nx = (float)Zbf[ro];
      }
      float e = dt * xc;
      float pw[DS];
      pow_tree(__expf(-dt), pw);
      float y = xc * Dpv;
#pragma unroll
      for (int n = 0; n < DS; ++n) {
        h[n] = fmaf(pw[n], h[n], e * Bsm[ss][n]);
        y = fmaf(h[n], Csm[ss][n], y);
      }
      y *= z * sigmoidf_(z);
      int s = s0 + ss;
      int tt = rdir ? (L - 1 - s) : s;
      YMbf[((size_t)b * L + tt) * 256 + rdir * 128 + d] = (__bf16)y;
    }
  } else {
    for (int ss = 0; ss < cn; ++ss) {
      float dt = dt_nx, xc = xc_nx, z = z_nx;
      if (ss + 1 < cn) {
        size_t ro = (rowbase + ss + 1) * D + d;
        dt_nx = DT[ro]; xc_nx = (float)XCCbf[ro]; z_nx = (float)Zbf[ro];
      }
      float e = dt * xc;
      float y = xc * Dpv;
#pragma unroll
      for (int n = 0; n < DS; ++n) {
        h[n] = __expf(dt * An[n]) * h[n] + e * Bsm[ss][n];
        y = fmaf(h[n], Csm[ss][n], y);
      }
      y *= z * sigmoidf_(z);
      int s = s0 + ss;
      int tt = rdir ? (L - 1 - s) : s;
      YMbf[((size_t)b * L + tt) * 256 + rdir * 128 + d] = (__bf16)y;
    }
  }
}

// ---------------- fused tail: outproj + residual + LN1 + FFN1 + FFN2 + LN2 ----------------
__global__ __launch_bounds__(256) void k_tail(
    const __bf16* __restrict__ YMbf, const __bf16* __restrict__ Wout,
    const float* __restrict__ g1, const float* __restrict__ be1,
    const __bf16* __restrict__ w1bf, const float* __restrict__ b1,
    const __bf16* __restrict__ w2bf, const float* __restrict__ b2,
    const float* __restrict__ g2, const float* __restrict__ be2,
    float* __restrict__ U, __bf16* __restrict__ Ubf)
{
  __shared__ short AX[64 * KS];    // phase1 As (YM) -> XRbf
  __shared__ short BH[128 * KS];   // phase1 Bs (Wout) -> Hbf (64 x HS)
  __shared__ short Ws[64 * KS];    // w1/w2 staging
  int m0 = blockIdx.x * 64;
  int tid = threadIdx.x;
  int wave = tid >> 6, lane = tid & 63, lm = lane & 15, lq = lane >> 4;
  f32x4 zero4 = {0.f, 0.f, 0.f, 0.f};

  // ---- phase 1: outproj (K=256) ----
  f32x4 acc[8];
#pragma unroll
  for (int c = 0; c < 8; ++c) acc[c] = zero4;
  for (int kc = 0; kc < 2; ++kc) {
    if (kc) __syncthreads();
    for (int q = tid; q < 64 * 16; q += 256) {
      int rr = q >> 4, g = q & 15;
      int m = m0 + rr;
      int4 v = make_int4(0, 0, 0, 0);
      if (m < BL) v = *(const int4*)(YMbf + (size_t)m * 256 + kc * 128 + g * 8);
      *(int4*)&AX[rr * KS + g * 8] = v;
    }
    for (int q = tid; q < 128 * 16; q += 256) {
      int rr = q >> 4, g = q & 15;
      int4 v = *(const int4*)(Wout + (size_t)rr * 256 + kc * 128 + g * 8);
      *(int4*)&BH[rr * KS + g * 8] = v;
    }
    __syncthreads();
    for (int ks = 0; ks < 128; ks += 32) {
      bf16x8 af = *(const bf16x8*)&AX[(wave * 16 + lm) * KS + ks + lq * 8];
#pragma unroll
      for (int c = 0; c < 8; ++c) {
        bf16x8 bfr = *(const bf16x8*)&BH[(c * 16 + lm) * KS + ks + lq * 8];
        acc[c] = __builtin_amdgcn_mfma_f32_16x16x32_bf16(af, bfr, acc[c], 0, 0, 0);
      }
    }
  }
  __syncthreads();   // all phase-1 LDS reads done before overwrite

  // ---- phase 2: residual + LN1 -> XRbf in AX (wave-private rows) ----
  {
    float g1c[8], be1c[8];
#pragma unroll
    for (int c = 0; c < 8; ++c) {
      int col = c * 16 + lm;
      g1c[c] = g1[col]; be1c[c] = be1[col];
    }
#pragma unroll
    for (int r = 0; r < 4; ++r) {
      int row = m0 + wave * 16 + lq * 4 + r;
      bool valid = row < BL;
      float os[8];
      float sum = 0.f;
#pragma unroll
      for (int c = 0; c < 8; ++c) {
        int col = c * 16 + lm;
        float uv = valid ? U[(size_t)row * 128 + col] : 0.f;
        os[c] = acc[c][r] + uv;
        sum += os[c];
      }
#pragma unroll
      for (int mm = 1; mm < 16; mm <<= 1) sum += __shfl_xor(sum, mm, 64);
      float mean = sum * (1.f / 128.f);
      float qv = 0.f;
#pragma unroll
      for (int c = 0; c < 8; ++c) { float dv = os[c] - mean; qv += dv * dv; }
#pragma unroll
      for (int mm = 1; mm < 16; mm <<= 1) qv += __shfl_xor(qv, mm, 64);
      float inv = rsqrtf(qv * (1.f / 128.f) + 1e-5f);
      int rl = wave * 16 + lq * 4 + r;
#pragma unroll
      for (int c = 0; c < 8; ++c) {
        int col = c * 16 + lm;
        float o = (os[c] - mean) * inv * g1c[c] + be1c[c];
        AX[rl * KS + col] = (short)__builtin_bit_cast(unsigned short, (__bf16)o);
      }
    }
  }

  // ---- phase 3: FFN1 (K=128), H -> BH (rows wave-private) ----
  for (int cc = 0; cc < 4; ++cc) {
    __syncthreads();
    for (int q = tid; q < 64 * 16; q += 256) {
      int rr = q >> 4, g = q & 15;
      int4 v = *(const int4*)(w1bf + (size_t)(cc * 64 + rr) * 128 + g * 8);
      *(int4*)&Ws[rr * KS + g * 8] = v;
    }
    __syncthreads();
    f32x4 a1[4];
#pragma unroll
    for (int c = 0; c < 4; ++c) a1[c] = zero4;
    for (int ks = 0; ks < 128; ks += 32) {
      bf16x8 af = *(const bf16x8*)&AX[(wave * 16 + lm) * KS + ks + lq * 8];
#pragma unroll
      for (int c = 0; c < 4; ++c) {
        bf16x8 bfr = *(const bf16x8*)&Ws[(c * 16 + lm) * KS + ks + lq * 8];
        a1[c] = __builtin_amdgcn_mfma_f32_16x16x32_bf16(af, bfr, a1[c], 0, 0, 0);
      }
    }
#pragma unroll
    for (int c = 0; c < 4; ++c) {
      int col = cc * 64 + c * 16 + lm;
      float bb = b1[col];
#pragma unroll
      for (int e = 0; e < 4; ++e) {
        int rl = wave * 16 + lq * 4 + e;
        float hv = fmaxf(a1[c][e] + bb, 0.f);
        BH[rl * HS + col] = (short)__builtin_bit_cast(unsigned short, (__bf16)hv);
      }
    }
  }

  // ---- phase 4: FFN2 (K=256) + residual + LN2 -> U, Ubf ----
  f32x4 a2[2][4];
#pragma unroll
  for (int nc = 0; nc < 2; ++nc)
#pragma unroll
    for (int c = 0; c < 4; ++c) a2[nc][c] = zero4;
  for (int nc = 0; nc < 2; ++nc) {
    for (int kc = 0; kc < 2; ++kc) {
      __syncthreads();
      for (int q = tid; q < 64 * 16; q += 256) {
        int rr = q >> 4, g = q & 15;
        int4 v = *(const int4*)(w2bf + (size_t)(nc * 64 + rr) * 256 + kc * 128 + g * 8);
        *(int4*)&Ws[rr * KS + g * 8] = v;
      }
      __syncthreads();
      for (int ks = 0; ks < 128; ks += 32) {
        bf16x8 af = *(const bf16x8*)&BH[(wave * 16 + lm) * HS + kc * 128 + ks + lq * 8];
#pragma unroll
        for (int c = 0; c < 4; ++c) {
          bf16x8 bfr = *(const bf16x8*)&Ws[(c * 16 + lm) * KS + ks + lq * 8];
          a2[nc][c] = __builtin_amdgcn_mfma_f32_16x16x32_bf16(af, bfr, a2[nc][c], 0, 0, 0);
        }
      }
    }
  }
  {
    float b2c[8], g2c[8], be2c[8];
#pragma unroll
    for (int q = 0; q < 8; ++q) {
      int col = (q >> 2) * 64 + (q & 3) * 16 + lm;
      b2c[q] = b2[col]; g2c[q] = g2[col]; be2c[q] = be2[col];
    }
#pragma unroll
    for (int r = 0; r < 4; ++r) {
      int rl = wave * 16 + lq * 4 + r;
      int row = m0 + rl;
      bool valid = row < BL;
      float os[8];
      float sum = 0.f;
#pragma unroll
      for (int q = 0; q < 8; ++q) {
        int nc = q >> 2, c = q & 3;
        int col = nc * 64 + c * 16 + lm;
        __bf16 xb = __builtin_bit_cast(__bf16, (unsigned short)AX[rl * KS + col]);
        os[q] = a2[nc][c][r] + b2c[q] + (float)xb;
        sum += os[q];
      }
#pragma unroll
      for (int mm = 1; mm < 16; mm <<= 1) sum += __shfl_xor(sum, mm, 64);
      float mean = sum * (1.f / 128.f);
      float qv = 0.f;
#pragma unroll
      for (int q = 0; q < 8; ++q) { float dv = os[q] - mean; qv += dv * dv; }
#pragma unroll
      for (int mm = 1; mm < 16; mm <<= 1) qv += __shfl_xor(qv, mm, 64);
      float inv = rsqrtf(qv * (1.f / 128.f) + 1e-5f);
      if (valid) {
#pragma unroll
        for (int q = 0; q < 8; ++q) {
          int nc = q >> 2, c = q & 3;
          int col = nc * 64 + c * 16 + lm;
          float o = (os[q] - mean) * inv * g2c[q] + be2c[q];
          U[(size_t)row * 128 + col] = o;
          Ubf[(size_t)row * 128 + col] = (__bf16)o;
        }
      }
    }
  }
}

// ---------------- final LN + slice + transpose -> out (B,N,D,P) ----------------
__global__ __launch_bounds__(256) void k_lnf_out(
    const float* __restrict__ U, const float* __restrict__ g,
    const float* __restrict__ be, float* __restrict__ out)
{
  int gg = blockIdx.x * 4 + (threadIdx.x >> 6);   // [0, B*2048)
  int lane = threadIdx.x & 63;
  int b = gg >> 11, t = gg & 2047;
  const float* ur = U + ((size_t)b * L + t) * D;
  float x0 = ur[lane], x1 = ur[lane + 64];
  float mean = wsum(x0 + x1) * (1.f / D);
  float d0 = x0 - mean, d1 = x1 - mean;
  float var = wsum(d0 * d0 + d1 * d1) * (1.f / D);
  float inv = rsqrtf(var + 1e-5f);
  float o0 = d0 * inv * g[lane] + be[lane];
  float o1 = d1 * inv * g[lane + 64] + be[lane + 64];
  int n = t >> 7, p = t & 127;
  size_t obase = (((size_t)b * N + n) * D) * P + p;
  out[obase + (size_t)lane * P] = o0;
  out[obase + (size_t)(lane + 64) * P] = o1;
}

extern "C" void kernel_launch(void* const* d_in, const int* in_sizes, int n_in,
                              void* d_out, int out_size, void* d_ws, size_t ws_size,
                              hipStream_t stream)
{
  (void)in_sizes; (void)n_in; (void)out_size; (void)ws_size;
  const float* x       = (const float*)d_in[0];
  const float* view    = (const float*)d_in[1];
  const float* wp_w    = (const float*)d_in[2];
  const float* wp_b    = (const float*)d_in[3];
  const float* m_in_w  = (const float*)d_in[4];
  const float* m_conv_w= (const float*)d_in[5];
  const float* m_conv_b= (const float*)d_in[6];
  const float* m_xproj = (const float*)d_in[7];
  const float* m_dt_w  = (const float*)d_in[8];
  const float* m_dt_b  = (const float*)d_in[9];
  const float* m_Alog  = (const float*)d_in[10];
  const float* m_Dp    = (const float*)d_in[11];
  const float* m_out_w = (const float*)d_in[12];
  const float* ffn_w1  = (const float*)d_in[13];
  const float* ffn_b1  = (const float*)d_in[14];
  const float* ffn_w2  = (const float*)d_in[15];
  const float* ffn_b2  = (const float*)d_in[16];
  const float* ln1_g   = (const float*)d_in[17];
  const float* ln1_b   = (const float*)d_in[18];
  const float* ln2_g   = (const float*)d_in[19];
  const float* ln2_b   = (const float*)d_in[20];
  const float* lnf_g   = (const float*)d_in[21];
  const float* lnf_b   = (const float*)d_in[22];
  float* out = (float*)d_out;

  float* W = (float*)d_ws;
  size_t off = 0;
  auto alloc = [&](size_t nfl) { float* p = W + off; off += (nfl + 3) & ~(size_t)3; return p; };
  float* U      = alloc((size_t)BL * D);
  float* Ubf_f  = alloc((size_t)BL * D / 2);
  float* XCC_f  = alloc((size_t)BL * D);          // 2*BL*D bf16
  float* Zbf_f  = alloc((size_t)BL * D);          // 2*BL*D bf16
  float* DTb    = alloc((size_t)2 * BL * D);
  float* BCb    = alloc((size_t)2 * BL * 2 * DS);
  float* YM_f   = alloc((size_t)BL * 256 / 2);
  float* HC     = alloc((size_t)2 * B * NC * D * DS);
  float* DTS    = alloc((size_t)2 * B * NC * D);
  float* HIN    = alloc((size_t)2 * B * NC * D * DS);
  float* weff_f = alloc(262144 / 2);
  float* xpw_f  = alloc(20480 / 2);
  float* outw_f = alloc(65536 / 2);
  float* w1_f   = alloc(65536 / 2);
  float* w2_f   = alloc(65536 / 2);

  __bf16* Ubf    = (__bf16*)Ubf_f;
  __bf16* XCCbf  = (__bf16*)XCC_f;
  __bf16* Zbf    = (__bf16*)Zbf_f;
  __bf16* YMbf   = (__bf16*)YM_f;
  __bf16* weff   = (__bf16*)weff_f;
  __bf16* xpw_bf = (__bf16*)xpw_f;
  __bf16* outw_bf= (__bf16*)outw_f;
  __bf16* w1_bf  = (__bf16*)w1_f;
  __bf16* w2_bf  = (__bf16*)w2_f;

  k_prep<<<1872, 256, 0, stream>>>(m_in_w, m_conv_w, m_xproj, m_out_w, ffn_w1, ffn_w2,
                                   weff, xpw_bf, outw_bf, w1_bf, w2_bf);
  k_embed<<<(BL * D + 255) / 256, 256, 0, stream>>>(x, view, wp_w, wp_b, U, Ubf);

  for (int l = 0; l < EL; ++l) {
    const float* conv_b_l = m_conv_b + (size_t)l * 2 * D;
    const float* dt_w_l   = m_dt_w   + (size_t)l * 2 * D * DTR;
    const float* dt_b_l   = m_dt_b   + (size_t)l * 2 * D;
    const float* Alog_l   = m_Alog   + (size_t)l * 2 * D * DS;
    const float* Dp_l     = m_Dp     + (size_t)l * 2 * D;

    k_xzc      <<<dim3(2 * MT128, 4), 256, 0, stream>>>(Ubf, weff + (size_t)l * 2 * 256 * 256,
                                                        conv_b_l, XCCbf, Zbf);
    k_xproj_dt <<<2 * MT128, 256, 0, stream>>>(XCCbf, xpw_bf + (size_t)l * 2 * 40 * 128,
                                               dt_w_l, dt_b_l, BCb, DTb);
    k_scanA    <<<2 * B * NC, 128, 0, stream>>>(DTb, XCCbf, BCb, Alog_l, HC, DTS);
    k_scanB    <<<2 * B, 128, 0, stream>>>(HC, DTS, Alog_l, HIN);
    k_scanC    <<<2 * B * NC, 128, 0, stream>>>(DTb, XCCbf, BCb, Zbf, HIN, Alog_l, Dp_l, YMbf);
    k_tail     <<<MT64, 256, 0, stream>>>(YMbf, outw_bf + (size_t)l * 128 * 256,
                                          ln1_g + l * D, ln1_b + l * D,
                                          w1_bf + (size_t)l * 256 * 128, ffn_b1 + l * DFF,
                                          w2_bf + (size_t)l * 128 * 256, ffn_b2 + l * D,
                                          ln2_g + l * D, ln2_b + l * D, U, Ubf);
  }
  k_lnf_out<<<(B * N * P) / 4, 256, 0, stream>>>(U, lnf_g, lnf_b, out);
}

// Round 8
// 441.464 us; speedup vs baseline: 2.2891x; 1.0256x over previous
//
#include <hip/hip_runtime.h>
#include <hip/hip_bf16.h>
#include <math.h>

#define DEV __device__ __forceinline__

constexpr int B  = 8,  N = 16, P = 128, PL = 16;
constexpr int D  = 128, DS = 16, DTR = 8, DFF = 256, EL = 2;
constexpr int L  = N * P + 1;            // 2049
constexpr int BL = B * L;                // 16392
constexpr int CT = 32;                   // scan chunk length
constexpr int NC = (L + CT - 1) / CT;    // 65
constexpr int MT128 = (BL + 127) / 128;  // 129
constexpr int MT64  = (BL + 63) / 64;    // 257
constexpr int KS = 136;                  // LDS row stride (bf16/short units)
constexpr int HS = 264;                  // LDS row stride for H (256+8)

using bf16x8 = __attribute__((ext_vector_type(8))) __bf16;
using f32x4  = __attribute__((ext_vector_type(4))) float;

DEV float sigmoidf_(float x) { return 1.0f / (1.0f + __expf(-x)); }

DEV float wsum(float v) {
#pragma unroll
  for (int m = 32; m; m >>= 1) v += __shfl_xor(v, m, 64);
  return v;
}

// r^(n+1) for n=0..15, depth-4 tree
DEV void pow_tree(float r, float* pw) {
  float r2 = r * r;
  float r3 = r2 * r;
  float r4 = r2 * r2;
  float r8 = r4 * r4;
  float r12 = r8 * r4;
  pw[0] = r;       pw[1] = r2;      pw[2] = r3;      pw[3] = r4;
  pw[4] = r4 * r;  pw[5] = r4 * r2; pw[6] = r4 * r3; pw[7] = r8;
  pw[8] = r8 * r;  pw[9] = r8 * r2; pw[10] = r8 * r3; pw[11] = r12;
  pw[12] = r12 * r; pw[13] = r12 * r2; pw[14] = r12 * r3; pw[15] = r12 * r4;
}

// A_n check: A_init = log(1..16) broadcast -> A_n = -(n+1) exactly.
DEV bool an_is_linear(const float* An) {
  bool ok = true;
#pragma unroll
  for (int n = 0; n < DS; ++n)
    ok = ok && (fabsf(An[n] + (float)(n + 1)) < 1e-3f * (n + 1));
  return ok;
}

// ---------------- weight prep ----------------
__global__ __launch_bounds__(256) void k_prep(
    const float* __restrict__ in_w, const float* __restrict__ conv_w,
    const float* __restrict__ xproj, const float* __restrict__ out_w,
    const float* __restrict__ w1, const float* __restrict__ w2,
    __bf16* __restrict__ weff, __bf16* __restrict__ xpw_bf,
    __bf16* __restrict__ outw_bf, __bf16* __restrict__ w1_bf,
    __bf16* __restrict__ w2_bf)
{
  int g = blockIdx.x * 256 + threadIdx.x;
  if (g < 262144) {
    int l = g >> 17;
    int r = g & 131071;
    int dir = r >> 16;
    int r2 = r & 65535;
    int col = r2 >> 8;
    int kk = r2 & 255;
    int chunk = kk >> 7, k = kk & 127;
    int ld = l * 2 + dir;
    float v;
    if (col < 128) {
      v = in_w[((size_t)ld * 256 + col) * 128 + k] *
          conv_w[((size_t)ld * 128 + col) * 2 + chunk];
    } else {
      v = chunk ? in_w[((size_t)ld * 256 + col) * 128 + k] : 0.f;
    }
    weff[((size_t)ld * 256 + col) * 256 + chunk * 128 + k] = (__bf16)v;
    return;
  }
  g -= 262144;
  if (g < 20480) { xpw_bf[g] = (__bf16)xproj[g]; return; }
  g -= 20480;
  if (g < 65536) {
    int k = g & 127; int q = g >> 7; int n = q & 127; int q2 = q >> 7;
    int dir = q2 & 1; int l = q2 >> 1;
    outw_bf[((size_t)(l * 128 + n)) * 256 + dir * 128 + k] = (__bf16)out_w[g];
    return;
  }
  g -= 65536;
  if (g < 65536) { w1_bf[g] = (__bf16)w1[g]; return; }
  g -= 65536;
  if (g < 65536) { w2_bf[g] = (__bf16)w2[g]; return; }
}

// ---------------- patch embed + view concat -> U (fp32) + Ubf ----------------
__global__ __launch_bounds__(256) void k_embed(
    const float* __restrict__ x, const float* __restrict__ view,
    const float* __restrict__ wp_w, const float* __restrict__ wp_b,
    float* __restrict__ U, __bf16* __restrict__ Ubf)
{
  int g = blockIdx.x * 256 + threadIdx.x;
  if (g >= BL * D) return;
  int d = g & (D - 1);
  int row = g >> 7;
  int b = row / L, t = row % L;
  float acc;
  if (t < N * P) {
    const float* xr = x + ((size_t)b * N * P + t) * PL;
    acc = wp_b[d];
#pragma unroll
    for (int k = 0; k < PL; ++k) acc += xr[k] * wp_w[d * PL + k];
  } else {
    acc = view[b * D + d];
  }
  U[(size_t)row * D + d] = acc;
  Ubf[(size_t)row * D + d] = (__bf16)acc;
}

// ---------------- fused xz GEMM + conv + silu (bf16 outputs) ----------------
__global__ __launch_bounds__(256) void k_xzc(
    const __bf16* __restrict__ Ubf, const __bf16* __restrict__ Weff,
    const float* __restrict__ conv_b_l,
    __bf16* __restrict__ XCCbf, __bf16* __restrict__ Zbf)
{
  __shared__ short As[128 * KS];
  __shared__ short Bs[64 * KS];
  int bx = blockIdx.x;
  int rdir = bx / MT128;
  int tile = bx % MT128;
  int col0 = blockIdx.y * 64;
  bool isx = col0 < 128;
  int tid = threadIdx.x;
  int m0 = tile * 128;
  const __bf16* Wb = Weff + (size_t)rdir * 256 * 256;
  int wave = tid >> 6, lane = tid & 63, lm = lane & 15, lq = lane >> 4;
  f32x4 zero4 = {0.f, 0.f, 0.f, 0.f};
  f32x4 acc[2][4];
#pragma unroll
  for (int r = 0; r < 2; ++r)
#pragma unroll
    for (int c = 0; c < 4; ++c) acc[r][c] = zero4;
  int kc0 = isx ? 0 : 1;
  for (int kc = kc0; kc < 2; ++kc) {
    if (kc != kc0) __syncthreads();
    for (int q = tid; q < 128 * 16; q += 256) {
      int rr = q >> 4, g = q & 15;
      int m = m0 + rr;
      int4 v = make_int4(0, 0, 0, 0);
      if (m < BL) {
        int b = m / L, s = m - b * L;
        bool ok = true;
        int idx;
        if (kc == 0) { ok = (s >= 1); idx = rdir ? (L - s) : (s - 1); }
        else         { idx = rdir ? (L - 1 - s) : s; }
        if (ok) v = *(const int4*)(Ubf + ((size_t)b * L + idx) * 128 + g * 8);
      }
      *(int4*)&As[rr * KS + g * 8] = v;
    }
    for (int q = tid; q < 64 * 16; q += 256) {
      int rr = q >> 4, g = q & 15;
      int4 v = *(const int4*)(Wb + (size_t)(col0 + rr) * 256 + kc * 128 + g * 8);
      *(int4*)&Bs[rr * KS + g * 8] = v;
    }
    __syncthreads();
    for (int ks = 0; ks < 128; ks += 32) {
      bf16x8 af[2];
#pragma unroll
      for (int r = 0; r < 2; ++r)
        af[r] = *(const bf16x8*)&As[(wave * 32 + r * 16 + lm) * KS + ks + lq * 8];
#pragma unroll
      for (int c = 0; c < 4; ++c) {
        bf16x8 bfr = *(const bf16x8*)&Bs[(c * 16 + lm) * KS + ks + lq * 8];
#pragma unroll
        for (int r = 0; r < 2; ++r)
          acc[r][c] = __builtin_amdgcn_mfma_f32_16x16x32_bf16(af[r], bfr, acc[r][c], 0, 0, 0);
      }
    }
  }
#pragma unroll
  for (int r = 0; r < 2; ++r) {
    int rowb = m0 + wave * 32 + r * 16 + lq * 4;
#pragma unroll
    for (int c = 0; c < 4; ++c) {
      int col = col0 + c * 16 + lm;
      float cb = isx ? conv_b_l[rdir * 128 + col] : 0.f;
#pragma unroll
      for (int e = 0; e < 4; ++e) {
        int m = rowb + e;
        if (m >= BL) continue;
        size_t base = ((size_t)rdir * BL + m) * 128;
        float v = acc[r][c][e];
        if (isx) {
          v += cb;
          XCCbf[base + col] = (__bf16)(v * sigmoidf_(v));
        } else {
          Zbf[base + col - 128] = (__bf16)v;
        }
      }
    }
  }
}

// ---------------- fused xproj GEMM + dt ----------------
__global__ __launch_bounds__(256) void k_xproj_dt(
    const __bf16* __restrict__ XCCbf, const __bf16* __restrict__ Wbf,
    const float* __restrict__ dt_w_l, const float* __restrict__ dt_b_l,
    float* __restrict__ BCb, float* __restrict__ DT)
{
  __shared__ short As[128 * KS];
  __shared__ short Bs[64 * KS];
  __shared__ float dbs[128][9];
  int bx = blockIdx.x;
  int rdir = bx / MT128;
  int tile = bx % MT128;
  int tid = threadIdx.x;
  int m0 = tile * 128;
  const __bf16* Wb = Wbf + (size_t)rdir * 40 * 128;
  for (int q = tid; q < 128 * 16; q += 256) {
    int rr = q >> 4, g = q & 15;
    int m = m0 + rr;
    int4 v = make_int4(0, 0, 0, 0);
    if (m < BL) v = *(const int4*)(XCCbf + ((size_t)rdir * BL + m) * 128 + g * 8);
    *(int4*)&As[rr * KS + g * 8] = v;
  }
  for (int q = tid; q < 64 * 16; q += 256) {
    int rr = q >> 4, g = q & 15;
    int4 v = make_int4(0, 0, 0, 0);
    if (rr < 40) v = *(const int4*)(Wb + (size_t)rr * 128 + g * 8);
    *(int4*)&Bs[rr * KS + g * 8] = v;
  }
  __syncthreads();
  int wave = tid >> 6, lane = tid & 63, lm = lane & 15, lq = lane >> 4;
  f32x4 zero4 = {0.f, 0.f, 0.f, 0.f};
  f32x4 acc[2][3];
#pragma unroll
  for (int r = 0; r < 2; ++r)
#pragma unroll
    for (int c = 0; c < 3; ++c) acc[r][c] = zero4;
  for (int ks = 0; ks < 128; ks += 32) {
    bf16x8 af[2];
#pragma unroll
    for (int r = 0; r < 2; ++r)
      af[r] = *(const bf16x8*)&As[(wave * 32 + r * 16 + lm) * KS + ks + lq * 8];
#pragma unroll
    for (int c = 0; c < 3; ++c) {
      bf16x8 bfr = *(const bf16x8*)&Bs[(c * 16 + lm) * KS + ks + lq * 8];
#pragma unroll
      for (int r = 0; r < 2; ++r)
        acc[r][c] = __builtin_amdgcn_mfma_f32_16x16x32_bf16(af[r], bfr, acc[r][c], 0, 0, 0);
    }
  }
#pragma unroll
  for (int r = 0; r < 2; ++r) {
    int rl = wave * 32 + r * 16 + lq * 4;
    int rowb = m0 + rl;
#pragma unroll
    for (int c = 0; c < 3; ++c) {
      int col = c * 16 + lm;
#pragma unroll
      for (int e = 0; e < 4; ++e) {
        int m = rowb + e;
        float v = acc[r][c][e];
        if (col < DTR) dbs[rl + e][col] = v;
        else if (col < DTR + 2 * DS && m < BL)
          BCb[((size_t)rdir * BL + m) * 32 + (col - DTR)] = v;
      }
    }
  }
  __syncthreads();
  {
    int dloc = tid & 127;
    int rpar = tid >> 7;
    const float* dw = dt_w_l + ((size_t)rdir * 128 + dloc) * 8;
    float dwr[8];
#pragma unroll
    for (int j = 0; j < 8; ++j) dwr[j] = dw[j];
    float db = dt_b_l[rdir * 128 + dloc];
    for (int rr = rpar; rr < 128; rr += 2) {
      int m = m0 + rr;
      if (m >= BL) break;
      float a = db;
#pragma unroll
      for (int j = 0; j < 8; ++j) a = fmaf(dbs[rr][j], dwr[j], a);
      float dtv = (a > 20.f) ? a : log1pf(__expf(a));
      DT[((size_t)rdir * BL + m) * 128 + dloc] = dtv;
    }
  }
}

// ---------------- scan phase A: LDS-staged inputs, serial loop out of LDS ----------------
__global__ __launch_bounds__(128) void k_scanA(
    const float* __restrict__ DT, const __bf16* __restrict__ XCCbf,
    const float* __restrict__ BCb, const float* __restrict__ Alog_l,
    float* __restrict__ HC, float* __restrict__ DTS)
{
  __shared__ float Bs[CT][DS];     // 2 KB
  __shared__ float DTs[CT][128];   // 16 KB
  __shared__ __bf16 XCs[CT][128];  // 8 KB
  int blk = blockIdx.x;
  int c  = blk % NC;
  int rb = blk / NC;
  int rdir = rb / B;
  int d = threadIdx.x;
  int s0 = c * CT;
  int cn = min(CT, L - s0);
  size_t rowbase = (size_t)rb * L + s0;
  // stage B
  for (int q = d; q < cn * DS; q += 128)
    Bs[q >> 4][q & 15] = BCb[(rowbase + (q >> 4)) * 32 + (q & 15)];
  // stage DT (float4) and XCC (int4 = 8 bf16) — all loads issued in a burst
  for (int q = d; q < cn * 32; q += 128) {
    int row = q >> 5, c4 = (q & 31) * 4;
    *(float4*)&DTs[row][c4] = *(const float4*)(DT + (rowbase + row) * D + c4);
  }
  for (int q = d; q < cn * 16; q += 128) {
    int row = q >> 4, c8 = (q & 15) * 8;
    *(int4*)&XCs[row][c8] = *(const int4*)(XCCbf + (rowbase + row) * D + c8);
  }
  float An[DS];
  const float* Ab = Alog_l + (size_t)rdir * D * DS + (size_t)d * DS;
#pragma unroll
  for (int n = 0; n < DS; ++n) An[n] = -__expf(Ab[n]);
  bool fast = an_is_linear(An);
  __syncthreads();
  float h[DS];
#pragma unroll
  for (int n = 0; n < DS; ++n) h[n] = 0.f;
  float dts = 0.f;
  if (fast) {
    for (int ss = 0; ss < cn; ++ss) {
      float dt = DTs[ss][d];
      float xc = (float)XCs[ss][d];
      dts += dt;
      float e = dt * xc;
      float pw[DS];
      pow_tree(__expf(-dt), pw);
#pragma unroll
      for (int n = 0; n < DS; ++n)
        h[n] = fmaf(pw[n], h[n], e * Bs[ss][n]);
    }
  } else {
    for (int ss = 0; ss < cn; ++ss) {
      float dt = DTs[ss][d];
      float xc = (float)XCs[ss][d];
      dts += dt;
      float e = dt * xc;
#pragma unroll
      for (int n = 0; n < DS; ++n)
        h[n] = __expf(dt * An[n]) * h[n] + e * Bs[ss][n];
    }
  }
  float* hp = HC + ((size_t)blk * D + d) * DS;
#pragma unroll
  for (int n = 0; n < DS; ++n) hp[n] = h[n];
  DTS[(size_t)blk * D + d] = dts;
}

// ---------------- scan phase B: boundary chain (separate kernel, plain loads) ----------------
__global__ __launch_bounds__(128) void k_scanB(
    const float* __restrict__ HC, const float* __restrict__ DTS,
    const float* __restrict__ Alog_l, float* __restrict__ HIN)
{
  int rb = blockIdx.x;
  int rdir = rb / B;
  int d = threadIdx.x;
  float An[DS];
  const float* Ab = Alog_l + (size_t)rdir * D * DS + (size_t)d * DS;
#pragma unroll
  for (int n = 0; n < DS; ++n) An[n] = -__expf(Ab[n]);
  bool fast = an_is_linear(An);
  float h[DS];
#pragma unroll
  for (int n = 0; n < DS; ++n) h[n] = 0.f;
  size_t i0 = ((size_t)(rb * NC) * D + d) * DS;
  float dts_nx = DTS[(size_t)(rb * NC) * D + d];
  float4 h0 = *(const float4*)(HC + i0);
  float4 h1 = *(const float4*)(HC + i0 + 4);
  float4 h2 = *(const float4*)(HC + i0 + 8);
  float4 h3 = *(const float4*)(HC + i0 + 12);
  for (int c = 0; c < NC; ++c) {
    float* hin = HIN + ((size_t)(rb * NC + c) * D + d) * DS;
    float hc[DS];
    hc[0]=h0.x; hc[1]=h0.y; hc[2]=h0.z; hc[3]=h0.w;
    hc[4]=h1.x; hc[5]=h1.y; hc[6]=h1.z; hc[7]=h1.w;
    hc[8]=h2.x; hc[9]=h2.y; hc[10]=h2.z; hc[11]=h2.w;
    hc[12]=h3.x; hc[13]=h3.y; hc[14]=h3.z; hc[15]=h3.w;
    float dts = dts_nx;
    if (c + 1 < NC) {
      size_t in2 = ((size_t)(rb * NC + c + 1) * D + d) * DS;
      dts_nx = DTS[(size_t)(rb * NC + c + 1) * D + d];
      h0 = *(const float4*)(HC + in2);
      h1 = *(const float4*)(HC + in2 + 4);
      h2 = *(const float4*)(HC + in2 + 8);
      h3 = *(const float4*)(HC + in2 + 12);
    }
#pragma unroll
    for (int n = 0; n < DS; ++n) hin[n] = h[n];
    if (fast) {
      float pw[DS];
      pow_tree(__expf(-dts), pw);
#pragma unroll
      for (int n = 0; n < DS; ++n)
        h[n] = fmaf(pw[n], h[n], hc[n]);
    } else {
#pragma unroll
      for (int n = 0; n < DS; ++n)
        h[n] = __expf(dts * An[n]) * h[n] + hc[n];
    }
  }
}

// ---------------- scan phase C: LDS-staged inputs, emit y bf16 ----------------
__global__ __launch_bounds__(128) void k_scanC(
    const float* __restrict__ DT, const __bf16* __restrict__ XCCbf,
    const float* __restrict__ BCb, const __bf16* __restrict__ Zbf,
    const float* __restrict__ HIN, const float* __restrict__ Alog_l,
    const float* __restrict__ Dp_l, __bf16* __restrict__ YMbf)
{
  __shared__ float Bsm[CT][DS];    // 2 KB
  __shared__ float Csm[CT][DS];    // 2 KB
  __shared__ float DTs[CT][128];   // 16 KB
  __shared__ __bf16 XCs[CT][128];  // 8 KB
  __shared__ __bf16 Zs[CT][128];   // 8 KB
  int blk = blockIdx.x;
  int c  = blk % NC;
  int rb = blk / NC;
  int rdir = rb / B;
  int b = rb % B;
  int d = threadIdx.x;
  int s0 = c * CT;
  int cn = min(CT, L - s0);
  size_t rowbase = (size_t)rb * L + s0;
  for (int q = d; q < cn * 2 * DS; q += 128) {
    int ss = q >> 5, j = q & 31;
    float vv = BCb[(rowbase + ss) * 32 + j];
    if (j < DS) Bsm[ss][j] = vv; else Csm[ss][j - DS] = vv;
  }
  for (int q = d; q < cn * 32; q += 128) {
    int row = q >> 5, c4 = (q & 31) * 4;
    *(float4*)&DTs[row][c4] = *(const float4*)(DT + (rowbase + row) * D + c4);
  }
  for (int q = d; q < cn * 16; q += 128) {
    int row = q >> 4, c8 = (q & 15) * 8;
    *(int4*)&XCs[row][c8] = *(const int4*)(XCCbf + (rowbase + row) * D + c8);
    *(int4*)&Zs[row][c8]  = *(const int4*)(Zbf + (rowbase + row) * D + c8);
  }
  float An[DS];
  const float* Ab = Alog_l + (size_t)rdir * D * DS + (size_t)d * DS;
#pragma unroll
  for (int n = 0; n < DS; ++n) An[n] = -__expf(Ab[n]);
  bool fast = an_is_linear(An);
  float h[DS];
  const float* hin = HIN + ((size_t)blk * D + d) * DS;
#pragma unroll
  for (int n = 0; n < DS; ++n) h[n] = hin[n];
  float Dpv = Dp_l[rdir * D + d];
  __syncthreads();
  if (fast) {
    for (int ss = 0; ss < cn; ++ss) {
      float dt = DTs[ss][d];
      float xc = (float)XCs[ss][d];
      float z  = (float)Zs[ss][d];
      float e = dt * xc;
      float pw[DS];
      pow_tree(__expf(-dt), pw);
      float y = xc * Dpv;
#pragma unroll
      for (int n = 0; n < DS; ++n) {
        h[n] = fmaf(pw[n], h[n], e * Bsm[ss][n]);
        y = fmaf(h[n], Csm[ss][n], y);
      }
      y *= z * sigmoidf_(z);
      int s = s0 + ss;
      int tt = rdir ? (L - 1 - s) : s;
      YMbf[((size_t)b * L + tt) * 256 + rdir * 128 + d] = (__bf16)y;
    }
  } else {
    for (int ss = 0; ss < cn; ++ss) {
      float dt = DTs[ss][d];
      float xc = (float)XCs[ss][d];
      float z  = (float)Zs[ss][d];
      float e = dt * xc;
      float y = xc * Dpv;
#pragma unroll
      for (int n = 0; n < DS; ++n) {
        h[n] = __expf(dt * An[n]) * h[n] + e * Bsm[ss][n];
        y = fmaf(h[n], Csm[ss][n], y);
      }
      y *= z * sigmoidf_(z);
      int s = s0 + ss;
      int tt = rdir ? (L - 1 - s) : s;
      YMbf[((size_t)b * L + tt) * 256 + rdir * 128 + d] = (__bf16)y;
    }
  }
}

// ---------------- fused tail: outproj + residual + LN1 + FFN1 + FFN2 + LN2 ----------------
__global__ __launch_bounds__(256) void k_tail(
    const __bf16* __restrict__ YMbf, const __bf16* __restrict__ Wout,
    const float* __restrict__ g1, const float* __restrict__ be1,
    const __bf16* __restrict__ w1bf, const float* __restrict__ b1,
    const __bf16* __restrict__ w2bf, const float* __restrict__ b2,
    const float* __restrict__ g2, const float* __restrict__ be2,
    float* __restrict__ U, __bf16* __restrict__ Ubf)
{
  __shared__ short AX[64 * KS];    // phase1 As (YM) -> XRbf
  __shared__ short BH[128 * KS];   // phase1 Bs (Wout) -> Hbf (64 x HS)
  __shared__ short Ws[64 * KS];    // w1/w2 staging
  int m0 = blockIdx.x * 64;
  int tid = threadIdx.x;
  int wave = tid >> 6, lane = tid & 63, lm = lane & 15, lq = lane >> 4;
  f32x4 zero4 = {0.f, 0.f, 0.f, 0.f};

  // ---- phase 1: outproj (K=256) ----
  f32x4 acc[8];
#pragma unroll
  for (int c = 0; c < 8; ++c) acc[c] = zero4;
  for (int kc = 0; kc < 2; ++kc) {
    if (kc) __syncthreads();
    for (int q = tid; q < 64 * 16; q += 256) {
      int rr = q >> 4, g = q & 15;
      int m = m0 + rr;
      int4 v = make_int4(0, 0, 0, 0);
      if (m < BL) v = *(const int4*)(YMbf + (size_t)m * 256 + kc * 128 + g * 8);
      *(int4*)&AX[rr * KS + g * 8] = v;
    }
    for (int q = tid; q < 128 * 16; q += 256) {
      int rr = q >> 4, g = q & 15;
      int4 v = *(const int4*)(Wout + (size_t)rr * 256 + kc * 128 + g * 8);
      *(int4*)&BH[rr * KS + g * 8] = v;
    }
    __syncthreads();
    for (int ks = 0; ks < 128; ks += 32) {
      bf16x8 af = *(const bf16x8*)&AX[(wave * 16 + lm) * KS + ks + lq * 8];
#pragma unroll
      for (int c = 0; c < 8; ++c) {
        bf16x8 bfr = *(const bf16x8*)&BH[(c * 16 + lm) * KS + ks + lq * 8];
        acc[c] = __builtin_amdgcn_mfma_f32_16x16x32_bf16(af, bfr, acc[c], 0, 0, 0);
      }
    }
  }
  __syncthreads();   // all phase-1 LDS reads done before overwrite

  // ---- phase 2: residual + LN1 -> XRbf in AX (wave-private rows) ----
  {
    float g1c[8], be1c[8];
#pragma unroll
    for (int c = 0; c < 8; ++c) {
      int col = c * 16 + lm;
      g1c[c] = g1[col]; be1c[c] = be1[col];
    }
#pragma unroll
    for (int r = 0; r < 4; ++r) {
      int row = m0 + wave * 16 + lq * 4 + r;
      bool valid = row < BL;
      float os[8];
      float sum = 0.f;
#pragma unroll
      for (int c = 0; c < 8; ++c) {
        int col = c * 16 + lm;
        float uv = valid ? U[(size_t)row * 128 + col] : 0.f;
        os[c] = acc[c][r] + uv;
        sum += os[c];
      }
#pragma unroll
      for (int mm = 1; mm < 16; mm <<= 1) sum += __shfl_xor(sum, mm, 64);
      float mean = sum * (1.f / 128.f);
      float qv = 0.f;
#pragma unroll
      for (int c = 0; c < 8; ++c) { float dv = os[c] - mean; qv += dv * dv; }
#pragma unroll
      for (int mm = 1; mm < 16; mm <<= 1) qv += __shfl_xor(qv, mm, 64);
      float inv = rsqrtf(qv * (1.f / 128.f) + 1e-5f);
      int rl = wave * 16 + lq * 4 + r;
#pragma unroll
      for (int c = 0; c < 8; ++c) {
        int col = c * 16 + lm;
        float o = (os[c] - mean) * inv * g1c[c] + be1c[c];
        AX[rl * KS + col] = (short)__builtin_bit_cast(unsigned short, (__bf16)o);
      }
    }
  }

  // ---- phase 3: FFN1 (K=128), H -> BH (rows wave-private) ----
  for (int cc = 0; cc < 4; ++cc) {
    __syncthreads();
    for (int q = tid; q < 64 * 16; q += 256) {
      int rr = q >> 4, g = q & 15;
      int4 v = *(const int4*)(w1bf + (size_t)(cc * 64 + rr) * 128 + g * 8);
      *(int4*)&Ws[rr * KS + g * 8] = v;
    }
    __syncthreads();
    f32x4 a1[4];
#pragma unroll
    for (int c = 0; c < 4; ++c) a1[c] = zero4;
    for (int ks = 0; ks < 128; ks += 32) {
      bf16x8 af = *(const bf16x8*)&AX[(wave * 16 + lm) * KS + ks + lq * 8];
#pragma unroll
      for (int c = 0; c < 4; ++c) {
        bf16x8 bfr = *(const bf16x8*)&Ws[(c * 16 + lm) * KS + ks + lq * 8];
        a1[c] = __builtin_amdgcn_mfma_f32_16x16x32_bf16(af, bfr, a1[c], 0, 0, 0);
      }
    }
#pragma unroll
    for (int c = 0; c < 4; ++c) {
      int col = cc * 64 + c * 16 + lm;
      float bb = b1[col];
#pragma unroll
      for (int e = 0; e < 4; ++e) {
        int rl = wave * 16 + lq * 4 + e;
        float hv = fmaxf(a1[c][e] + bb, 0.f);
        BH[rl * HS + col] = (short)__builtin_bit_cast(unsigned short, (__bf16)hv);
      }
    }
  }

  // ---- phase 4: FFN2 (K=256) + residual + LN2 -> U, Ubf ----
  f32x4 a2[2][4];
#pragma unroll
  for (int nc = 0; nc < 2; ++nc)
#pragma unroll
    for (int c = 0; c < 4; ++c) a2[nc][c] = zero4;
  for (int nc = 0; nc < 2; ++nc) {
    for (int kc = 0; kc < 2; ++kc) {
      __syncthreads();
      for (int q = tid; q < 64 * 16; q += 256) {
        int rr = q >> 4, g = q & 15;
        int4 v = *(const int4*)(w2bf + (size_t)(nc * 64 + rr) * 256 + kc * 128 + g * 8);
        *(int4*)&Ws[rr * KS + g * 8] = v;
      }
      __syncthreads();
      for (int ks = 0; ks < 128; ks += 32) {
        bf16x8 af = *(const bf16x8*)&BH[(wave * 16 + lm) * HS + kc * 128 + ks + lq * 8];
#pragma unroll
        for (int c = 0; c < 4; ++c) {
          bf16x8 bfr = *(const bf16x8*)&Ws[(c * 16 + lm) * KS + ks + lq * 8];
          a2[nc][c] = __builtin_amdgcn_mfma_f32_16x16x32_bf16(af, bfr, a2[nc][c], 0, 0, 0);
        }
      }
    }
  }
  {
    float b2c[8], g2c[8], be2c[8];
#pragma unroll
    for (int q = 0; q < 8; ++q) {
      int col = (q >> 2) * 64 + (q & 3) * 16 + lm;
      b2c[q] = b2[col]; g2c[q] = g2[col]; be2c[q] = be2[col];
    }
#pragma unroll
    for (int r = 0; r < 4; ++r) {
      int rl = wave * 16 + lq * 4 + r;
      int row = m0 + rl;
      bool valid = row < BL;
      float os[8];
      float sum = 0.f;
#pragma unroll
      for (int q = 0; q < 8; ++q) {
        int nc = q >> 2, c = q & 3;
        int col = nc * 64 + c * 16 + lm;
        __bf16 xb = __builtin_bit_cast(__bf16, (unsigned short)AX[rl * KS + col]);
        os[q] = a2[nc][c][r] + b2c[q] + (float)xb;
        sum += os[q];
      }
#pragma unroll
      for (int mm = 1; mm < 16; mm <<= 1) sum += __shfl_xor(sum, mm, 64);
      float mean = sum * (1.f / 128.f);
      float qv = 0.f;
#pragma unroll
      for (int q = 0; q < 8; ++q) { float dv = os[q] - mean; qv += dv * dv; }
#pragma unroll
      for (int mm = 1; mm < 16; mm <<= 1) qv += __shfl_xor(qv, mm, 64);
      float inv = rsqrtf(qv * (1.f / 128.f) + 1e-5f);
      if (valid) {
#pragma unroll
        for (int q = 0; q < 8; ++q) {
          int nc = q >> 2, c = q & 3;
          int col = nc * 64 + c * 16 + lm;
          float o = (os[q] - mean) * inv * g2c[q] + be2c[q];
          U[(size_t)row * 128 + col] = o;
          Ubf[(size_t)row * 128 + col] = (__bf16)o;
        }
      }
    }
  }
}

// ---------------- final LN + slice + transpose -> out (B,N,D,P) ----------------
__global__ __launch_bounds__(256) void k_lnf_out(
    const float* __restrict__ U, const float* __restrict__ g,
    const float* __restrict__ be, float* __restrict__ out)
{
  int gg = blockIdx.x * 4 + (threadIdx.x >> 6);   // [0, B*2048)
  int lane = threadIdx.x & 63;
  int b = gg >> 11, t = gg & 2047;
  const float* ur = U + ((size_t)b * L + t) * D;
  float x0 = ur[lane], x1 = ur[lane + 64];
  float mean = wsum(x0 + x1) * (1.f / D);
  float d0 = x0 - mean, d1 = x1 - mean;
  float var = wsum(d0 * d0 + d1 * d1) * (1.f / D);
  float inv = rsqrtf(var + 1e-5f);
  float o0 = d0 * inv * g[lane] + be[lane];
  float o1 = d1 * inv * g[lane + 64] + be[lane + 64];
  int n = t >> 7, p = t & 127;
  size_t obase = (((size_t)b * N + n) * D) * P + p;
  out[obase + (size_t)lane * P] = o0;
  out[obase + (size_t)(lane + 64) * P] = o1;
}

extern "C" void kernel_launch(void* const* d_in, const int* in_sizes, int n_in,
                              void* d_out, int out_size, void* d_ws, size_t ws_size,
                              hipStream_t stream)
{
  (void)in_sizes; (void)n_in; (void)out_size; (void)ws_size;
  const float* x       = (const float*)d_in[0];
  const float* view    = (const float*)d_in[1];
  const float* wp_w    = (const float*)d_in[2];
  const float* wp_b    = (const float*)d_in[3];
  const float* m_in_w  = (const float*)d_in[4];
  const float* m_conv_w= (const float*)d_in[5];
  const float* m_conv_b= (const float*)d_in[6];
  const float* m_xproj = (const float*)d_in[7];
  const float* m_dt_w  = (const float*)d_in[8];
  const float* m_dt_b  = (const float*)d_in[9];
  const float* m_Alog  = (const float*)d_in[10];
  const float* m_Dp    = (const float*)d_in[11];
  const float* m_out_w = (const float*)d_in[12];
  const float* ffn_w1  = (const float*)d_in[13];
  const float* ffn_b1  = (const float*)d_in[14];
  const float* ffn_w2  = (const float*)d_in[15];
  const float* ffn_b2  = (const float*)d_in[16];
  const float* ln1_g   = (const float*)d_in[17];
  const float* ln1_b   = (const float*)d_in[18];
  const float* ln2_g   = (const float*)d_in[19];
  const float* ln2_b   = (const float*)d_in[20];
  const float* lnf_g   = (const float*)d_in[21];
  const float* lnf_b   = (const float*)d_in[22];
  float* out = (float*)d_out;

  float* W = (float*)d_ws;
  size_t off = 0;
  auto alloc = [&](size_t nfl) { float* p = W + off; off += (nfl + 3) & ~(size_t)3; return p; };
  float* U      = alloc((size_t)BL * D);
  float* Ubf_f  = alloc((size_t)BL * D / 2);
  float* XCC_f  = alloc((size_t)BL * D);          // 2*BL*D bf16
  float* Zbf_f  = alloc((size_t)BL * D);          // 2*BL*D bf16
  float* DTb    = alloc((size_t)2 * BL * D);
  float* BCb    = alloc((size_t)2 * BL * 2 * DS);
  float* YM_f   = alloc((size_t)BL * 256 / 2);
  float* HC     = alloc((size_t)2 * B * NC * D * DS);
  float* DTS    = alloc((size_t)2 * B * NC * D);
  float* HIN    = alloc((size_t)2 * B * NC * D * DS);
  float* weff_f = alloc(262144 / 2);
  float* xpw_f  = alloc(20480 / 2);
  float* outw_f = alloc(65536 / 2);
  float* w1_f   = alloc(65536 / 2);
  float* w2_f   = alloc(65536 / 2);

  __bf16* Ubf    = (__bf16*)Ubf_f;
  __bf16* XCCbf  = (__bf16*)XCC_f;
  __bf16* Zbf    = (__bf16*)Zbf_f;
  __bf16* YMbf   = (__bf16*)YM_f;
  __bf16* weff   = (__bf16*)weff_f;
  __bf16* xpw_bf = (__bf16*)xpw_f;
  __bf16* outw_bf= (__bf16*)outw_f;
  __bf16* w1_bf  = (__bf16*)w1_f;
  __bf16* w2_bf  = (__bf16*)w2_f;

  k_prep<<<1872, 256, 0, stream>>>(m_in_w, m_conv_w, m_xproj, m_out_w, ffn_w1, ffn_w2,
                                   weff, xpw_bf, outw_bf, w1_bf, w2_bf);
  k_embed<<<(BL * D + 255) / 256, 256, 0, stream>>>(x, view, wp_w, wp_b, U, Ubf);

  for (int l = 0; l < EL; ++l) {
    const float* conv_b_l = m_conv_b + (size_t)l * 2 * D;
    const float* dt_w_l   = m_dt_w   + (size_t)l * 2 * D * DTR;
    const float* dt_b_l   = m_dt_b   + (size_t)l * 2 * D;
    const float* Alog_l   = m_Alog   + (size_t)l * 2 * D * DS;
    const float* Dp_l     = m_Dp     + (size_t)l * 2 * D;

    k_xzc      <<<dim3(2 * MT128, 4), 256, 0, stream>>>(Ubf, weff + (size_t)l * 2 * 256 * 256,
                                                        conv_b_l, XCCbf, Zbf);
    k_xproj_dt <<<2 * MT128, 256, 0, stream>>>(XCCbf, xpw_bf + (size_t)l * 2 * 40 * 128,
                                               dt_w_l, dt_b_l, BCb, DTb);
    k_scanA    <<<2 * B * NC, 128, 0, stream>>>(DTb, XCCbf, BCb, Alog_l, HC, DTS);
    k_scanB    <<<2 * B, 128, 0, stream>>>(HC, DTS, Alog_l, HIN);
    k_scanC    <<<2 * B * NC, 128, 0, stream>>>(DTb, XCCbf, BCb, Zbf, HIN, Alog_l, Dp_l, YMbf);
    k_tail     <<<MT64, 256, 0, stream>>>(YMbf, outw_bf + (size_t)l * 128 * 256,
                                          ln1_g + l * D, ln1_b + l * D,
                                          w1_bf + (size_t)l * 256 * 128, ffn_b1 + l * DFF,
                                          w2_bf + (size_t)l * 128 * 256, ffn_b2 + l * D,
                                          ln2_g + l * D, ln2_b + l * D, U, Ubf);
  }
  k_lnf_out<<<(B * N * P) / 4, 256, 0, stream>>>(U, lnf_g, lnf_b, out);
}

// Round 9
// 412.942 us; speedup vs baseline: 2.4472x; 1.0691x over previous
//
#include <hip/hip_runtime.h>
#include <hip/hip_bf16.h>
#include <math.h>

#define DEV __device__ __forceinline__

constexpr int B  = 8,  N = 16, P = 128, PL = 16;
constexpr int D  = 128, DS = 16, DTR = 8, DFF = 256, EL = 2;
constexpr int L  = N * P + 1;            // 2049
constexpr int BL = B * L;                // 16392
constexpr int CT = 32;                   // scan chunk length
constexpr int NC = (L + CT - 1) / CT;    // 65
constexpr int MT128 = (BL + 127) / 128;  // 129
constexpr int MT64  = (BL + 63) / 64;    // 257
constexpr int KS = 136;                  // LDS row stride (bf16/short units)
constexpr int HS = 264;                  // LDS row stride for H (256+8)

using bf16x8 = __attribute__((ext_vector_type(8))) __bf16;
using f32x4  = __attribute__((ext_vector_type(4))) float;

DEV float sigmoidf_(float x) { return 1.0f / (1.0f + __expf(-x)); }

DEV float wsum(float v) {
#pragma unroll
  for (int m = 32; m; m >>= 1) v += __shfl_xor(v, m, 64);
  return v;
}

// r^(n+1) for n=0..15, depth-4 tree
DEV void pow_tree(float r, float* pw) {
  float r2 = r * r;
  float r3 = r2 * r;
  float r4 = r2 * r2;
  float r8 = r4 * r4;
  float r12 = r8 * r4;
  pw[0] = r;       pw[1] = r2;      pw[2] = r3;      pw[3] = r4;
  pw[4] = r4 * r;  pw[5] = r4 * r2; pw[6] = r4 * r3; pw[7] = r8;
  pw[8] = r8 * r;  pw[9] = r8 * r2; pw[10] = r8 * r3; pw[11] = r12;
  pw[12] = r12 * r; pw[13] = r12 * r2; pw[14] = r12 * r3; pw[15] = r12 * r4;
}

// A_n check: A_init = log(1..16) broadcast -> A_n = -(n+1) exactly.
DEV bool an_is_linear(const float* An) {
  bool ok = true;
#pragma unroll
  for (int n = 0; n < DS; ++n)
    ok = ok && (fabsf(An[n] + (float)(n + 1)) < 1e-3f * (n + 1));
  return ok;
}

// ---------------- weight prep ----------------
__global__ __launch_bounds__(256) void k_prep(
    const float* __restrict__ in_w, const float* __restrict__ conv_w,
    const float* __restrict__ xproj, const float* __restrict__ out_w,
    const float* __restrict__ w1, const float* __restrict__ w2,
    __bf16* __restrict__ weff, __bf16* __restrict__ xpw_bf,
    __bf16* __restrict__ outw_bf, __bf16* __restrict__ w1_bf,
    __bf16* __restrict__ w2_bf)
{
  int g = blockIdx.x * 256 + threadIdx.x;
  if (g < 262144) {
    int l = g >> 17;
    int r = g & 131071;
    int dir = r >> 16;
    int r2 = r & 65535;
    int col = r2 >> 8;
    int kk = r2 & 255;
    int chunk = kk >> 7, k = kk & 127;
    int ld = l * 2 + dir;
    float v;
    if (col < 128) {
      v = in_w[((size_t)ld * 256 + col) * 128 + k] *
          conv_w[((size_t)ld * 128 + col) * 2 + chunk];
    } else {
      v = chunk ? in_w[((size_t)ld * 256 + col) * 128 + k] : 0.f;
    }
    weff[((size_t)ld * 256 + col) * 256 + chunk * 128 + k] = (__bf16)v;
    return;
  }
  g -= 262144;
  if (g < 20480) { xpw_bf[g] = (__bf16)xproj[g]; return; }
  g -= 20480;
  if (g < 65536) {
    int k = g & 127; int q = g >> 7; int n = q & 127; int q2 = q >> 7;
    int dir = q2 & 1; int l = q2 >> 1;
    outw_bf[((size_t)(l * 128 + n)) * 256 + dir * 128 + k] = (__bf16)out_w[g];
    return;
  }
  g -= 65536;
  if (g < 65536) { w1_bf[g] = (__bf16)w1[g]; return; }
  g -= 65536;
  if (g < 65536) { w2_bf[g] = (__bf16)w2[g]; return; }
}

// ---------------- patch embed + view concat -> U (fp32) + Ubf ----------------
__global__ __launch_bounds__(256) void k_embed(
    const float* __restrict__ x, const float* __restrict__ view,
    const float* __restrict__ wp_w, const float* __restrict__ wp_b,
    float* __restrict__ U, __bf16* __restrict__ Ubf)
{
  int g = blockIdx.x * 256 + threadIdx.x;
  if (g >= BL * D) return;
  int d = g & (D - 1);
  int row = g >> 7;
  int b = row / L, t = row % L;
  float acc;
  if (t < N * P) {
    const float* xr = x + ((size_t)b * N * P + t) * PL;
    acc = wp_b[d];
#pragma unroll
    for (int k = 0; k < PL; ++k) acc += xr[k] * wp_w[d * PL + k];
  } else {
    acc = view[b * D + d];
  }
  U[(size_t)row * D + d] = acc;
  Ubf[(size_t)row * D + d] = (__bf16)acc;
}

// ---------------- fused front: xz GEMM + conv + silu + xproj + dt ----------------
// grid (2*MT128, 2): y=0 x-path (128 x-cols, K=256, then xproj+dt inline),
//                    y=1 z-path (128 z-cols, K=128 -> Zbf)
__global__ __launch_bounds__(256) void k_front(
    const __bf16* __restrict__ Ubf, const __bf16* __restrict__ Weff,
    const float* __restrict__ conv_b_l, const __bf16* __restrict__ xpw,
    const float* __restrict__ dt_w_l, const float* __restrict__ dt_b_l,
    __bf16* __restrict__ XCCbf, __bf16* __restrict__ Zbf,
    float* __restrict__ BCb, float* __restrict__ DT)
{
  __shared__ short As[128 * KS];   // 34816 B : U staging -> later xc bf16
  __shared__ short Ws[64 * KS];    // 17408 B : weight staging (64-col halves / xpw)
  __shared__ float dbs[128][9];    //  4608 B
  int bx = blockIdx.x;
  int rdir = bx / MT128;
  int tile = bx % MT128;
  bool isx = (blockIdx.y == 0);
  int tid = threadIdx.x;
  int m0 = tile * 128;
  const __bf16* Wb = Weff + (size_t)rdir * 256 * 256;
  int wave = tid >> 6, lane = tid & 63, lm = lane & 15, lq = lane >> 4;
  f32x4 zero4 = {0.f, 0.f, 0.f, 0.f};
  f32x4 acc[2][8];
#pragma unroll
  for (int r = 0; r < 2; ++r)
#pragma unroll
    for (int c = 0; c < 8; ++c) acc[r][c] = zero4;

  int kc0 = isx ? 0 : 1;
  for (int kc = kc0; kc < 2; ++kc) {
    if (kc != kc0) __syncthreads();
    // stage A (gathered U rows for this k-chunk)
    for (int q = tid; q < 128 * 16; q += 256) {
      int rr = q >> 4, g = q & 15;
      int m = m0 + rr;
      int4 v = make_int4(0, 0, 0, 0);
      if (m < BL) {
        int b = m / L, s = m - b * L;
        bool ok = true;
        int idx;
        if (kc == 0) { ok = (s >= 1); idx = rdir ? (L - s) : (s - 1); }
        else         { idx = rdir ? (L - 1 - s) : s; }
        if (ok) v = *(const int4*)(Ubf + ((size_t)b * L + idx) * 128 + g * 8);
      }
      *(int4*)&As[rr * KS + g * 8] = v;
    }
    for (int ch = 0; ch < 2; ++ch) {
      if (ch) __syncthreads();
      int colbase = (isx ? 0 : 128) + ch * 64;
      for (int q = tid; q < 64 * 16; q += 256) {
        int rr = q >> 4, g = q & 15;
        int4 v = *(const int4*)(Wb + (size_t)(colbase + rr) * 256 + kc * 128 + g * 8);
        *(int4*)&Ws[rr * KS + g * 8] = v;
      }
      __syncthreads();
      for (int ks = 0; ks < 128; ks += 32) {
        bf16x8 af[2];
#pragma unroll
        for (int r = 0; r < 2; ++r)
          af[r] = *(const bf16x8*)&As[(wave * 32 + r * 16 + lm) * KS + ks + lq * 8];
#pragma unroll
        for (int c = 0; c < 4; ++c) {
          bf16x8 bfr = *(const bf16x8*)&Ws[(c * 16 + lm) * KS + ks + lq * 8];
#pragma unroll
          for (int r = 0; r < 2; ++r)
            acc[r][ch * 4 + c] = __builtin_amdgcn_mfma_f32_16x16x32_bf16(af[r], bfr, acc[r][ch * 4 + c], 0, 0, 0);
        }
      }
    }
  }

  if (!isx) {
    // z epilogue
#pragma unroll
    for (int r = 0; r < 2; ++r) {
      int rl = wave * 32 + r * 16 + lq * 4;
#pragma unroll
      for (int cg = 0; cg < 8; ++cg) {
        int col = cg * 16 + lm;
#pragma unroll
        for (int e = 0; e < 4; ++e) {
          int m = m0 + rl + e;
          if (m < BL)
            Zbf[((size_t)rdir * BL + m) * 128 + col] = (__bf16)acc[r][cg][e];
        }
      }
    }
    return;
  }

  // x epilogue: conv bias + silu -> XCCbf global + xc bf16 back into As (wave-private rows)
#pragma unroll
  for (int r = 0; r < 2; ++r) {
    int rl = wave * 32 + r * 16 + lq * 4;
#pragma unroll
    for (int cg = 0; cg < 8; ++cg) {
      int col = cg * 16 + lm;
      float cb = conv_b_l[rdir * 128 + col];
#pragma unroll
      for (int e = 0; e < 4; ++e) {
        int rloc = rl + e;
        int m = m0 + rloc;
        float v = acc[r][cg][e] + cb;
        float o = v * sigmoidf_(v);
        __bf16 ob = (__bf16)o;
        if (m < BL) XCCbf[((size_t)rdir * BL + m) * 128 + col] = ob;
        As[rloc * KS + col] = (short)__builtin_bit_cast(unsigned short, ob);
      }
    }
  }

  // ---- xproj over LDS-resident xc ----
  __syncthreads();
  for (int q = tid; q < 48 * 16; q += 256) {
    int rr = q >> 4, g = q & 15;
    int4 v = make_int4(0, 0, 0, 0);
    if (rr < 40) v = *(const int4*)(xpw + ((size_t)rdir * 40 + rr) * 128 + g * 8);
    *(int4*)&Ws[rr * KS + g * 8] = v;
  }
  __syncthreads();
  f32x4 acc2[2][3];
#pragma unroll
  for (int r = 0; r < 2; ++r)
#pragma unroll
    for (int c = 0; c < 3; ++c) acc2[r][c] = zero4;
  for (int ks = 0; ks < 128; ks += 32) {
    bf16x8 af[2];
#pragma unroll
    for (int r = 0; r < 2; ++r)
      af[r] = *(const bf16x8*)&As[(wave * 32 + r * 16 + lm) * KS + ks + lq * 8];
#pragma unroll
    for (int c = 0; c < 3; ++c) {
      bf16x8 bfr = *(const bf16x8*)&Ws[(c * 16 + lm) * KS + ks + lq * 8];
#pragma unroll
      for (int r = 0; r < 2; ++r)
        acc2[r][c] = __builtin_amdgcn_mfma_f32_16x16x32_bf16(af[r], bfr, acc2[r][c], 0, 0, 0);
    }
  }
#pragma unroll
  for (int r = 0; r < 2; ++r) {
    int rl = wave * 32 + r * 16 + lq * 4;
#pragma unroll
    for (int c = 0; c < 3; ++c) {
      int col = c * 16 + lm;
#pragma unroll
      for (int e = 0; e < 4; ++e) {
        int m = m0 + rl + e;
        float v = acc2[r][c][e];
        if (col < DTR) dbs[rl + e][col] = v;
        else if (col < DTR + 2 * DS && m < BL)
          BCb[((size_t)rdir * BL + m) * 32 + (col - DTR)] = v;
      }
    }
  }
  __syncthreads();
  {
    int dloc = tid & 127;
    int rpar = tid >> 7;
    const float* dw = dt_w_l + ((size_t)rdir * 128 + dloc) * 8;
    float dwr[8];
#pragma unroll
    for (int j = 0; j < 8; ++j) dwr[j] = dw[j];
    float db = dt_b_l[rdir * 128 + dloc];
    for (int rr = rpar; rr < 128; rr += 2) {
      int m = m0 + rr;
      if (m >= BL) break;
      float a = db;
#pragma unroll
      for (int j = 0; j < 8; ++j) a = fmaf(dbs[rr][j], dwr[j], a);
      float dtv = (a > 20.f) ? a : log1pf(__expf(a));
      DT[((size_t)rdir * BL + m) * 128 + dloc] = dtv;
    }
  }
}

// ---------------- scan phase A: LDS-staged inputs ----------------
__global__ __launch_bounds__(128) void k_scanA(
    const float* __restrict__ DT, const __bf16* __restrict__ XCCbf,
    const float* __restrict__ BCb, const float* __restrict__ Alog_l,
    float* __restrict__ HC, float* __restrict__ DTS)
{
  __shared__ float Bs[CT][DS];
  __shared__ float DTs[CT][128];
  __shared__ __bf16 XCs[CT][128];
  int blk = blockIdx.x;
  int c  = blk % NC;
  int rb = blk / NC;
  int rdir = rb / B;
  int d = threadIdx.x;
  int s0 = c * CT;
  int cn = min(CT, L - s0);
  size_t rowbase = (size_t)rb * L + s0;
  for (int q = d; q < cn * DS; q += 128)
    Bs[q >> 4][q & 15] = BCb[(rowbase + (q >> 4)) * 32 + (q & 15)];
  for (int q = d; q < cn * 32; q += 128) {
    int row = q >> 5, c4 = (q & 31) * 4;
    *(float4*)&DTs[row][c4] = *(const float4*)(DT + (rowbase + row) * D + c4);
  }
  for (int q = d; q < cn * 16; q += 128) {
    int row = q >> 4, c8 = (q & 15) * 8;
    *(int4*)&XCs[row][c8] = *(const int4*)(XCCbf + (rowbase + row) * D + c8);
  }
  float An[DS];
  const float* Ab = Alog_l + (size_t)rdir * D * DS + (size_t)d * DS;
#pragma unroll
  for (int n = 0; n < DS; ++n) An[n] = -__expf(Ab[n]);
  bool fast = an_is_linear(An);
  __syncthreads();
  float h[DS];
#pragma unroll
  for (int n = 0; n < DS; ++n) h[n] = 0.f;
  float dts = 0.f;
  if (fast) {
    for (int ss = 0; ss < cn; ++ss) {
      float dt = DTs[ss][d];
      float xc = (float)XCs[ss][d];
      dts += dt;
      float e = dt * xc;
      float pw[DS];
      pow_tree(__expf(-dt), pw);
#pragma unroll
      for (int n = 0; n < DS; ++n)
        h[n] = fmaf(pw[n], h[n], e * Bs[ss][n]);
    }
  } else {
    for (int ss = 0; ss < cn; ++ss) {
      float dt = DTs[ss][d];
      float xc = (float)XCs[ss][d];
      dts += dt;
      float e = dt * xc;
#pragma unroll
      for (int n = 0; n < DS; ++n)
        h[n] = __expf(dt * An[n]) * h[n] + e * Bs[ss][n];
    }
  }
  float* hp = HC + ((size_t)blk * D + d) * DS;
#pragma unroll
  for (int n = 0; n < DS; ++n) hp[n] = h[n];
  DTS[(size_t)blk * D + d] = dts;
}

// ---------------- scan phase B: boundary chain ----------------
__global__ __launch_bounds__(128) void k_scanB(
    const float* __restrict__ HC, const float* __restrict__ DTS,
    const float* __restrict__ Alog_l, float* __restrict__ HIN)
{
  int rb = blockIdx.x;
  int rdir = rb / B;
  int d = threadIdx.x;
  float An[DS];
  const float* Ab = Alog_l + (size_t)rdir * D * DS + (size_t)d * DS;
#pragma unroll
  for (int n = 0; n < DS; ++n) An[n] = -__expf(Ab[n]);
  bool fast = an_is_linear(An);
  float h[DS];
#pragma unroll
  for (int n = 0; n < DS; ++n) h[n] = 0.f;
  size_t i0 = ((size_t)(rb * NC) * D + d) * DS;
  float dts_nx = DTS[(size_t)(rb * NC) * D + d];
  float4 h0 = *(const float4*)(HC + i0);
  float4 h1 = *(const float4*)(HC + i0 + 4);
  float4 h2 = *(const float4*)(HC + i0 + 8);
  float4 h3 = *(const float4*)(HC + i0 + 12);
  for (int c = 0; c < NC; ++c) {
    float* hin = HIN + ((size_t)(rb * NC + c) * D + d) * DS;
    float hc[DS];
    hc[0]=h0.x; hc[1]=h0.y; hc[2]=h0.z; hc[3]=h0.w;
    hc[4]=h1.x; hc[5]=h1.y; hc[6]=h1.z; hc[7]=h1.w;
    hc[8]=h2.x; hc[9]=h2.y; hc[10]=h2.z; hc[11]=h2.w;
    hc[12]=h3.x; hc[13]=h3.y; hc[14]=h3.z; hc[15]=h3.w;
    float dts = dts_nx;
    if (c + 1 < NC) {
      size_t in2 = ((size_t)(rb * NC + c + 1) * D + d) * DS;
      dts_nx = DTS[(size_t)(rb * NC + c + 1) * D + d];
      h0 = *(const float4*)(HC + in2);
      h1 = *(const float4*)(HC + in2 + 4);
      h2 = *(const float4*)(HC + in2 + 8);
      h3 = *(const float4*)(HC + in2 + 12);
    }
#pragma unroll
    for (int n = 0; n < DS; ++n) hin[n] = h[n];
    if (fast) {
      float pw[DS];
      pow_tree(__expf(-dts), pw);
#pragma unroll
      for (int n = 0; n < DS; ++n)
        h[n] = fmaf(pw[n], h[n], hc[n]);
    } else {
#pragma unroll
      for (int n = 0; n < DS; ++n)
        h[n] = __expf(dts * An[n]) * h[n] + hc[n];
    }
  }
}

// ---------------- scan phase C: LDS-staged inputs, emit y bf16 ----------------
__global__ __launch_bounds__(128) void k_scanC(
    const float* __restrict__ DT, const __bf16* __restrict__ XCCbf,
    const float* __restrict__ BCb, const __bf16* __restrict__ Zbf,
    const float* __restrict__ HIN, const float* __restrict__ Alog_l,
    const float* __restrict__ Dp_l, __bf16* __restrict__ YMbf)
{
  __shared__ float Bsm[CT][DS];
  __shared__ float Csm[CT][DS];
  __shared__ float DTs[CT][128];
  __shared__ __bf16 XCs[CT][128];
  __shared__ __bf16 Zs[CT][128];
  int blk = blockIdx.x;
  int c  = blk % NC;
  int rb = blk / NC;
  int rdir = rb / B;
  int b = rb % B;
  int d = threadIdx.x;
  int s0 = c * CT;
  int cn = min(CT, L - s0);
  size_t rowbase = (size_t)rb * L + s0;
  for (int q = d; q < cn * 2 * DS; q += 128) {
    int ss = q >> 5, j = q & 31;
    float vv = BCb[(rowbase + ss) * 32 + j];
    if (j < DS) Bsm[ss][j] = vv; else Csm[ss][j - DS] = vv;
  }
  for (int q = d; q < cn * 32; q += 128) {
    int row = q >> 5, c4 = (q & 31) * 4;
    *(float4*)&DTs[row][c4] = *(const float4*)(DT + (rowbase + row) * D + c4);
  }
  for (int q = d; q < cn * 16; q += 128) {
    int row = q >> 4, c8 = (q & 15) * 8;
    *(int4*)&XCs[row][c8] = *(const int4*)(XCCbf + (rowbase + row) * D + c8);
    *(int4*)&Zs[row][c8]  = *(const int4*)(Zbf + (rowbase + row) * D + c8);
  }
  float An[DS];
  const float* Ab = Alog_l + (size_t)rdir * D * DS + (size_t)d * DS;
#pragma unroll
  for (int n = 0; n < DS; ++n) An[n] = -__expf(Ab[n]);
  bool fast = an_is_linear(An);
  float h[DS];
  const float* hin = HIN + ((size_t)blk * D + d) * DS;
#pragma unroll
  for (int n = 0; n < DS; ++n) h[n] = hin[n];
  float Dpv = Dp_l[rdir * D + d];
  __syncthreads();
  if (fast) {
    for (int ss = 0; ss < cn; ++ss) {
      float dt = DTs[ss][d];
      float xc = (float)XCs[ss][d];
      float z  = (float)Zs[ss][d];
      float e = dt * xc;
      float pw[DS];
      pow_tree(__expf(-dt), pw);
      float y = xc * Dpv;
#pragma unroll
      for (int n = 0; n < DS; ++n) {
        h[n] = fmaf(pw[n], h[n], e * Bsm[ss][n]);
        y = fmaf(h[n], Csm[ss][n], y);
      }
      y *= z * sigmoidf_(z);
      int s = s0 + ss;
      int tt = rdir ? (L - 1 - s) : s;
      YMbf[((size_t)b * L + tt) * 256 + rdir * 128 + d] = (__bf16)y;
    }
  } else {
    for (int ss = 0; ss < cn; ++ss) {
      float dt = DTs[ss][d];
      float xc = (float)XCs[ss][d];
      float z  = (float)Zs[ss][d];
      float e = dt * xc;
      float y = xc * Dpv;
#pragma unroll
      for (int n = 0; n < DS; ++n) {
        h[n] = __expf(dt * An[n]) * h[n] + e * Bsm[ss][n];
        y = fmaf(h[n], Csm[ss][n], y);
      }
      y *= z * sigmoidf_(z);
      int s = s0 + ss;
      int tt = rdir ? (L - 1 - s) : s;
      YMbf[((size_t)b * L + tt) * 256 + rdir * 128 + d] = (__bf16)y;
    }
  }
}

// ---------------- fused tail: outproj + LN1 + FFN1 + FFN2 + LN2 (+ final LN/out on last) ----------------
__global__ __launch_bounds__(256) void k_tail(
    const __bf16* __restrict__ YMbf, const __bf16* __restrict__ Wout,
    const float* __restrict__ g1, const float* __restrict__ be1,
    const __bf16* __restrict__ w1bf, const float* __restrict__ b1,
    const __bf16* __restrict__ w2bf, const float* __restrict__ b2,
    const float* __restrict__ g2, const float* __restrict__ be2,
    float* __restrict__ U, __bf16* __restrict__ Ubf,
    int last, const float* __restrict__ lnfg, const float* __restrict__ lnfb,
    float* __restrict__ outp)
{
  __shared__ short AX[64 * KS];
  __shared__ short BH[128 * KS];
  __shared__ short Ws[64 * KS];
  int m0 = blockIdx.x * 64;
  int tid = threadIdx.x;
  int wave = tid >> 6, lane = tid & 63, lm = lane & 15, lq = lane >> 4;
  f32x4 zero4 = {0.f, 0.f, 0.f, 0.f};

  // ---- phase 1: outproj (K=256) ----
  f32x4 acc[8];
#pragma unroll
  for (int c = 0; c < 8; ++c) acc[c] = zero4;
  for (int kc = 0; kc < 2; ++kc) {
    if (kc) __syncthreads();
    for (int q = tid; q < 64 * 16; q += 256) {
      int rr = q >> 4, g = q & 15;
      int m = m0 + rr;
      int4 v = make_int4(0, 0, 0, 0);
      if (m < BL) v = *(const int4*)(YMbf + (size_t)m * 256 + kc * 128 + g * 8);
      *(int4*)&AX[rr * KS + g * 8] = v;
    }
    for (int q = tid; q < 128 * 16; q += 256) {
      int rr = q >> 4, g = q & 15;
      int4 v = *(const int4*)(Wout + (size_t)rr * 256 + kc * 128 + g * 8);
      *(int4*)&BH[rr * KS + g * 8] = v;
    }
    __syncthreads();
    for (int ks = 0; ks < 128; ks += 32) {
      bf16x8 af = *(const bf16x8*)&AX[(wave * 16 + lm) * KS + ks + lq * 8];
#pragma unroll
      for (int c = 0; c < 8; ++c) {
        bf16x8 bfr = *(const bf16x8*)&BH[(c * 16 + lm) * KS + ks + lq * 8];
        acc[c] = __builtin_amdgcn_mfma_f32_16x16x32_bf16(af, bfr, acc[c], 0, 0, 0);
      }
    }
  }
  __syncthreads();

  // ---- phase 2: residual + LN1 -> XRbf in AX ----
  {
    float g1c[8], be1c[8];
#pragma unroll
    for (int c = 0; c < 8; ++c) {
      int col = c * 16 + lm;
      g1c[c] = g1[col]; be1c[c] = be1[col];
    }
#pragma unroll
    for (int r = 0; r < 4; ++r) {
      int row = m0 + wave * 16 + lq * 4 + r;
      bool valid = row < BL;
      float os[8];
      float sum = 0.f;
#pragma unroll
      for (int c = 0; c < 8; ++c) {
        int col = c * 16 + lm;
        float uv = valid ? U[(size_t)row * 128 + col] : 0.f;
        os[c] = acc[c][r] + uv;
        sum += os[c];
      }
#pragma unroll
      for (int mm = 1; mm < 16; mm <<= 1) sum += __shfl_xor(sum, mm, 64);
      float mean = sum * (1.f / 128.f);
      float qv = 0.f;
#pragma unroll
      for (int c = 0; c < 8; ++c) { float dv = os[c] - mean; qv += dv * dv; }
#pragma unroll
      for (int mm = 1; mm < 16; mm <<= 1) qv += __shfl_xor(qv, mm, 64);
      float inv = rsqrtf(qv * (1.f / 128.f) + 1e-5f);
      int rl = wave * 16 + lq * 4 + r;
#pragma unroll
      for (int c = 0; c < 8; ++c) {
        int col = c * 16 + lm;
        float o = (os[c] - mean) * inv * g1c[c] + be1c[c];
        AX[rl * KS + col] = (short)__builtin_bit_cast(unsigned short, (__bf16)o);
      }
    }
  }

  // ---- phase 3: FFN1 (K=128), H -> BH ----
  for (int cc = 0; cc < 4; ++cc) {
    __syncthreads();
    for (int q = tid; q < 64 * 16; q += 256) {
      int rr = q >> 4, g = q & 15;
      int4 v = *(const int4*)(w1bf + (size_t)(cc * 64 + rr) * 128 + g * 8);
      *(int4*)&Ws[rr * KS + g * 8] = v;
    }
    __syncthreads();
    f32x4 a1[4];
#pragma unroll
    for (int c = 0; c < 4; ++c) a1[c] = zero4;
    for (int ks = 0; ks < 128; ks += 32) {
      bf16x8 af = *(const bf16x8*)&AX[(wave * 16 + lm) * KS + ks + lq * 8];
#pragma unroll
      for (int c = 0; c < 4; ++c) {
        bf16x8 bfr = *(const bf16x8*)&Ws[(c * 16 + lm) * KS + ks + lq * 8];
        a1[c] = __builtin_amdgcn_mfma_f32_16x16x32_bf16(af, bfr, a1[c], 0, 0, 0);
      }
    }
#pragma unroll
    for (int c = 0; c < 4; ++c) {
      int col = cc * 64 + c * 16 + lm;
      float bb = b1[col];
#pragma unroll
      for (int e = 0; e < 4; ++e) {
        int rl = wave * 16 + lq * 4 + e;
        float hv = fmaxf(a1[c][e] + bb, 0.f);
        BH[rl * HS + col] = (short)__builtin_bit_cast(unsigned short, (__bf16)hv);
      }
    }
  }

  // ---- phase 4: FFN2 (K=256) + residual + LN2 (+ lnf/out on last) ----
  f32x4 a2[2][4];
#pragma unroll
  for (int nc = 0; nc < 2; ++nc)
#pragma unroll
    for (int c = 0; c < 4; ++c) a2[nc][c] = zero4;
  for (int nc = 0; nc < 2; ++nc) {
    for (int kc = 0; kc < 2; ++kc) {
      __syncthreads();
      for (int q = tid; q < 64 * 16; q += 256) {
        int rr = q >> 4, g = q & 15;
        int4 v = *(const int4*)(w2bf + (size_t)(nc * 64 + rr) * 256 + kc * 128 + g * 8);
        *(int4*)&Ws[rr * KS + g * 8] = v;
      }
      __syncthreads();
      for (int ks = 0; ks < 128; ks += 32) {
        bf16x8 af = *(const bf16x8*)&BH[(wave * 16 + lm) * HS + kc * 128 + ks + lq * 8];
#pragma unroll
        for (int c = 0; c < 4; ++c) {
          bf16x8 bfr = *(const bf16x8*)&Ws[(c * 16 + lm) * KS + ks + lq * 8];
          a2[nc][c] = __builtin_amdgcn_mfma_f32_16x16x32_bf16(af, bfr, a2[nc][c], 0, 0, 0);
        }
      }
    }
  }
  {
    float b2c[8], g2c[8], be2c[8];
#pragma unroll
    for (int q = 0; q < 8; ++q) {
      int col = (q >> 2) * 64 + (q & 3) * 16 + lm;
      b2c[q] = b2[col]; g2c[q] = g2[col]; be2c[q] = be2[col];
    }
#pragma unroll
    for (int r = 0; r < 4; ++r) {
      int rl = wave * 16 + lq * 4 + r;
      int row = m0 + rl;
      bool valid = row < BL;
      float os[8];
      float sum = 0.f;
#pragma unroll
      for (int q = 0; q < 8; ++q) {
        int nc = q >> 2, c = q & 3;
        int col = nc * 64 + c * 16 + lm;
        __bf16 xb = __builtin_bit_cast(__bf16, (unsigned short)AX[rl * KS + col]);
        os[q] = a2[nc][c][r] + b2c[q] + (float)xb;
        sum += os[q];
      }
#pragma unroll
      for (int mm = 1; mm < 16; mm <<= 1) sum += __shfl_xor(sum, mm, 64);
      float mean = sum * (1.f / 128.f);
      float qv = 0.f;
#pragma unroll
      for (int q = 0; q < 8; ++q) { float dv = os[q] - mean; qv += dv * dv; }
#pragma unroll
      for (int mm = 1; mm < 16; mm <<= 1) qv += __shfl_xor(qv, mm, 64);
      float inv = rsqrtf(qv * (1.f / 128.f) + 1e-5f);
      float o[8];
#pragma unroll
      for (int q = 0; q < 8; ++q)
        o[q] = (os[q] - mean) * inv * g2c[q] + be2c[q];
      if (!last) {
        if (valid) {
#pragma unroll
          for (int q = 0; q < 8; ++q) {
            int col = (q >> 2) * 64 + (q & 3) * 16 + lm;
            U[(size_t)row * 128 + col] = o[q];
            Ubf[(size_t)row * 128 + col] = (__bf16)o[q];
          }
        }
      } else {
        // final LN + slice + transpose, fused
        float s2 = 0.f;
#pragma unroll
        for (int q = 0; q < 8; ++q) s2 += o[q];
#pragma unroll
        for (int mm = 1; mm < 16; mm <<= 1) s2 += __shfl_xor(s2, mm, 64);
        float mean2 = s2 * (1.f / 128.f);
        float qv2 = 0.f;
#pragma unroll
        for (int q = 0; q < 8; ++q) { float dv = o[q] - mean2; qv2 += dv * dv; }
#pragma unroll
        for (int mm = 1; mm < 16; mm <<= 1) qv2 += __shfl_xor(qv2, mm, 64);
        float inv2 = rsqrtf(qv2 * (1.f / 128.f) + 1e-5f);
        if (valid) {
          int bb = row / L;
          int t = row - bb * L;
          if (t < N * P) {
            int n = t >> 7, p = t & 127;
            size_t obase = (((size_t)bb * N + n) * D) * P + p;
#pragma unroll
            for (int q = 0; q < 8; ++q) {
              int col = (q >> 2) * 64 + (q & 3) * 16 + lm;
              float o2 = (o[q] - mean2) * inv2 * lnfg[col] + lnfb[col];
              outp[obase + (size_t)col * P] = o2;
            }
          }
        }
      }
    }
  }
}

extern "C" void kernel_launch(void* const* d_in, const int* in_sizes, int n_in,
                              void* d_out, int out_size, void* d_ws, size_t ws_size,
                              hipStream_t stream)
{
  (void)in_sizes; (void)n_in; (void)out_size; (void)ws_size;
  const float* x       = (const float*)d_in[0];
  const float* view    = (const float*)d_in[1];
  const float* wp_w    = (const float*)d_in[2];
  const float* wp_b    = (const float*)d_in[3];
  const float* m_in_w  = (const float*)d_in[4];
  const float* m_conv_w= (const float*)d_in[5];
  const float* m_conv_b= (const float*)d_in[6];
  const float* m_xproj = (const float*)d_in[7];
  const float* m_dt_w  = (const float*)d_in[8];
  const float* m_dt_b  = (const float*)d_in[9];
  const float* m_Alog  = (const float*)d_in[10];
  const float* m_Dp    = (const float*)d_in[11];
  const float* m_out_w = (const float*)d_in[12];
  const float* ffn_w1  = (const float*)d_in[13];
  const float* ffn_b1  = (const float*)d_in[14];
  const float* ffn_w2  = (const float*)d_in[15];
  const float* ffn_b2  = (const float*)d_in[16];
  const float* ln1_g   = (const float*)d_in[17];
  const float* ln1_b   = (const float*)d_in[18];
  const float* ln2_g   = (const float*)d_in[19];
  const float* ln2_b   = (const float*)d_in[20];
  const float* lnf_g   = (const float*)d_in[21];
  const float* lnf_b   = (const float*)d_in[22];
  float* out = (float*)d_out;

  float* W = (float*)d_ws;
  size_t off = 0;
  auto alloc = [&](size_t nfl) { float* p = W + off; off += (nfl + 3) & ~(size_t)3; return p; };
  float* U      = alloc((size_t)BL * D);
  float* Ubf_f  = alloc((size_t)BL * D / 2);
  float* XCC_f  = alloc((size_t)BL * D);          // 2*BL*D bf16
  float* Zbf_f  = alloc((size_t)BL * D);          // 2*BL*D bf16
  float* DTb    = alloc((size_t)2 * BL * D);
  float* BCb    = alloc((size_t)2 * BL * 2 * DS);
  float* YM_f   = alloc((size_t)BL * 256 / 2);
  float* HC     = alloc((size_t)2 * B * NC * D * DS);
  float* DTS    = alloc((size_t)2 * B * NC * D);
  float* HIN    = alloc((size_t)2 * B * NC * D * DS);
  float* weff_f = alloc(262144 / 2);
  float* xpw_f  = alloc(20480 / 2);
  float* outw_f = alloc(65536 / 2);
  float* w1_f   = alloc(65536 / 2);
  float* w2_f   = alloc(65536 / 2);

  __bf16* Ubf    = (__bf16*)Ubf_f;
  __bf16* XCCbf  = (__bf16*)XCC_f;
  __bf16* Zbf    = (__bf16*)Zbf_f;
  __bf16* YMbf   = (__bf16*)YM_f;
  __bf16* weff   = (__bf16*)weff_f;
  __bf16* xpw_bf = (__bf16*)xpw_f;
  __bf16* outw_bf= (__bf16*)outw_f;
  __bf16* w1_bf  = (__bf16*)w1_f;
  __bf16* w2_bf  = (__bf16*)w2_f;

  k_prep<<<1872, 256, 0, stream>>>(m_in_w, m_conv_w, m_xproj, m_out_w, ffn_w1, ffn_w2,
                                   weff, xpw_bf, outw_bf, w1_bf, w2_bf);
  k_embed<<<(BL * D + 255) / 256, 256, 0, stream>>>(x, view, wp_w, wp_b, U, Ubf);

  for (int l = 0; l < EL; ++l) {
    const float* conv_b_l = m_conv_b + (size_t)l * 2 * D;
    const float* dt_w_l   = m_dt_w   + (size_t)l * 2 * D * DTR;
    const float* dt_b_l   = m_dt_b   + (size_t)l * 2 * D;
    const float* Alog_l   = m_Alog   + (size_t)l * 2 * D * DS;
    const float* Dp_l     = m_Dp     + (size_t)l * 2 * D;

    k_front <<<dim3(2 * MT128, 2), 256, 0, stream>>>(
        Ubf, weff + (size_t)l * 2 * 256 * 256, conv_b_l,
        xpw_bf + (size_t)l * 2 * 40 * 128, dt_w_l, dt_b_l,
        XCCbf, Zbf, BCb, DTb);
    k_scanA <<<2 * B * NC, 128, 0, stream>>>(DTb, XCCbf, BCb, Alog_l, HC, DTS);
    k_scanB <<<2 * B, 128, 0, stream>>>(HC, DTS, Alog_l, HIN);
    k_scanC <<<2 * B * NC, 128, 0, stream>>>(DTb, XCCbf, BCb, Zbf, HIN, Alog_l, Dp_l, YMbf);
    k_tail  <<<MT64, 256, 0, stream>>>(
        YMbf, outw_bf + (size_t)l * 128 * 256,
        ln1_g + l * D, ln1_b + l * D,
        w1_bf + (size_t)l * 256 * 128, ffn_b1 + l * DFF,
        w2_bf + (size_t)l * 128 * 256, ffn_b2 + l * D,
        ln2_g + l * D, ln2_b + l * D, U, Ubf,
        (l == EL - 1) ? 1 : 0, lnf_g, lnf_b, out);
  }
}

// Round 10
// 410.238 us; speedup vs baseline: 2.4633x; 1.0066x over previous
//
#include <hip/hip_runtime.h>
#include <hip/hip_bf16.h>
#include <math.h>

#define DEV __device__ __forceinline__

constexpr int B  = 8,  N = 16, P = 128, PL = 16;
constexpr int D  = 128, DS = 16, DTR = 8, DFF = 256, EL = 2;
constexpr int L  = N * P + 1;            // 2049
constexpr int BL = B * L;                // 16392
constexpr int CT = 32;                   // scan chunk length
constexpr int NC = (L + CT - 1) / CT;    // 65
constexpr int MT128 = (BL + 127) / 128;  // 129
constexpr int MT64  = (BL + 63) / 64;    // 257
constexpr int KS = 136;                  // LDS row stride (bf16/short units)
constexpr int HS = 264;                  // LDS row stride for H (256+8)

using bf16x8 = __attribute__((ext_vector_type(8))) __bf16;
using f32x4  = __attribute__((ext_vector_type(4))) float;

DEV float sigmoidf_(float x) { return 1.0f / (1.0f + __expf(-x)); }

DEV float wsum(float v) {
#pragma unroll
  for (int m = 32; m; m >>= 1) v += __shfl_xor(v, m, 64);
  return v;
}

// r^(n+1) for n=0..15, depth-4 tree
DEV void pow_tree(float r, float* pw) {
  float r2 = r * r;
  float r3 = r2 * r;
  float r4 = r2 * r2;
  float r8 = r4 * r4;
  float r12 = r8 * r4;
  pw[0] = r;       pw[1] = r2;      pw[2] = r3;      pw[3] = r4;
  pw[4] = r4 * r;  pw[5] = r4 * r2; pw[6] = r4 * r3; pw[7] = r8;
  pw[8] = r8 * r;  pw[9] = r8 * r2; pw[10] = r8 * r3; pw[11] = r12;
  pw[12] = r12 * r; pw[13] = r12 * r2; pw[14] = r12 * r3; pw[15] = r12 * r4;
}

// A_n check: A_init = log(1..16) broadcast -> A_n = -(n+1) exactly.
DEV bool an_is_linear(const float* An) {
  bool ok = true;
#pragma unroll
  for (int n = 0; n < DS; ++n)
    ok = ok && (fabsf(An[n] + (float)(n + 1)) < 1e-3f * (n + 1));
  return ok;
}

// ---------------- weight prep ----------------
__global__ __launch_bounds__(256) void k_prep(
    const float* __restrict__ in_w, const float* __restrict__ conv_w,
    const float* __restrict__ xproj, const float* __restrict__ out_w,
    const float* __restrict__ w1, const float* __restrict__ w2,
    __bf16* __restrict__ weff, __bf16* __restrict__ xpw_bf,
    __bf16* __restrict__ outw_bf, __bf16* __restrict__ w1_bf,
    __bf16* __restrict__ w2_bf)
{
  int g = blockIdx.x * 256 + threadIdx.x;
  if (g < 262144) {
    int l = g >> 17;
    int r = g & 131071;
    int dir = r >> 16;
    int r2 = r & 65535;
    int col = r2 >> 8;
    int kk = r2 & 255;
    int chunk = kk >> 7, k = kk & 127;
    int ld = l * 2 + dir;
    float v;
    if (col < 128) {
      v = in_w[((size_t)ld * 256 + col) * 128 + k] *
          conv_w[((size_t)ld * 128 + col) * 2 + chunk];
    } else {
      v = chunk ? in_w[((size_t)ld * 256 + col) * 128 + k] : 0.f;
    }
    weff[((size_t)ld * 256 + col) * 256 + chunk * 128 + k] = (__bf16)v;
    return;
  }
  g -= 262144;
  if (g < 20480) { xpw_bf[g] = (__bf16)xproj[g]; return; }
  g -= 20480;
  if (g < 65536) {
    int k = g & 127; int q = g >> 7; int n = q & 127; int q2 = q >> 7;
    int dir = q2 & 1; int l = q2 >> 1;
    outw_bf[((size_t)(l * 128 + n)) * 256 + dir * 128 + k] = (__bf16)out_w[g];
    return;
  }
  g -= 65536;
  if (g < 65536) { w1_bf[g] = (__bf16)w1[g]; return; }
  g -= 65536;
  if (g < 65536) { w2_bf[g] = (__bf16)w2[g]; return; }
}

// ---------------- patch embed + view concat -> U (fp32) + Ubf ----------------
__global__ __launch_bounds__(256) void k_embed(
    const float* __restrict__ x, const float* __restrict__ view,
    const float* __restrict__ wp_w, const float* __restrict__ wp_b,
    float* __restrict__ U, __bf16* __restrict__ Ubf)
{
  int g = blockIdx.x * 256 + threadIdx.x;
  if (g >= BL * D) return;
  int d = g & (D - 1);
  int row = g >> 7;
  int b = row / L, t = row % L;
  float acc;
  if (t < N * P) {
    const float* xr = x + ((size_t)b * N * P + t) * PL;
    acc = wp_b[d];
#pragma unroll
    for (int k = 0; k < PL; ++k) acc += xr[k] * wp_w[d * PL + k];
  } else {
    acc = view[b * D + d];
  }
  U[(size_t)row * D + d] = acc;
  Ubf[(size_t)row * D + d] = (__bf16)acc;
}

// ---------------- fused front: xz GEMM + conv + silu + xproj + dt ----------------
// grid (2*MT128, 2): y=0 x-path (128 x-cols, K=256, then xproj+dt inline),
//                    y=1 z-path (128 z-cols, K=128 -> Zbf)
// W staging double-buffered with register prefetch; A-gather rows precomputed once.
__global__ __launch_bounds__(256) void k_front(
    const __bf16* __restrict__ Ubf, const __bf16* __restrict__ Weff,
    const float* __restrict__ conv_b_l, const __bf16* __restrict__ xpw,
    const float* __restrict__ dt_w_l, const float* __restrict__ dt_b_l,
    __bf16* __restrict__ XCCbf, __bf16* __restrict__ Zbf,
    float* __restrict__ BCb, __bf16* __restrict__ DTbf)
{
  __shared__ short As[128 * KS];       // 34816 B : U staging -> later xc bf16
  __shared__ short Ws[2][64 * KS];     // 2 x 17408 B, double-buffered weights
  float (*dbs)[9] = (float(*)[9])&Ws[1][0];   // aliases Ws[1] after last MFMA
  int bx = blockIdx.x;
  int rdir = bx / MT128;
  int tile = bx % MT128;
  bool isx = (blockIdx.y == 0);
  int tid = threadIdx.x;
  int m0 = tile * 128;
  const __bf16* Wb = Weff + (size_t)rdir * 256 * 256;
  int wave = tid >> 6, lane = tid & 63, lm = lane & 15, lq = lane >> 4;
  int rr0 = tid >> 4, gcol = tid & 15;

  // per-thread A-row precompute (8 rows, one 16B column-group each)
  int aoff[8];
  unsigned vmask = 0, smask = 0;
  int shif = rdir ? 128 : -128;     // element delta for kc=0 (shifted row)
#pragma unroll
  for (int i = 0; i < 8; ++i) {
    int rr = rr0 + 16 * i;
    int m = m0 + rr;
    aoff[i] = 0;
    if (m < BL) {
      int b = m / L, s = m - b * L;
      int idx1 = rdir ? (L - 1 - s) : s;
      aoff[i] = (b * L + idx1) * 128 + gcol * 8;
      vmask |= 1u << i;
      if (s >= 1) smask |= 1u << i;
    }
  }

  f32x4 zero4 = {0.f, 0.f, 0.f, 0.f};
  f32x4 acc[2][8];
#pragma unroll
  for (int r = 0; r < 2; ++r)
#pragma unroll
    for (int c = 0; c < 8; ++c) acc[r][c] = zero4;

  int4 wreg[4];
  auto loadW = [&](int colbase, int kc) {
#pragma unroll
    for (int i = 0; i < 4; ++i) {
      int rr = rr0 + 16 * i;
      wreg[i] = *(const int4*)(Wb + (size_t)(colbase + rr) * 256 + kc * 128 + gcol * 8);
    }
  };
  auto storeW = [&](int buf) {
#pragma unroll
    for (int i = 0; i < 4; ++i) {
      int rr = rr0 + 16 * i;
      *(int4*)&Ws[buf][rr * KS + gcol * 8] = wreg[i];
    }
  };

  int kc0 = isx ? 0 : 1;
  int colx = isx ? 0 : 128;
  loadW(colx, kc0);
  for (int kc = kc0; kc < 2; ++kc) {
    if (kc != kc0) __syncthreads();
    // stage A
#pragma unroll
    for (int i = 0; i < 8; ++i) {
      int rr = rr0 + 16 * i;
      int4 v = make_int4(0, 0, 0, 0);
      bool ok = (vmask >> i) & 1;
      if (kc == 0) ok = ok && ((smask >> i) & 1);
      if (ok) v = *(const int4*)(Ubf + aoff[i] + (kc == 0 ? shif : 0));
      *(int4*)&As[rr * KS + gcol * 8] = v;
    }
    for (int ch = 0; ch < 2; ++ch) {
      storeW(ch);
      if (ch == 0) loadW(colx + 64, kc);        // prefetch other half
      else if (kc == 0) loadW(colx, 1);          // prefetch next kc's first half
      __syncthreads();
      for (int ks = 0; ks < 128; ks += 32) {
        bf16x8 af[2];
#pragma unroll
        for (int r = 0; r < 2; ++r)
          af[r] = *(const bf16x8*)&As[(wave * 32 + r * 16 + lm) * KS + ks + lq * 8];
#pragma unroll
        for (int c = 0; c < 4; ++c) {
          bf16x8 bfr = *(const bf16x8*)&Ws[ch][(c * 16 + lm) * KS + ks + lq * 8];
#pragma unroll
          for (int r = 0; r < 2; ++r)
            acc[r][ch * 4 + c] = __builtin_amdgcn_mfma_f32_16x16x32_bf16(af[r], bfr, acc[r][ch * 4 + c], 0, 0, 0);
        }
      }
    }
  }

  if (!isx) {
    // z epilogue
#pragma unroll
    for (int r = 0; r < 2; ++r) {
      int rl = wave * 32 + r * 16 + lq * 4;
#pragma unroll
      for (int cg = 0; cg < 8; ++cg) {
        int col = cg * 16 + lm;
#pragma unroll
        for (int e = 0; e < 4; ++e) {
          int m = m0 + rl + e;
          if (m < BL)
            Zbf[((size_t)rdir * BL + m) * 128 + col] = (__bf16)acc[r][cg][e];
        }
      }
    }
    return;
  }

  // x epilogue: conv bias + silu -> XCCbf global + xc bf16 back into As (wave-private rows)
#pragma unroll
  for (int r = 0; r < 2; ++r) {
    int rl = wave * 32 + r * 16 + lq * 4;
#pragma unroll
    for (int cg = 0; cg < 8; ++cg) {
      int col = cg * 16 + lm;
      float cb = conv_b_l[rdir * 128 + col];
#pragma unroll
      for (int e = 0; e < 4; ++e) {
        int rloc = rl + e;
        int m = m0 + rloc;
        float v = acc[r][cg][e] + cb;
        float o = v * sigmoidf_(v);
        __bf16 ob = (__bf16)o;
        if (m < BL) XCCbf[((size_t)rdir * BL + m) * 128 + col] = ob;
        As[rloc * KS + col] = (short)__builtin_bit_cast(unsigned short, ob);
      }
    }
  }

  // ---- xproj over LDS-resident xc ----
  // Ws[0] is safe to write (last read at kc=1 ch=0, all waves past the pre-ch1 barrier)
#pragma unroll
  for (int i = 0; i < 3; ++i) {
    int rr = rr0 + 16 * i;
    int4 v = make_int4(0, 0, 0, 0);
    if (rr < 40) v = *(const int4*)(xpw + ((size_t)rdir * 40 + rr) * 128 + gcol * 8);
    *(int4*)&Ws[0][rr * KS + gcol * 8] = v;
  }
  __syncthreads();
  f32x4 acc2[2][3];
#pragma unroll
  for (int r = 0; r < 2; ++r)
#pragma unroll
    for (int c = 0; c < 3; ++c) acc2[r][c] = zero4;
  for (int ks = 0; ks < 128; ks += 32) {
    bf16x8 af[2];
#pragma unroll
    for (int r = 0; r < 2; ++r)
      af[r] = *(const bf16x8*)&As[(wave * 32 + r * 16 + lm) * KS + ks + lq * 8];
#pragma unroll
    for (int c = 0; c < 3; ++c) {
      bf16x8 bfr = *(const bf16x8*)&Ws[0][(c * 16 + lm) * KS + ks + lq * 8];
#pragma unroll
      for (int r = 0; r < 2; ++r)
        acc2[r][c] = __builtin_amdgcn_mfma_f32_16x16x32_bf16(af[r], bfr, acc2[r][c], 0, 0, 0);
    }
  }
  // dbs aliases Ws[1]: all waves are past the last Ws[1] read (barrier above)
#pragma unroll
  for (int r = 0; r < 2; ++r) {
    int rl = wave * 32 + r * 16 + lq * 4;
#pragma unroll
    for (int c = 0; c < 3; ++c) {
      int col = c * 16 + lm;
#pragma unroll
      for (int e = 0; e < 4; ++e) {
        int m = m0 + rl + e;
        float v = acc2[r][c][e];
        if (col < DTR) dbs[rl + e][col] = v;
        else if (col < DTR + 2 * DS && m < BL)
          BCb[((size_t)rdir * BL + m) * 32 + (col - DTR)] = v;
      }
    }
  }
  __syncthreads();
  {
    int dloc = tid & 127;
    int rpar = tid >> 7;
    const float* dw = dt_w_l + ((size_t)rdir * 128 + dloc) * 8;
    float dwr[8];
#pragma unroll
    for (int j = 0; j < 8; ++j) dwr[j] = dw[j];
    float db = dt_b_l[rdir * 128 + dloc];
    for (int rr = rpar; rr < 128; rr += 2) {
      int m = m0 + rr;
      if (m >= BL) break;
      float a = db;
#pragma unroll
      for (int j = 0; j < 8; ++j) a = fmaf(dbs[rr][j], dwr[j], a);
      float dtv = (a > 20.f) ? a : log1pf(__expf(a));
      DTbf[((size_t)rdir * BL + m) * 128 + dloc] = (__bf16)dtv;
    }
  }
}

// ---------------- scan phase A: LDS-staged inputs (bf16 DT) ----------------
__global__ __launch_bounds__(128) void k_scanA(
    const __bf16* __restrict__ DTbf, const __bf16* __restrict__ XCCbf,
    const float* __restrict__ BCb, const float* __restrict__ Alog_l,
    float* __restrict__ HC, float* __restrict__ DTS)
{
  __shared__ float Bs[CT][DS];     // 2 KB
  __shared__ __bf16 DTs[CT][128];  // 8 KB
  __shared__ __bf16 XCs[CT][128];  // 8 KB
  int blk = blockIdx.x;
  int c  = blk % NC;
  int rb = blk / NC;
  int rdir = rb / B;
  int d = threadIdx.x;
  int s0 = c * CT;
  int cn = min(CT, L - s0);
  size_t rowbase = (size_t)rb * L + s0;
  for (int q = d; q < cn * DS; q += 128)
    Bs[q >> 4][q & 15] = BCb[(rowbase + (q >> 4)) * 32 + (q & 15)];
  for (int q = d; q < cn * 16; q += 128) {
    int row = q >> 4, c8 = (q & 15) * 8;
    *(int4*)&DTs[row][c8] = *(const int4*)(DTbf + (rowbase + row) * D + c8);
    *(int4*)&XCs[row][c8] = *(const int4*)(XCCbf + (rowbase + row) * D + c8);
  }
  float An[DS];
  const float* Ab = Alog_l + (size_t)rdir * D * DS + (size_t)d * DS;
#pragma unroll
  for (int n = 0; n < DS; ++n) An[n] = -__expf(Ab[n]);
  bool fast = an_is_linear(An);
  __syncthreads();
  float h[DS];
#pragma unroll
  for (int n = 0; n < DS; ++n) h[n] = 0.f;
  float dts = 0.f;
  if (fast) {
    for (int ss = 0; ss < cn; ++ss) {
      float dt = (float)DTs[ss][d];
      float xc = (float)XCs[ss][d];
      dts += dt;
      float e = dt * xc;
      float pw[DS];
      pow_tree(__expf(-dt), pw);
#pragma unroll
      for (int n = 0; n < DS; ++n)
        h[n] = fmaf(pw[n], h[n], e * Bs[ss][n]);
    }
  } else {
    for (int ss = 0; ss < cn; ++ss) {
      float dt = (float)DTs[ss][d];
      float xc = (float)XCs[ss][d];
      dts += dt;
      float e = dt * xc;
#pragma unroll
      for (int n = 0; n < DS; ++n)
        h[n] = __expf(dt * An[n]) * h[n] + e * Bs[ss][n];
    }
  }
  float* hp = HC + ((size_t)blk * D + d) * DS;
#pragma unroll
  for (int n = 0; n < DS; ++n) hp[n] = h[n];
  DTS[(size_t)blk * D + d] = dts;
}

// ---------------- scan phase B: boundary chain ----------------
__global__ __launch_bounds__(128) void k_scanB(
    const float* __restrict__ HC, const float* __restrict__ DTS,
    const float* __restrict__ Alog_l, float* __restrict__ HIN)
{
  int rb = blockIdx.x;
  int rdir = rb / B;
  int d = threadIdx.x;
  float An[DS];
  const float* Ab = Alog_l + (size_t)rdir * D * DS + (size_t)d * DS;
#pragma unroll
  for (int n = 0; n < DS; ++n) An[n] = -__expf(Ab[n]);
  bool fast = an_is_linear(An);
  float h[DS];
#pragma unroll
  for (int n = 0; n < DS; ++n) h[n] = 0.f;
  size_t i0 = ((size_t)(rb * NC) * D + d) * DS;
  float dts_nx = DTS[(size_t)(rb * NC) * D + d];
  float4 h0 = *(const float4*)(HC + i0);
  float4 h1 = *(const float4*)(HC + i0 + 4);
  float4 h2 = *(const float4*)(HC + i0 + 8);
  float4 h3 = *(const float4*)(HC + i0 + 12);
  for (int c = 0; c < NC; ++c) {
    float* hin = HIN + ((size_t)(rb * NC + c) * D + d) * DS;
    float hc[DS];
    hc[0]=h0.x; hc[1]=h0.y; hc[2]=h0.z; hc[3]=h0.w;
    hc[4]=h1.x; hc[5]=h1.y; hc[6]=h1.z; hc[7]=h1.w;
    hc[8]=h2.x; hc[9]=h2.y; hc[10]=h2.z; hc[11]=h2.w;
    hc[12]=h3.x; hc[13]=h3.y; hc[14]=h3.z; hc[15]=h3.w;
    float dts = dts_nx;
    if (c + 1 < NC) {
      size_t in2 = ((size_t)(rb * NC + c + 1) * D + d) * DS;
      dts_nx = DTS[(size_t)(rb * NC + c + 1) * D + d];
      h0 = *(const float4*)(HC + in2);
      h1 = *(const float4*)(HC + in2 + 4);
      h2 = *(const float4*)(HC + in2 + 8);
      h3 = *(const float4*)(HC + in2 + 12);
    }
#pragma unroll
    for (int n = 0; n < DS; ++n) hin[n] = h[n];
    if (fast) {
      float pw[DS];
      pow_tree(__expf(-dts), pw);
#pragma unroll
      for (int n = 0; n < DS; ++n)
        h[n] = fmaf(pw[n], h[n], hc[n]);
    } else {
#pragma unroll
      for (int n = 0; n < DS; ++n)
        h[n] = __expf(dts * An[n]) * h[n] + hc[n];
    }
  }
}

// ---------------- scan phase C: LDS-staged inputs, emit y bf16 ----------------
__global__ __launch_bounds__(128) void k_scanC(
    const __bf16* __restrict__ DTbf, const __bf16* __restrict__ XCCbf,
    const float* __restrict__ BCb, const __bf16* __restrict__ Zbf,
    const float* __restrict__ HIN, const float* __restrict__ Alog_l,
    const float* __restrict__ Dp_l, __bf16* __restrict__ YMbf)
{
  __shared__ float Bsm[CT][DS];
  __shared__ float Csm[CT][DS];
  __shared__ __bf16 DTs[CT][128];
  __shared__ __bf16 XCs[CT][128];
  __shared__ __bf16 Zs[CT][128];
  int blk = blockIdx.x;
  int c  = blk % NC;
  int rb = blk / NC;
  int rdir = rb / B;
  int b = rb % B;
  int d = threadIdx.x;
  int s0 = c * CT;
  int cn = min(CT, L - s0);
  size_t rowbase = (size_t)rb * L + s0;
  for (int q = d; q < cn * 2 * DS; q += 128) {
    int ss = q >> 5, j = q & 31;
    float vv = BCb[(rowbase + ss) * 32 + j];
    if (j < DS) Bsm[ss][j] = vv; else Csm[ss][j - DS] = vv;
  }
  for (int q = d; q < cn * 16; q += 128) {
    int row = q >> 4, c8 = (q & 15) * 8;
    *(int4*)&DTs[row][c8] = *(const int4*)(DTbf + (rowbase + row) * D + c8);
    *(int4*)&XCs[row][c8] = *(const int4*)(XCCbf + (rowbase + row) * D + c8);
    *(int4*)&Zs[row][c8]  = *(const int4*)(Zbf + (rowbase + row) * D + c8);
  }
  float An[DS];
  const float* Ab = Alog_l + (size_t)rdir * D * DS + (size_t)d * DS;
#pragma unroll
  for (int n = 0; n < DS; ++n) An[n] = -__expf(Ab[n]);
  bool fast = an_is_linear(An);
  float h[DS];
  const float* hin = HIN + ((size_t)blk * D + d) * DS;
#pragma unroll
  for (int n = 0; n < DS; ++n) h[n] = hin[n];
  float Dpv = Dp_l[rdir * D + d];
  __syncthreads();
  if (fast) {
    for (int ss = 0; ss < cn; ++ss) {
      float dt = (float)DTs[ss][d];
      float xc = (float)XCs[ss][d];
      float z  = (float)Zs[ss][d];
      float e = dt * xc;
      float pw[DS];
      pow_tree(__expf(-dt), pw);
      float y = xc * Dpv;
#pragma unroll
      for (int n = 0; n < DS; ++n) {
        h[n] = fmaf(pw[n], h[n], e * Bsm[ss][n]);
        y = fmaf(h[n], Csm[ss][n], y);
      }
      y *= z * sigmoidf_(z);
      int s = s0 + ss;
      int tt = rdir ? (L - 1 - s) : s;
      YMbf[((size_t)b * L + tt) * 256 + rdir * 128 + d] = (__bf16)y;
    }
  } else {
    for (int ss = 0; ss < cn; ++ss) {
      float dt = (float)DTs[ss][d];
      float xc = (float)XCs[ss][d];
      float z  = (float)Zs[ss][d];
      float e = dt * xc;
      float y = xc * Dpv;
#pragma unroll
      for (int n = 0; n < DS; ++n) {
        h[n] = __expf(dt * An[n]) * h[n] + e * Bsm[ss][n];
        y = fmaf(h[n], Csm[ss][n], y);
      }
      y *= z * sigmoidf_(z);
      int s = s0 + ss;
      int tt = rdir ? (L - 1 - s) : s;
      YMbf[((size_t)b * L + tt) * 256 + rdir * 128 + d] = (__bf16)y;
    }
  }
}

// ---------------- fused tail: outproj + LN1 + FFN1 + FFN2 + LN2 (+ final LN/out on last) ----------------
__global__ __launch_bounds__(256) void k_tail(
    const __bf16* __restrict__ YMbf, const __bf16* __restrict__ Wout,
    const float* __restrict__ g1, const float* __restrict__ be1,
    const __bf16* __restrict__ w1bf, const float* __restrict__ b1,
    const __bf16* __restrict__ w2bf, const float* __restrict__ b2,
    const float* __restrict__ g2, const float* __restrict__ be2,
    float* __restrict__ U, __bf16* __restrict__ Ubf,
    int last, const float* __restrict__ lnfg, const float* __restrict__ lnfb,
    float* __restrict__ outp)
{
  __shared__ short AX[64 * KS];
  __shared__ short BH[128 * KS];
  __shared__ short Ws[64 * KS];
  int m0 = blockIdx.x * 64;
  int tid = threadIdx.x;
  int wave = tid >> 6, lane = tid & 63, lm = lane & 15, lq = lane >> 4;
  f32x4 zero4 = {0.f, 0.f, 0.f, 0.f};

  // ---- phase 1: outproj (K=256) ----
  f32x4 acc[8];
#pragma unroll
  for (int c = 0; c < 8; ++c) acc[c] = zero4;
  for (int kc = 0; kc < 2; ++kc) {
    if (kc) __syncthreads();
    for (int q = tid; q < 64 * 16; q += 256) {
      int rr = q >> 4, g = q & 15;
      int m = m0 + rr;
      int4 v = make_int4(0, 0, 0, 0);
      if (m < BL) v = *(const int4*)(YMbf + (size_t)m * 256 + kc * 128 + g * 8);
      *(int4*)&AX[rr * KS + g * 8] = v;
    }
    for (int q = tid; q < 128 * 16; q += 256) {
      int rr = q >> 4, g = q & 15;
      int4 v = *(const int4*)(Wout + (size_t)rr * 256 + kc * 128 + g * 8);
      *(int4*)&BH[rr * KS + g * 8] = v;
    }
    __syncthreads();
    for (int ks = 0; ks < 128; ks += 32) {
      bf16x8 af = *(const bf16x8*)&AX[(wave * 16 + lm) * KS + ks + lq * 8];
#pragma unroll
      for (int c = 0; c < 8; ++c) {
        bf16x8 bfr = *(const bf16x8*)&BH[(c * 16 + lm) * KS + ks + lq * 8];
        acc[c] = __builtin_amdgcn_mfma_f32_16x16x32_bf16(af, bfr, acc[c], 0, 0, 0);
      }
    }
  }
  __syncthreads();

  // ---- phase 2: residual + LN1 -> XRbf in AX ----
  {
    float g1c[8], be1c[8];
#pragma unroll
    for (int c = 0; c < 8; ++c) {
      int col = c * 16 + lm;
      g1c[c] = g1[col]; be1c[c] = be1[col];
    }
#pragma unroll
    for (int r = 0; r < 4; ++r) {
      int row = m0 + wave * 16 + lq * 4 + r;
      bool valid = row < BL;
      float os[8];
      float sum = 0.f;
#pragma unroll
      for (int c = 0; c < 8; ++c) {
        int col = c * 16 + lm;
        float uv = valid ? U[(size_t)row * 128 + col] : 0.f;
        os[c] = acc[c][r] + uv;
        sum += os[c];
      }
#pragma unroll
      for (int mm = 1; mm < 16; mm <<= 1) sum += __shfl_xor(sum, mm, 64);
      float mean = sum * (1.f / 128.f);
      float qv = 0.f;
#pragma unroll
      for (int c = 0; c < 8; ++c) { float dv = os[c] - mean; qv += dv * dv; }
#pragma unroll
      for (int mm = 1; mm < 16; mm <<= 1) qv += __shfl_xor(qv, mm, 64);
      float inv = rsqrtf(qv * (1.f / 128.f) + 1e-5f);
      int rl = wave * 16 + lq * 4 + r;
#pragma unroll
      for (int c = 0; c < 8; ++c) {
        int col = c * 16 + lm;
        float o = (os[c] - mean) * inv * g1c[c] + be1c[c];
        AX[rl * KS + col] = (short)__builtin_bit_cast(unsigned short, (__bf16)o);
      }
    }
  }

  // ---- phase 3: FFN1 (K=128), H -> BH ----
  for (int cc = 0; cc < 4; ++cc) {
    __syncthreads();
    for (int q = tid; q < 64 * 16; q += 256) {
      int rr = q >> 4, g = q & 15;
      int4 v = *(const int4*)(w1bf + (size_t)(cc * 64 + rr) * 128 + g * 8);
      *(int4*)&Ws[rr * KS + g * 8] = v;
    }
    __syncthreads();
    f32x4 a1[4];
#pragma unroll
    for (int c = 0; c < 4; ++c) a1[c] = zero4;
    for (int ks = 0; ks < 128; ks += 32) {
      bf16x8 af = *(const bf16x8*)&AX[(wave * 16 + lm) * KS + ks + lq * 8];
#pragma unroll
      for (int c = 0; c < 4; ++c) {
        bf16x8 bfr = *(const bf16x8*)&Ws[(c * 16 + lm) * KS + ks + lq * 8];
        a1[c] = __builtin_amdgcn_mfma_f32_16x16x32_bf16(af, bfr, a1[c], 0, 0, 0);
      }
    }
#pragma unroll
    for (int c = 0; c < 4; ++c) {
      int col = cc * 64 + c * 16 + lm;
      float bb = b1[col];
#pragma unroll
      for (int e = 0; e < 4; ++e) {
        int rl = wave * 16 + lq * 4 + e;
        float hv = fmaxf(a1[c][e] + bb, 0.f);
        BH[rl * HS + col] = (short)__builtin_bit_cast(unsigned short, (__bf16)hv);
      }
    }
  }

  // ---- phase 4: FFN2 (K=256) + residual + LN2 (+ lnf/out on last) ----
  f32x4 a2[2][4];
#pragma unroll
  for (int nc = 0; nc < 2; ++nc)
#pragma unroll
    for (int c = 0; c < 4; ++c) a2[nc][c] = zero4;
  for (int nc = 0; nc < 2; ++nc) {
    for (int kc = 0; kc < 2; ++kc) {
      __syncthreads();
      for (int q = tid; q < 64 * 16; q += 256) {
        int rr = q >> 4, g = q & 15;
        int4 v = *(const int4*)(w2bf + (size_t)(nc * 64 + rr) * 256 + kc * 128 + g * 8);
        *(int4*)&Ws[rr * KS + g * 8] = v;
      }
      __syncthreads();
      for (int ks = 0; ks < 128; ks += 32) {
        bf16x8 af = *(const bf16x8*)&BH[(wave * 16 + lm) * HS + kc * 128 + ks + lq * 8];
#pragma unroll
        for (int c = 0; c < 4; ++c) {
          bf16x8 bfr = *(const bf16x8*)&Ws[(c * 16 + lm) * KS + ks + lq * 8];
          a2[nc][c] = __builtin_amdgcn_mfma_f32_16x16x32_bf16(af, bfr, a2[nc][c], 0, 0, 0);
        }
      }
    }
  }
  {
    float b2c[8], g2c[8], be2c[8];
#pragma unroll
    for (int q = 0; q < 8; ++q) {
      int col = (q >> 2) * 64 + (q & 3) * 16 + lm;
      b2c[q] = b2[col]; g2c[q] = g2[col]; be2c[q] = be2[col];
    }
#pragma unroll
    for (int r = 0; r < 4; ++r) {
      int rl = wave * 16 + lq * 4 + r;
      int row = m0 + rl;
      bool valid = row < BL;
      float os[8];
      float sum = 0.f;
#pragma unroll
      for (int q = 0; q < 8; ++q) {
        int nc = q >> 2, c = q & 3;
        int col = nc * 64 + c * 16 + lm;
        __bf16 xb = __builtin_bit_cast(__bf16, (unsigned short)AX[rl * KS + col]);
        os[q] = a2[nc][c][r] + b2c[q] + (float)xb;
        sum += os[q];
      }
#pragma unroll
      for (int mm = 1; mm < 16; mm <<= 1) sum += __shfl_xor(sum, mm, 64);
      float mean = sum * (1.f / 128.f);
      float qv = 0.f;
#pragma unroll
      for (int q = 0; q < 8; ++q) { float dv = os[q] - mean; qv += dv * dv; }
#pragma unroll
      for (int mm = 1; mm < 16; mm <<= 1) qv += __shfl_xor(qv, mm, 64);
      float inv = rsqrtf(qv * (1.f / 128.f) + 1e-5f);
      float o[8];
#pragma unroll
      for (int q = 0; q < 8; ++q)
        o[q] = (os[q] - mean) * inv * g2c[q] + be2c[q];
      if (!last) {
        if (valid) {
#pragma unroll
          for (int q = 0; q < 8; ++q) {
            int col = (q >> 2) * 64 + (q & 3) * 16 + lm;
            U[(size_t)row * 128 + col] = o[q];
            Ubf[(size_t)row * 128 + col] = (__bf16)o[q];
          }
        }
      } else {
        float s2 = 0.f;
#pragma unroll
        for (int q = 0; q < 8; ++q) s2 += o[q];
#pragma unroll
        for (int mm = 1; mm < 16; mm <<= 1) s2 += __shfl_xor(s2, mm, 64);
        float mean2 = s2 * (1.f / 128.f);
        float qv2 = 0.f;
#pragma unroll
        for (int q = 0; q < 8; ++q) { float dv = o[q] - mean2; qv2 += dv * dv; }
#pragma unroll
        for (int mm = 1; mm < 16; mm <<= 1) qv2 += __shfl_xor(qv2, mm, 64);
        float inv2 = rsqrtf(qv2 * (1.f / 128.f) + 1e-5f);
        if (valid) {
          int bb = row / L;
          int t = row - bb * L;
          if (t < N * P) {
            int n = t >> 7, p = t & 127;
            size_t obase = (((size_t)bb * N + n) * D) * P + p;
#pragma unroll
            for (int q = 0; q < 8; ++q) {
              int col = (q >> 2) * 64 + (q & 3) * 16 + lm;
              float o2 = (o[q] - mean2) * inv2 * lnfg[col] + lnfb[col];
              outp[obase + (size_t)col * P] = o2;
            }
          }
        }
      }
    }
  }
}

extern "C" void kernel_launch(void* const* d_in, const int* in_sizes, int n_in,
                              void* d_out, int out_size, void* d_ws, size_t ws_size,
                              hipStream_t stream)
{
  (void)in_sizes; (void)n_in; (void)out_size; (void)ws_size;
  const float* x       = (const float*)d_in[0];
  const float* view    = (const float*)d_in[1];
  const float* wp_w    = (const float*)d_in[2];
  const float* wp_b    = (const float*)d_in[3];
  const float* m_in_w  = (const float*)d_in[4];
  const float* m_conv_w= (const float*)d_in[5];
  const float* m_conv_b= (const float*)d_in[6];
  const float* m_xproj = (const float*)d_in[7];
  const float* m_dt_w  = (const float*)d_in[8];
  const float* m_dt_b  = (const float*)d_in[9];
  const float* m_Alog  = (const float*)d_in[10];
  const float* m_Dp    = (const float*)d_in[11];
  const float* m_out_w = (const float*)d_in[12];
  const float* ffn_w1  = (const float*)d_in[13];
  const float* ffn_b1  = (const float*)d_in[14];
  const float* ffn_w2  = (const float*)d_in[15];
  const float* ffn_b2  = (const float*)d_in[16];
  const float* ln1_g   = (const float*)d_in[17];
  const float* ln1_b   = (const float*)d_in[18];
  const float* ln2_g   = (const float*)d_in[19];
  const float* ln2_b   = (const float*)d_in[20];
  const float* lnf_g   = (const float*)d_in[21];
  const float* lnf_b   = (const float*)d_in[22];
  float* out = (float*)d_out;

  float* W = (float*)d_ws;
  size_t off = 0;
  auto alloc = [&](size_t nfl) { float* p = W + off; off += (nfl + 3) & ~(size_t)3; return p; };
  float* U      = alloc((size_t)BL * D);
  float* Ubf_f  = alloc((size_t)BL * D / 2);
  float* XCC_f  = alloc((size_t)BL * D);          // 2*BL*D bf16
  float* Zbf_f  = alloc((size_t)BL * D);          // 2*BL*D bf16
  float* DT_f   = alloc((size_t)BL * D);          // 2*BL*D bf16
  float* BCb    = alloc((size_t)2 * BL * 2 * DS);
  float* YM_f   = alloc((size_t)BL * 256 / 2);
  float* HC     = alloc((size_t)2 * B * NC * D * DS);
  float* DTS    = alloc((size_t)2 * B * NC * D);
  float* HIN    = alloc((size_t)2 * B * NC * D * DS);
  float* weff_f = alloc(262144 / 2);
  float* xpw_f  = alloc(20480 / 2);
  float* outw_f = alloc(65536 / 2);
  float* w1_f   = alloc(65536 / 2);
  float* w2_f   = alloc(65536 / 2);

  __bf16* Ubf    = (__bf16*)Ubf_f;
  __bf16* XCCbf  = (__bf16*)XCC_f;
  __bf16* Zbf    = (__bf16*)Zbf_f;
  __bf16* DTbf   = (__bf16*)DT_f;
  __bf16* YMbf   = (__bf16*)YM_f;
  __bf16* weff   = (__bf16*)weff_f;
  __bf16* xpw_bf = (__bf16*)xpw_f;
  __bf16* outw_bf= (__bf16*)outw_f;
  __bf16* w1_bf  = (__bf16*)w1_f;
  __bf16* w2_bf  = (__bf16*)w2_f;

  k_prep<<<1872, 256, 0, stream>>>(m_in_w, m_conv_w, m_xproj, m_out_w, ffn_w1, ffn_w2,
                                   weff, xpw_bf, outw_bf, w1_bf, w2_bf);
  k_embed<<<(BL * D + 255) / 256, 256, 0, stream>>>(x, view, wp_w, wp_b, U, Ubf);

  for (int l = 0; l < EL; ++l) {
    const float* conv_b_l = m_conv_b + (size_t)l * 2 * D;
    const float* dt_w_l   = m_dt_w   + (size_t)l * 2 * D * DTR;
    const float* dt_b_l   = m_dt_b   + (size_t)l * 2 * D;
    const float* Alog_l   = m_Alog   + (size_t)l * 2 * D * DS;
    const float* Dp_l     = m_Dp     + (size_t)l * 2 * D;

    k_front <<<dim3(2 * MT128, 2), 256, 0, stream>>>(
        Ubf, weff + (size_t)l * 2 * 256 * 256, conv_b_l,
        xpw_bf + (size_t)l * 2 * 40 * 128, dt_w_l, dt_b_l,
        XCCbf, Zbf, BCb, DTbf);
    k_scanA <<<2 * B * NC, 128, 0, stream>>>(DTbf, XCCbf, BCb, Alog_l, HC, DTS);
    k_scanB <<<2 * B, 128, 0, stream>>>(HC, DTS, Alog_l, HIN);
    k_scanC <<<2 * B * NC, 128, 0, stream>>>(DTbf, XCCbf, BCb, Zbf, HIN, Alog_l, Dp_l, YMbf);
    k_tail  <<<MT64, 256, 0, stream>>>(
        YMbf, outw_bf + (size_t)l * 128 * 256,
        ln1_g + l * D, ln1_b + l * D,
        w1_bf + (size_t)l * 256 * 128, ffn_b1 + l * DFF,
        w2_bf + (size_t)l * 128 * 256, ffn_b2 + l * D,
        ln2_g + l * D, ln2_b + l * D, U, Ubf,
        (l == EL - 1) ? 1 : 0, lnf_g, lnf_b, out);
  }
}

// Round 11
// 399.917 us; speedup vs baseline: 2.5269x; 1.0258x over previous
//
#include <hip/hip_runtime.h>
#include <hip/hip_bf16.h>
#include <math.h>

#define DEV __device__ __forceinline__

constexpr int B  = 8,  N = 16, P = 128, PL = 16;
constexpr int D  = 128, DS = 16, DTR = 8, DFF = 256, EL = 2;
constexpr int L  = N * P + 1;            // 2049
constexpr int BL = B * L;                // 16392
constexpr int CT = 32;                   // scan chunk length
constexpr int NC = (L + CT - 1) / CT;    // 65
constexpr int MT128 = (BL + 127) / 128;  // 129
constexpr int MT64  = (BL + 63) / 64;    // 257
constexpr int KS = 136;                  // LDS row stride (bf16/short units)
constexpr int HS = 264;                  // LDS row stride for H (256+8)

using bf16x8 = __attribute__((ext_vector_type(8))) __bf16;
using f32x4  = __attribute__((ext_vector_type(4))) float;

DEV float sigmoidf_(float x) { return 1.0f / (1.0f + __expf(-x)); }

DEV float wsum(float v) {
#pragma unroll
  for (int m = 32; m; m >>= 1) v += __shfl_xor(v, m, 64);
  return v;
}

// r^(n+1) for n=0..15, depth-4 tree
DEV void pow_tree(float r, float* pw) {
  float r2 = r * r;
  float r3 = r2 * r;
  float r4 = r2 * r2;
  float r8 = r4 * r4;
  float r12 = r8 * r4;
  pw[0] = r;       pw[1] = r2;      pw[2] = r3;      pw[3] = r4;
  pw[4] = r4 * r;  pw[5] = r4 * r2; pw[6] = r4 * r3; pw[7] = r8;
  pw[8] = r8 * r;  pw[9] = r8 * r2; pw[10] = r8 * r3; pw[11] = r12;
  pw[12] = r12 * r; pw[13] = r12 * r2; pw[14] = r12 * r3; pw[15] = r12 * r4;
}

// A_n check: A_init = log(1..16) broadcast -> A_n = -(n+1) exactly.
DEV bool an_is_linear(const float* An) {
  bool ok = true;
#pragma unroll
  for (int n = 0; n < DS; ++n)
    ok = ok && (fabsf(An[n] + (float)(n + 1)) < 1e-3f * (n + 1));
  return ok;
}

// ---------------- weight prep ----------------
__global__ __launch_bounds__(256) void k_prep(
    const float* __restrict__ in_w, const float* __restrict__ conv_w,
    const float* __restrict__ xproj, const float* __restrict__ out_w,
    const float* __restrict__ w1, const float* __restrict__ w2,
    __bf16* __restrict__ weff, __bf16* __restrict__ xpw_bf,
    __bf16* __restrict__ outw_bf, __bf16* __restrict__ w1_bf,
    __bf16* __restrict__ w2_bf)
{
  int g = blockIdx.x * 256 + threadIdx.x;
  if (g < 262144) {
    int l = g >> 17;
    int r = g & 131071;
    int dir = r >> 16;
    int r2 = r & 65535;
    int col = r2 >> 8;
    int kk = r2 & 255;
    int chunk = kk >> 7, k = kk & 127;
    int ld = l * 2 + dir;
    float v;
    if (col < 128) {
      v = in_w[((size_t)ld * 256 + col) * 128 + k] *
          conv_w[((size_t)ld * 128 + col) * 2 + chunk];
    } else {
      v = chunk ? in_w[((size_t)ld * 256 + col) * 128 + k] : 0.f;
    }
    weff[((size_t)ld * 256 + col) * 256 + chunk * 128 + k] = (__bf16)v;
    return;
  }
  g -= 262144;
  if (g < 20480) { xpw_bf[g] = (__bf16)xproj[g]; return; }
  g -= 20480;
  if (g < 65536) {
    int k = g & 127; int q = g >> 7; int n = q & 127; int q2 = q >> 7;
    int dir = q2 & 1; int l = q2 >> 1;
    outw_bf[((size_t)(l * 128 + n)) * 256 + dir * 128 + k] = (__bf16)out_w[g];
    return;
  }
  g -= 65536;
  if (g < 65536) { w1_bf[g] = (__bf16)w1[g]; return; }
  g -= 65536;
  if (g < 65536) { w2_bf[g] = (__bf16)w2[g]; return; }
}

// ---------------- patch embed + view concat -> U (fp32) + Ubf ----------------
__global__ __launch_bounds__(256) void k_embed(
    const float* __restrict__ x, const float* __restrict__ view,
    const float* __restrict__ wp_w, const float* __restrict__ wp_b,
    float* __restrict__ U, __bf16* __restrict__ Ubf)
{
  int g = blockIdx.x * 256 + threadIdx.x;
  if (g >= BL * D) return;
  int d = g & (D - 1);
  int row = g >> 7;
  int b = row / L, t = row % L;
  float acc;
  if (t < N * P) {
    const float* xr = x + ((size_t)b * N * P + t) * PL;
    acc = wp_b[d];
#pragma unroll
    for (int k = 0; k < PL; ++k) acc += xr[k] * wp_w[d * PL + k];
  } else {
    acc = view[b * D + d];
  }
  U[(size_t)row * D + d] = acc;
  Ubf[(size_t)row * D + d] = (__bf16)acc;
}

// ---------------- fused front: xz GEMM + conv + silu + xproj + dt ----------------
// grid (2*MT128, 2): y=0 x-path (128 x-cols, K=256, then xproj+dt inline),
//                    y=1 z-path (128 z-cols, K=128 -> Zbf)
// All bf16 tile outputs routed through LDS -> coalesced int4 stores.
__global__ __launch_bounds__(256) void k_front(
    const __bf16* __restrict__ Ubf, const __bf16* __restrict__ Weff,
    const float* __restrict__ conv_b_l, const __bf16* __restrict__ xpw,
    const float* __restrict__ dt_w_l, const float* __restrict__ dt_b_l,
    __bf16* __restrict__ XCCbf, __bf16* __restrict__ Zbf,
    float* __restrict__ BCb, __bf16* __restrict__ DTbf)
{
  __shared__ short As[128 * KS];   // 34816 B : U staging -> later xc/z bf16 results
  __shared__ short Ws[64 * KS];    // 17408 B : weight staging
  __shared__ float dbs[128][9];    //  4608 B
  int bx = blockIdx.x;
  int rdir = bx / MT128;
  int tile = bx % MT128;
  bool isx = (blockIdx.y == 0);
  int tid = threadIdx.x;
  int m0 = tile * 128;
  const __bf16* Wb = Weff + (size_t)rdir * 256 * 256;
  int wave = tid >> 6, lane = tid & 63, lm = lane & 15, lq = lane >> 4;
  int rr0 = tid >> 4, gcol = tid & 15;

  // per-thread A-row precompute (8 rows, one 16B column-group each)
  int aoff[8];
  unsigned vmask = 0, smask = 0;
  int shif = rdir ? 128 : -128;     // element delta for kc=0 (shifted row)
#pragma unroll
  for (int i = 0; i < 8; ++i) {
    int rr = rr0 + 16 * i;
    int m = m0 + rr;
    aoff[i] = 0;
    if (m < BL) {
      int b = m / L, s = m - b * L;
      int idx1 = rdir ? (L - 1 - s) : s;
      aoff[i] = (b * L + idx1) * 128 + gcol * 8;
      vmask |= 1u << i;
      if (s >= 1) smask |= 1u << i;
    }
  }

  f32x4 zero4 = {0.f, 0.f, 0.f, 0.f};
  f32x4 acc[2][8];
#pragma unroll
  for (int r = 0; r < 2; ++r)
#pragma unroll
    for (int c = 0; c < 8; ++c) acc[r][c] = zero4;

  int kc0 = isx ? 0 : 1;
  int colx = isx ? 0 : 128;
  for (int kc = kc0; kc < 2; ++kc) {
    if (kc != kc0) __syncthreads();
    // stage A
#pragma unroll
    for (int i = 0; i < 8; ++i) {
      int rr = rr0 + 16 * i;
      int4 v = make_int4(0, 0, 0, 0);
      bool ok = (vmask >> i) & 1;
      if (kc == 0) ok = ok && ((smask >> i) & 1);
      if (ok) v = *(const int4*)(Ubf + aoff[i] + (kc == 0 ? shif : 0));
      *(int4*)&As[rr * KS + gcol * 8] = v;
    }
    for (int ch = 0; ch < 2; ++ch) {
      if (ch) __syncthreads();
#pragma unroll
      for (int i = 0; i < 4; ++i) {
        int rr = rr0 + 16 * i;
        int4 v = *(const int4*)(Wb + (size_t)(colx + ch * 64 + rr) * 256 + kc * 128 + gcol * 8);
        *(int4*)&Ws[rr * KS + gcol * 8] = v;
      }
      __syncthreads();
      for (int ks = 0; ks < 128; ks += 32) {
        bf16x8 af[2];
#pragma unroll
        for (int r = 0; r < 2; ++r)
          af[r] = *(const bf16x8*)&As[(wave * 32 + r * 16 + lm) * KS + ks + lq * 8];
#pragma unroll
        for (int c = 0; c < 4; ++c) {
          bf16x8 bfr = *(const bf16x8*)&Ws[(c * 16 + lm) * KS + ks + lq * 8];
#pragma unroll
          for (int r = 0; r < 2; ++r)
            acc[r][ch * 4 + c] = __builtin_amdgcn_mfma_f32_16x16x32_bf16(af[r], bfr, acc[r][ch * 4 + c], 0, 0, 0);
        }
      }
    }
  }
  __syncthreads();   // all MFMA reads of As/Ws done

  if (!isx) {
    // z epilogue: results -> As (wave-private rows) -> coalesced store
#pragma unroll
    for (int r = 0; r < 2; ++r) {
      int rl = wave * 32 + r * 16 + lq * 4;
#pragma unroll
      for (int cg = 0; cg < 8; ++cg) {
        int col = cg * 16 + lm;
#pragma unroll
        for (int e = 0; e < 4; ++e)
          As[(rl + e) * KS + col] = (short)__builtin_bit_cast(unsigned short, (__bf16)acc[r][cg][e]);
      }
    }
    __syncthreads();
#pragma unroll
    for (int i = 0; i < 8; ++i) {
      int rr = rr0 + 16 * i;
      int m = m0 + rr;
      if (m < BL)
        *(int4*)(Zbf + ((size_t)rdir * BL + m) * 128 + gcol * 8) = *(const int4*)&As[rr * KS + gcol * 8];
    }
    return;
  }

  // x epilogue: conv bias + silu -> xc bf16 into As (wave-private rows)
#pragma unroll
  for (int r = 0; r < 2; ++r) {
    int rl = wave * 32 + r * 16 + lq * 4;
#pragma unroll
    for (int cg = 0; cg < 8; ++cg) {
      int col = cg * 16 + lm;
      float cb = conv_b_l[rdir * 128 + col];
#pragma unroll
      for (int e = 0; e < 4; ++e) {
        float v = acc[r][cg][e] + cb;
        float o = v * sigmoidf_(v);
        As[(rl + e) * KS + col] = (short)__builtin_bit_cast(unsigned short, (__bf16)o);
      }
    }
  }
  __syncthreads();
  // coalesced XCC store + xpw staging (no conflicts: As read, Ws write)
#pragma unroll
  for (int i = 0; i < 8; ++i) {
    int rr = rr0 + 16 * i;
    int m = m0 + rr;
    if (m < BL)
      *(int4*)(XCCbf + ((size_t)rdir * BL + m) * 128 + gcol * 8) = *(const int4*)&As[rr * KS + gcol * 8];
  }
#pragma unroll
  for (int i = 0; i < 3; ++i) {
    int rr = rr0 + 16 * i;
    int4 v = make_int4(0, 0, 0, 0);
    if (rr < 40) v = *(const int4*)(xpw + ((size_t)rdir * 40 + rr) * 128 + gcol * 8);
    *(int4*)&Ws[rr * KS + gcol * 8] = v;
  }
  __syncthreads();
  // ---- xproj over LDS-resident xc ----
  f32x4 acc2[2][3];
#pragma unroll
  for (int r = 0; r < 2; ++r)
#pragma unroll
    for (int c = 0; c < 3; ++c) acc2[r][c] = zero4;
  for (int ks = 0; ks < 128; ks += 32) {
    bf16x8 af[2];
#pragma unroll
    for (int r = 0; r < 2; ++r)
      af[r] = *(const bf16x8*)&As[(wave * 32 + r * 16 + lm) * KS + ks + lq * 8];
#pragma unroll
    for (int c = 0; c < 3; ++c) {
      bf16x8 bfr = *(const bf16x8*)&Ws[(c * 16 + lm) * KS + ks + lq * 8];
#pragma unroll
      for (int r = 0; r < 2; ++r)
        acc2[r][c] = __builtin_amdgcn_mfma_f32_16x16x32_bf16(af[r], bfr, acc2[r][c], 0, 0, 0);
    }
  }
#pragma unroll
  for (int r = 0; r < 2; ++r) {
    int rl = wave * 32 + r * 16 + lq * 4;
#pragma unroll
    for (int c = 0; c < 3; ++c) {
      int col = c * 16 + lm;
#pragma unroll
      for (int e = 0; e < 4; ++e) {
        int m = m0 + rl + e;
        float v = acc2[r][c][e];
        if (col < DTR) dbs[rl + e][col] = v;
        else if (col < DTR + 2 * DS && m < BL)
          BCb[((size_t)rdir * BL + m) * 32 + (col - DTR)] = v;
      }
    }
  }
  __syncthreads();
  {
    int dloc = tid & 127;
    int rpar = tid >> 7;
    const float* dw = dt_w_l + ((size_t)rdir * 128 + dloc) * 8;
    float dwr[8];
#pragma unroll
    for (int j = 0; j < 8; ++j) dwr[j] = dw[j];
    float db = dt_b_l[rdir * 128 + dloc];
    for (int rr = rpar; rr < 128; rr += 2) {
      int m = m0 + rr;
      if (m >= BL) break;
      float a = db;
#pragma unroll
      for (int j = 0; j < 8; ++j) a = fmaf(dbs[rr][j], dwr[j], a);
      float dtv = (a > 20.f) ? a : log1pf(__expf(a));
      DTbf[((size_t)rdir * BL + m) * 128 + dloc] = (__bf16)dtv;
    }
  }
}

// ---------------- scan phase A: LDS-staged inputs (bf16 DT) ----------------
__global__ __launch_bounds__(128) void k_scanA(
    const __bf16* __restrict__ DTbf, const __bf16* __restrict__ XCCbf,
    const float* __restrict__ BCb, const float* __restrict__ Alog_l,
    float* __restrict__ HC, float* __restrict__ DTS)
{
  __shared__ float Bs[CT][DS];     // 2 KB
  __shared__ __bf16 DTs[CT][128];  // 8 KB
  __shared__ __bf16 XCs[CT][128];  // 8 KB
  int blk = blockIdx.x;
  int c  = blk % NC;
  int rb = blk / NC;
  int rdir = rb / B;
  int d = threadIdx.x;
  int s0 = c * CT;
  int cn = min(CT, L - s0);
  size_t rowbase = (size_t)rb * L + s0;
  for (int q = d; q < cn * DS; q += 128)
    Bs[q >> 4][q & 15] = BCb[(rowbase + (q >> 4)) * 32 + (q & 15)];
  for (int q = d; q < cn * 16; q += 128) {
    int row = q >> 4, c8 = (q & 15) * 8;
    *(int4*)&DTs[row][c8] = *(const int4*)(DTbf + (rowbase + row) * D + c8);
    *(int4*)&XCs[row][c8] = *(const int4*)(XCCbf + (rowbase + row) * D + c8);
  }
  float An[DS];
  const float* Ab = Alog_l + (size_t)rdir * D * DS + (size_t)d * DS;
#pragma unroll
  for (int n = 0; n < DS; ++n) An[n] = -__expf(Ab[n]);
  bool fast = an_is_linear(An);
  __syncthreads();
  float h[DS];
#pragma unroll
  for (int n = 0; n < DS; ++n) h[n] = 0.f;
  float dts = 0.f;
  if (fast) {
    for (int ss = 0; ss < cn; ++ss) {
      float dt = (float)DTs[ss][d];
      float xc = (float)XCs[ss][d];
      dts += dt;
      float e = dt * xc;
      float pw[DS];
      pow_tree(__expf(-dt), pw);
#pragma unroll
      for (int n = 0; n < DS; ++n)
        h[n] = fmaf(pw[n], h[n], e * Bs[ss][n]);
    }
  } else {
    for (int ss = 0; ss < cn; ++ss) {
      float dt = (float)DTs[ss][d];
      float xc = (float)XCs[ss][d];
      dts += dt;
      float e = dt * xc;
#pragma unroll
      for (int n = 0; n < DS; ++n)
        h[n] = __expf(dt * An[n]) * h[n] + e * Bs[ss][n];
    }
  }
  float* hp = HC + ((size_t)blk * D + d) * DS;
#pragma unroll
  for (int n = 0; n < DS; ++n) hp[n] = h[n];
  DTS[(size_t)blk * D + d] = dts;
}

// ---------------- scan phase B: boundary chain ----------------
__global__ __launch_bounds__(128) void k_scanB(
    const float* __restrict__ HC, const float* __restrict__ DTS,
    const float* __restrict__ Alog_l, float* __restrict__ HIN)
{
  int rb = blockIdx.x;
  int rdir = rb / B;
  int d = threadIdx.x;
  float An[DS];
  const float* Ab = Alog_l + (size_t)rdir * D * DS + (size_t)d * DS;
#pragma unroll
  for (int n = 0; n < DS; ++n) An[n] = -__expf(Ab[n]);
  bool fast = an_is_linear(An);
  float h[DS];
#pragma unroll
  for (int n = 0; n < DS; ++n) h[n] = 0.f;
  size_t i0 = ((size_t)(rb * NC) * D + d) * DS;
  float dts_nx = DTS[(size_t)(rb * NC) * D + d];
  float4 h0 = *(const float4*)(HC + i0);
  float4 h1 = *(const float4*)(HC + i0 + 4);
  float4 h2 = *(const float4*)(HC + i0 + 8);
  float4 h3 = *(const float4*)(HC + i0 + 12);
  for (int c = 0; c < NC; ++c) {
    float* hin = HIN + ((size_t)(rb * NC + c) * D + d) * DS;
    float hc[DS];
    hc[0]=h0.x; hc[1]=h0.y; hc[2]=h0.z; hc[3]=h0.w;
    hc[4]=h1.x; hc[5]=h1.y; hc[6]=h1.z; hc[7]=h1.w;
    hc[8]=h2.x; hc[9]=h2.y; hc[10]=h2.z; hc[11]=h2.w;
    hc[12]=h3.x; hc[13]=h3.y; hc[14]=h3.z; hc[15]=h3.w;
    float dts = dts_nx;
    if (c + 1 < NC) {
      size_t in2 = ((size_t)(rb * NC + c + 1) * D + d) * DS;
      dts_nx = DTS[(size_t)(rb * NC + c + 1) * D + d];
      h0 = *(const float4*)(HC + in2);
      h1 = *(const float4*)(HC + in2 + 4);
      h2 = *(const float4*)(HC + in2 + 8);
      h3 = *(const float4*)(HC + in2 + 12);
    }
#pragma unroll
    for (int n = 0; n < DS; ++n) hin[n] = h[n];
    if (fast) {
      float pw[DS];
      pow_tree(__expf(-dts), pw);
#pragma unroll
      for (int n = 0; n < DS; ++n)
        h[n] = fmaf(pw[n], h[n], hc[n]);
    } else {
#pragma unroll
      for (int n = 0; n < DS; ++n)
        h[n] = __expf(dts * An[n]) * h[n] + hc[n];
    }
  }
}

// ---------------- scan phase C: LDS-staged inputs, emit y bf16 ----------------
__global__ __launch_bounds__(128) void k_scanC(
    const __bf16* __restrict__ DTbf, const __bf16* __restrict__ XCCbf,
    const float* __restrict__ BCb, const __bf16* __restrict__ Zbf,
    const float* __restrict__ HIN, const float* __restrict__ Alog_l,
    const float* __restrict__ Dp_l, __bf16* __restrict__ YMbf)
{
  __shared__ float Bsm[CT][DS];
  __shared__ float Csm[CT][DS];
  __shared__ __bf16 DTs[CT][128];
  __shared__ __bf16 XCs[CT][128];
  __shared__ __bf16 Zs[CT][128];
  int blk = blockIdx.x;
  int c  = blk % NC;
  int rb = blk / NC;
  int rdir = rb / B;
  int b = rb % B;
  int d = threadIdx.x;
  int s0 = c * CT;
  int cn = min(CT, L - s0);
  size_t rowbase = (size_t)rb * L + s0;
  for (int q = d; q < cn * 2 * DS; q += 128) {
    int ss = q >> 5, j = q & 31;
    float vv = BCb[(rowbase + ss) * 32 + j];
    if (j < DS) Bsm[ss][j] = vv; else Csm[ss][j - DS] = vv;
  }
  for (int q = d; q < cn * 16; q += 128) {
    int row = q >> 4, c8 = (q & 15) * 8;
    *(int4*)&DTs[row][c8] = *(const int4*)(DTbf + (rowbase + row) * D + c8);
    *(int4*)&XCs[row][c8] = *(const int4*)(XCCbf + (rowbase + row) * D + c8);
    *(int4*)&Zs[row][c8]  = *(const int4*)(Zbf + (rowbase + row) * D + c8);
  }
  float An[DS];
  const float* Ab = Alog_l + (size_t)rdir * D * DS + (size_t)d * DS;
#pragma unroll
  for (int n = 0; n < DS; ++n) An[n] = -__expf(Ab[n]);
  bool fast = an_is_linear(An);
  float h[DS];
  const float* hin = HIN + ((size_t)blk * D + d) * DS;
#pragma unroll
  for (int n = 0; n < DS; ++n) h[n] = hin[n];
  float Dpv = Dp_l[rdir * D + d];
  __syncthreads();
  if (fast) {
    for (int ss = 0; ss < cn; ++ss) {
      float dt = (float)DTs[ss][d];
      float xc = (float)XCs[ss][d];
      float z  = (float)Zs[ss][d];
      float e = dt * xc;
      float pw[DS];
      pow_tree(__expf(-dt), pw);
      float y = xc * Dpv;
#pragma unroll
      for (int n = 0; n < DS; ++n) {
        h[n] = fmaf(pw[n], h[n], e * Bsm[ss][n]);
        y = fmaf(h[n], Csm[ss][n], y);
      }
      y *= z * sigmoidf_(z);
      int s = s0 + ss;
      int tt = rdir ? (L - 1 - s) : s;
      YMbf[((size_t)b * L + tt) * 256 + rdir * 128 + d] = (__bf16)y;
    }
  } else {
    for (int ss = 0; ss < cn; ++ss) {
      float dt = (float)DTs[ss][d];
      float xc = (float)XCs[ss][d];
      float z  = (float)Zs[ss][d];
      float e = dt * xc;
      float y = xc * Dpv;
#pragma unroll
      for (int n = 0; n < DS; ++n) {
        h[n] = __expf(dt * An[n]) * h[n] + e * Bsm[ss][n];
        y = fmaf(h[n], Csm[ss][n], y);
      }
      y *= z * sigmoidf_(z);
      int s = s0 + ss;
      int tt = rdir ? (L - 1 - s) : s;
      YMbf[((size_t)b * L + tt) * 256 + rdir * 128 + d] = (__bf16)y;
    }
  }
}

// ---------------- fused tail: outproj + LN1 + FFN1 + FFN2 + LN2 (+ final LN/out on last) ----------------
__global__ __launch_bounds__(256) void k_tail(
    const __bf16* __restrict__ YMbf, const __bf16* __restrict__ Wout,
    const float* __restrict__ g1, const float* __restrict__ be1,
    const __bf16* __restrict__ w1bf, const float* __restrict__ b1,
    const __bf16* __restrict__ w2bf, const float* __restrict__ b2,
    const float* __restrict__ g2, const float* __restrict__ be2,
    float* __restrict__ U, __bf16* __restrict__ Ubf,
    int last, const float* __restrict__ lnfg, const float* __restrict__ lnfb,
    float* __restrict__ outp)
{
  __shared__ short AX[64 * KS];
  __shared__ short BH[128 * KS];
  __shared__ short Ws[64 * KS];
  int m0 = blockIdx.x * 64;
  int tid = threadIdx.x;
  int wave = tid >> 6, lane = tid & 63, lm = lane & 15, lq = lane >> 4;
  int rr0 = tid >> 4, gcol = tid & 15;
  f32x4 zero4 = {0.f, 0.f, 0.f, 0.f};

  // ---- phase 1: outproj (K=256) ----
  f32x4 acc[8];
#pragma unroll
  for (int c = 0; c < 8; ++c) acc[c] = zero4;
  for (int kc = 0; kc < 2; ++kc) {
    if (kc) __syncthreads();
    for (int q = tid; q < 64 * 16; q += 256) {
      int rr = q >> 4, g = q & 15;
      int m = m0 + rr;
      int4 v = make_int4(0, 0, 0, 0);
      if (m < BL) v = *(const int4*)(YMbf + (size_t)m * 256 + kc * 128 + g * 8);
      *(int4*)&AX[rr * KS + g * 8] = v;
    }
    for (int q = tid; q < 128 * 16; q += 256) {
      int rr = q >> 4, g = q & 15;
      int4 v = *(const int4*)(Wout + (size_t)rr * 256 + kc * 128 + g * 8);
      *(int4*)&BH[rr * KS + g * 8] = v;
    }
    __syncthreads();
    for (int ks = 0; ks < 128; ks += 32) {
      bf16x8 af = *(const bf16x8*)&AX[(wave * 16 + lm) * KS + ks + lq * 8];
#pragma unroll
      for (int c = 0; c < 8; ++c) {
        bf16x8 bfr = *(const bf16x8*)&BH[(c * 16 + lm) * KS + ks + lq * 8];
        acc[c] = __builtin_amdgcn_mfma_f32_16x16x32_bf16(af, bfr, acc[c], 0, 0, 0);
      }
    }
  }
  __syncthreads();

  // ---- phase 2: residual + LN1 -> XRbf in AX ----
  {
    float g1c[8], be1c[8];
#pragma unroll
    for (int c = 0; c < 8; ++c) {
      int col = c * 16 + lm;
      g1c[c] = g1[col]; be1c[c] = be1[col];
    }
#pragma unroll
    for (int r = 0; r < 4; ++r) {
      int row = m0 + wave * 16 + lq * 4 + r;
      bool valid = row < BL;
      float os[8];
      float sum = 0.f;
#pragma unroll
      for (int c = 0; c < 8; ++c) {
        int col = c * 16 + lm;
        float uv = valid ? U[(size_t)row * 128 + col] : 0.f;
        os[c] = acc[c][r] + uv;
        sum += os[c];
      }
#pragma unroll
      for (int mm = 1; mm < 16; mm <<= 1) sum += __shfl_xor(sum, mm, 64);
      float mean = sum * (1.f / 128.f);
      float qv = 0.f;
#pragma unroll
      for (int c = 0; c < 8; ++c) { float dv = os[c] - mean; qv += dv * dv; }
#pragma unroll
      for (int mm = 1; mm < 16; mm <<= 1) qv += __shfl_xor(qv, mm, 64);
      float inv = rsqrtf(qv * (1.f / 128.f) + 1e-5f);
      int rl = wave * 16 + lq * 4 + r;
#pragma unroll
      for (int c = 0; c < 8; ++c) {
        int col = c * 16 + lm;
        float o = (os[c] - mean) * inv * g1c[c] + be1c[c];
        AX[rl * KS + col] = (short)__builtin_bit_cast(unsigned short, (__bf16)o);
      }
    }
  }

  // ---- phase 3: FFN1 (K=128), H -> BH ----
  for (int cc = 0; cc < 4; ++cc) {
    __syncthreads();
    for (int q = tid; q < 64 * 16; q += 256) {
      int rr = q >> 4, g = q & 15;
      int4 v = *(const int4*)(w1bf + (size_t)(cc * 64 + rr) * 128 + g * 8);
      *(int4*)&Ws[rr * KS + g * 8] = v;
    }
    __syncthreads();
    f32x4 a1[4];
#pragma unroll
    for (int c = 0; c < 4; ++c) a1[c] = zero4;
    for (int ks = 0; ks < 128; ks += 32) {
      bf16x8 af = *(const bf16x8*)&AX[(wave * 16 + lm) * KS + ks + lq * 8];
#pragma unroll
      for (int c = 0; c < 4; ++c) {
        bf16x8 bfr = *(const bf16x8*)&Ws[(c * 16 + lm) * KS + ks + lq * 8];
        a1[c] = __builtin_amdgcn_mfma_f32_16x16x32_bf16(af, bfr, a1[c], 0, 0, 0);
      }
    }
#pragma unroll
    for (int c = 0; c < 4; ++c) {
      int col = cc * 64 + c * 16 + lm;
      float bb = b1[col];
#pragma unroll
      for (int e = 0; e < 4; ++e) {
        int rl = wave * 16 + lq * 4 + e;
        float hv = fmaxf(a1[c][e] + bb, 0.f);
        BH[rl * HS + col] = (short)__builtin_bit_cast(unsigned short, (__bf16)hv);
      }
    }
  }

  // ---- phase 4: FFN2 (K=256) + residual + LN2 (+ lnf/out on last) ----
  f32x4 a2[2][4];
#pragma unroll
  for (int nc = 0; nc < 2; ++nc)
#pragma unroll
    for (int c = 0; c < 4; ++c) a2[nc][c] = zero4;
  for (int nc = 0; nc < 2; ++nc) {
    for (int kc = 0; kc < 2; ++kc) {
      __syncthreads();
      for (int q = tid; q < 64 * 16; q += 256) {
        int rr = q >> 4, g = q & 15;
        int4 v = *(const int4*)(w2bf + (size_t)(nc * 64 + rr) * 256 + kc * 128 + g * 8);
        *(int4*)&Ws[rr * KS + g * 8] = v;
      }
      __syncthreads();
      for (int ks = 0; ks < 128; ks += 32) {
        bf16x8 af = *(const bf16x8*)&BH[(wave * 16 + lm) * HS + kc * 128 + ks + lq * 8];
#pragma unroll
        for (int c = 0; c < 4; ++c) {
          bf16x8 bfr = *(const bf16x8*)&Ws[(c * 16 + lm) * KS + ks + lq * 8];
          a2[nc][c] = __builtin_amdgcn_mfma_f32_16x16x32_bf16(af, bfr, a2[nc][c], 0, 0, 0);
        }
      }
    }
  }
  {
    float b2c[8], g2c[8], be2c[8];
#pragma unroll
    for (int q = 0; q < 8; ++q) {
      int col = (q >> 2) * 64 + (q & 3) * 16 + lm;
      b2c[q] = b2[col]; g2c[q] = g2[col]; be2c[q] = be2[col];
    }
#pragma unroll
    for (int r = 0; r < 4; ++r) {
      int rl = wave * 16 + lq * 4 + r;
      int row = m0 + rl;
      bool valid = row < BL;
      float os[8];
      float sum = 0.f;
#pragma unroll
      for (int q = 0; q < 8; ++q) {
        int nc = q >> 2, c = q & 3;
        int col = nc * 64 + c * 16 + lm;
        __bf16 xb = __builtin_bit_cast(__bf16, (unsigned short)AX[rl * KS + col]);
        os[q] = a2[nc][c][r] + b2c[q] + (float)xb;
        sum += os[q];
      }
#pragma unroll
      for (int mm = 1; mm < 16; mm <<= 1) sum += __shfl_xor(sum, mm, 64);
      float mean = sum * (1.f / 128.f);
      float qv = 0.f;
#pragma unroll
      for (int q = 0; q < 8; ++q) { float dv = os[q] - mean; qv += dv * dv; }
#pragma unroll
      for (int mm = 1; mm < 16; mm <<= 1) qv += __shfl_xor(qv, mm, 64);
      float inv = rsqrtf(qv * (1.f / 128.f) + 1e-5f);
      float o[8];
#pragma unroll
      for (int q = 0; q < 8; ++q)
        o[q] = (os[q] - mean) * inv * g2c[q] + be2c[q];
      if (!last) {
        if (valid) {
#pragma unroll
          for (int q = 0; q < 8; ++q) {
            int col = (q >> 2) * 64 + (q & 3) * 16 + lm;
            U[(size_t)row * 128 + col] = o[q];
          }
        }
        // Ubf routed through AX (same elements this thread just read)
#pragma unroll
        for (int q = 0; q < 8; ++q) {
          int col = (q >> 2) * 64 + (q & 3) * 16 + lm;
          AX[rl * KS + col] = (short)__builtin_bit_cast(unsigned short, (__bf16)o[q]);
        }
      } else {
        float s2 = 0.f;
#pragma unroll
        for (int q = 0; q < 8; ++q) s2 += o[q];
#pragma unroll
        for (int mm = 1; mm < 16; mm <<= 1) s2 += __shfl_xor(s2, mm, 64);
        float mean2 = s2 * (1.f / 128.f);
        float qv2 = 0.f;
#pragma unroll
        for (int q = 0; q < 8; ++q) { float dv = o[q] - mean2; qv2 += dv * dv; }
#pragma unroll
        for (int mm = 1; mm < 16; mm <<= 1) qv2 += __shfl_xor(qv2, mm, 64);
        float inv2 = rsqrtf(qv2 * (1.f / 128.f) + 1e-5f);
        if (valid) {
          int bb = row / L;
          int t = row - bb * L;
          if (t < N * P) {
            int n = t >> 7, p = t & 127;
            size_t obase = (((size_t)bb * N + n) * D) * P + p;
#pragma unroll
            for (int q = 0; q < 8; ++q) {
              int col = (q >> 2) * 64 + (q & 3) * 16 + lm;
              float o2 = (o[q] - mean2) * inv2 * lnfg[col] + lnfb[col];
              outp[obase + (size_t)col * P] = o2;
            }
          }
        }
      }
    }
  }
  if (!last) {
    __syncthreads();
    // coalesced Ubf store from AX
#pragma unroll
    for (int i = 0; i < 4; ++i) {
      int rr = rr0 + 16 * i;
      int m = m0 + rr;
      if (m < BL)
        *(int4*)(Ubf + (size_t)m * 128 + gcol * 8) = *(const int4*)&AX[rr * KS + gcol * 8];
    }
  }
}

extern "C" void kernel_launch(void* const* d_in, const int* in_sizes, int n_in,
                              void* d_out, int out_size, void* d_ws, size_t ws_size,
                              hipStream_t stream)
{
  (void)in_sizes; (void)n_in; (void)out_size; (void)ws_size;
  const float* x       = (const float*)d_in[0];
  const float* view    = (const float*)d_in[1];
  const float* wp_w    = (const float*)d_in[2];
  const float* wp_b    = (const float*)d_in[3];
  const float* m_in_w  = (const float*)d_in[4];
  const float* m_conv_w= (const float*)d_in[5];
  const float* m_conv_b= (const float*)d_in[6];
  const float* m_xproj = (const float*)d_in[7];
  const float* m_dt_w  = (const float*)d_in[8];
  const float* m_dt_b  = (const float*)d_in[9];
  const float* m_Alog  = (const float*)d_in[10];
  const float* m_Dp    = (const float*)d_in[11];
  const float* m_out_w = (const float*)d_in[12];
  const float* ffn_w1  = (const float*)d_in[13];
  const float* ffn_b1  = (const float*)d_in[14];
  const float* ffn_w2  = (const float*)d_in[15];
  const float* ffn_b2  = (const float*)d_in[16];
  const float* ln1_g   = (const float*)d_in[17];
  const float* ln1_b   = (const float*)d_in[18];
  const float* ln2_g   = (const float*)d_in[19];
  const float* ln2_b   = (const float*)d_in[20];
  const float* lnf_g   = (const float*)d_in[21];
  const float* lnf_b   = (const float*)d_in[22];
  float* out = (float*)d_out;

  float* W = (float*)d_ws;
  size_t off = 0;
  auto alloc = [&](size_t nfl) { float* p = W + off; off += (nfl + 3) & ~(size_t)3; return p; };
  float* U      = alloc((size_t)BL * D);
  float* Ubf_f  = alloc((size_t)BL * D / 2);
  float* XCC_f  = alloc((size_t)BL * D);          // 2*BL*D bf16
  float* Zbf_f  = alloc((size_t)BL * D);          // 2*BL*D bf16
  float* DT_f   = alloc((size_t)BL * D);          // 2*BL*D bf16
  float* BCb    = alloc((size_t)2 * BL * 2 * DS);
  float* YM_f   = alloc((size_t)BL * 256 / 2);
  float* HC     = alloc((size_t)2 * B * NC * D * DS);
  float* DTS    = alloc((size_t)2 * B * NC * D);
  float* HIN    = alloc((size_t)2 * B * NC * D * DS);
  float* weff_f = alloc(262144 / 2);
  float* xpw_f  = alloc(20480 / 2);
  float* outw_f = alloc(65536 / 2);
  float* w1_f   = alloc(65536 / 2);
  float* w2_f   = alloc(65536 / 2);

  __bf16* Ubf    = (__bf16*)Ubf_f;
  __bf16* XCCbf  = (__bf16*)XCC_f;
  __bf16* Zbf    = (__bf16*)Zbf_f;
  __bf16* DTbf   = (__bf16*)DT_f;
  __bf16* YMbf   = (__bf16*)YM_f;
  __bf16* weff   = (__bf16*)weff_f;
  __bf16* xpw_bf = (__bf16*)xpw_f;
  __bf16* outw_bf= (__bf16*)outw_f;
  __bf16* w1_bf  = (__bf16*)w1_f;
  __bf16* w2_bf  = (__bf16*)w2_f;

  k_prep<<<1872, 256, 0, stream>>>(m_in_w, m_conv_w, m_xproj, m_out_w, ffn_w1, ffn_w2,
                                   weff, xpw_bf, outw_bf, w1_bf, w2_bf);
  k_embed<<<(BL * D + 255) / 256, 256, 0, stream>>>(x, view, wp_w, wp_b, U, Ubf);

  for (int l = 0; l < EL; ++l) {
    const float* conv_b_l = m_conv_b + (size_t)l * 2 * D;
    const float* dt_w_l   = m_dt_w   + (size_t)l * 2 * D * DTR;
    const float* dt_b_l   = m_dt_b   + (size_t)l * 2 * D;
    const float* Alog_l   = m_Alog   + (size_t)l * 2 * D * DS;
    const float* Dp_l     = m_Dp     + (size_t)l * 2 * D;

    k_front <<<dim3(2 * MT128, 2), 256, 0, stream>>>(
        Ubf, weff + (size_t)l * 2 * 256 * 256, conv_b_l,
        xpw_bf + (size_t)l * 2 * 40 * 128, dt_w_l, dt_b_l,
        XCCbf, Zbf, BCb, DTbf);
    k_scanA <<<2 * B * NC, 128, 0, stream>>>(DTbf, XCCbf, BCb, Alog_l, HC, DTS);
    k_scanB <<<2 * B, 128, 0, stream>>>(HC, DTS, Alog_l, HIN);
    k_scanC <<<2 * B * NC, 128, 0, stream>>>(DTbf, XCCbf, BCb, Zbf, HIN, Alog_l, Dp_l, YMbf);
    k_tail  <<<MT64, 256, 0, stream>>>(
        YMbf, outw_bf + (size_t)l * 128 * 256,
        ln1_g + l * D, ln1_b + l * D,
        w1_bf + (size_t)l * 256 * 128, ffn_b1 + l * DFF,
        w2_bf + (size_t)l * 128 * 256, ffn_b2 + l * D,
        ln2_g + l * D, ln2_b + l * D, U, Ubf,
        (l == EL - 1) ? 1 : 0, lnf_g, lnf_b, out);
  }
}

// Round 12
// 366.395 us; speedup vs baseline: 2.7581x; 1.0915x over previous
//
#include <hip/hip_runtime.h>
#include <hip/hip_bf16.h>
#include <math.h>

#define DEV __device__ __forceinline__

constexpr int B  = 8,  N = 16, P = 128, PL = 16;
constexpr int D  = 128, DS = 16, DTR = 8, DFF = 256, EL = 2;
constexpr int L  = N * P + 1;            // 2049
constexpr int BL = B * L;                // 16392
constexpr int CT = 32;                   // scan chunk length
constexpr int NC = (L + CT - 1) / CT;    // 65
constexpr int MT128 = (BL + 127) / 128;  // 129
constexpr int MT64  = (BL + 63) / 64;    // 257
constexpr int KS = 136;                  // LDS row stride (bf16/short units)
constexpr int HS = 264;                  // LDS row stride for H (256+8)

using bf16x8 = __attribute__((ext_vector_type(8))) __bf16;
using f32x4  = __attribute__((ext_vector_type(4))) float;

DEV float sigmoidf_(float x) { return 1.0f / (1.0f + __expf(-x)); }

DEV float wsum(float v) {
#pragma unroll
  for (int m = 32; m; m >>= 1) v += __shfl_xor(v, m, 64);
  return v;
}

// r^(n+1) for n=0..15, depth-4 tree
DEV void pow_tree(float r, float* pw) {
  float r2 = r * r;
  float r3 = r2 * r;
  float r4 = r2 * r2;
  float r8 = r4 * r4;
  float r12 = r8 * r4;
  pw[0] = r;       pw[1] = r2;      pw[2] = r3;      pw[3] = r4;
  pw[4] = r4 * r;  pw[5] = r4 * r2; pw[6] = r4 * r3; pw[7] = r8;
  pw[8] = r8 * r;  pw[9] = r8 * r2; pw[10] = r8 * r3; pw[11] = r12;
  pw[12] = r12 * r; pw[13] = r12 * r2; pw[14] = r12 * r3; pw[15] = r12 * r4;
}

// A_n check: A_init = log(1..16) broadcast -> A_n = -(n+1) exactly.
DEV bool an_is_linear(const float* An) {
  bool ok = true;
#pragma unroll
  for (int n = 0; n < DS; ++n)
    ok = ok && (fabsf(An[n] + (float)(n + 1)) < 1e-3f * (n + 1));
  return ok;
}

// ---------------- weight prep ----------------
__global__ __launch_bounds__(256) void k_prep(
    const float* __restrict__ in_w, const float* __restrict__ conv_w,
    const float* __restrict__ xproj, const float* __restrict__ out_w,
    const float* __restrict__ w1, const float* __restrict__ w2,
    __bf16* __restrict__ weff, __bf16* __restrict__ xpw_bf,
    __bf16* __restrict__ outw_bf, __bf16* __restrict__ w1_bf,
    __bf16* __restrict__ w2_bf)
{
  int g = blockIdx.x * 256 + threadIdx.x;
  if (g < 262144) {
    int l = g >> 17;
    int r = g & 131071;
    int dir = r >> 16;
    int r2 = r & 65535;
    int col = r2 >> 8;
    int kk = r2 & 255;
    int chunk = kk >> 7, k = kk & 127;
    int ld = l * 2 + dir;
    float v;
    if (col < 128) {
      v = in_w[((size_t)ld * 256 + col) * 128 + k] *
          conv_w[((size_t)ld * 128 + col) * 2 + chunk];
    } else {
      v = chunk ? in_w[((size_t)ld * 256 + col) * 128 + k] : 0.f;
    }
    weff[((size_t)ld * 256 + col) * 256 + chunk * 128 + k] = (__bf16)v;
    return;
  }
  g -= 262144;
  if (g < 20480) { xpw_bf[g] = (__bf16)xproj[g]; return; }
  g -= 20480;
  if (g < 65536) {
    int k = g & 127; int q = g >> 7; int n = q & 127; int q2 = q >> 7;
    int dir = q2 & 1; int l = q2 >> 1;
    outw_bf[((size_t)(l * 128 + n)) * 256 + dir * 128 + k] = (__bf16)out_w[g];
    return;
  }
  g -= 65536;
  if (g < 65536) { w1_bf[g] = (__bf16)w1[g]; return; }
  g -= 65536;
  if (g < 65536) { w2_bf[g] = (__bf16)w2[g]; return; }
}

// ---------------- patch embed + view concat -> U (fp32) + Ubf ----------------
__global__ __launch_bounds__(256) void k_embed(
    const float* __restrict__ x, const float* __restrict__ view,
    const float* __restrict__ wp_w, const float* __restrict__ wp_b,
    float* __restrict__ U, __bf16* __restrict__ Ubf)
{
  int g = blockIdx.x * 256 + threadIdx.x;
  if (g >= BL * D) return;
  int d = g & (D - 1);
  int row = g >> 7;
  int b = row / L, t = row % L;
  float acc;
  if (t < N * P) {
    const float* xr = x + ((size_t)b * N * P + t) * PL;
    acc = wp_b[d];
#pragma unroll
    for (int k = 0; k < PL; ++k) acc += xr[k] * wp_w[d * PL + k];
  } else {
    acc = view[b * D + d];
  }
  U[(size_t)row * D + d] = acc;
  Ubf[(size_t)row * D + d] = (__bf16)acc;
}

// ---------------- fused front: xz GEMM + conv + silu + xproj + dt ----------------
// grid (2*MT64, 2): 64-row tiles for 2x occupancy (~4 blocks/CU).
// y=0 x-path (128 x-cols, K=256, then xproj+dt inline), y=1 z-path (K=128 -> Zbf).
// Direct scatter stores (latency-bound kernel; store RMW inflation is free).
__global__ __launch_bounds__(256) void k_front(
    const __bf16* __restrict__ Ubf, const __bf16* __restrict__ Weff,
    const float* __restrict__ conv_b_l, const __bf16* __restrict__ xpw,
    const float* __restrict__ dt_w_l, const float* __restrict__ dt_b_l,
    __bf16* __restrict__ XCCbf, __bf16* __restrict__ Zbf,
    float* __restrict__ BCb, __bf16* __restrict__ DTbf)
{
  __shared__ short As[64 * KS];    // 17408 B : U staging -> later xc bf16
  __shared__ short Ws[64 * KS];    // 17408 B : weight staging
  __shared__ float dbs[64][9];     //  2304 B
  int bx = blockIdx.x;
  int rdir = bx / MT64;
  int tile = bx % MT64;
  bool isx = (blockIdx.y == 0);
  int tid = threadIdx.x;
  int m0 = tile * 64;
  const __bf16* Wb = Weff + (size_t)rdir * 256 * 256;
  int wave = tid >> 6, lane = tid & 63, lm = lane & 15, lq = lane >> 4;
  int rr0 = tid >> 4, gcol = tid & 15;

  // per-thread A-row precompute (4 rows, one 16B column-group each)
  int aoff[4];
  unsigned vmask = 0, smask = 0;
  int shif = rdir ? 128 : -128;     // element delta for kc=0 (shifted row)
#pragma unroll
  for (int i = 0; i < 4; ++i) {
    int rr = rr0 + 16 * i;
    int m = m0 + rr;
    aoff[i] = 0;
    if (m < BL) {
      int b = m / L, s = m - b * L;
      int idx1 = rdir ? (L - 1 - s) : s;
      aoff[i] = (b * L + idx1) * 128 + gcol * 8;
      vmask |= 1u << i;
      if (s >= 1) smask |= 1u << i;
    }
  }

  f32x4 zero4 = {0.f, 0.f, 0.f, 0.f};
  f32x4 acc[8];
#pragma unroll
  for (int c = 0; c < 8; ++c) acc[c] = zero4;

  int kc0 = isx ? 0 : 1;
  int colx = isx ? 0 : 128;
  for (int kc = kc0; kc < 2; ++kc) {
    if (kc != kc0) __syncthreads();
    // stage A (64 rows)
#pragma unroll
    for (int i = 0; i < 4; ++i) {
      int rr = rr0 + 16 * i;
      int4 v = make_int4(0, 0, 0, 0);
      bool ok = (vmask >> i) & 1;
      if (kc == 0) ok = ok && ((smask >> i) & 1);
      if (ok) v = *(const int4*)(Ubf + aoff[i] + (kc == 0 ? shif : 0));
      *(int4*)&As[rr * KS + gcol * 8] = v;
    }
    for (int ch = 0; ch < 2; ++ch) {
      if (ch) __syncthreads();
#pragma unroll
      for (int i = 0; i < 4; ++i) {
        int rr = rr0 + 16 * i;
        int4 v = *(const int4*)(Wb + (size_t)(colx + ch * 64 + rr) * 256 + kc * 128 + gcol * 8);
        *(int4*)&Ws[rr * KS + gcol * 8] = v;
      }
      __syncthreads();
      for (int ks = 0; ks < 128; ks += 32) {
        bf16x8 af = *(const bf16x8*)&As[(wave * 16 + lm) * KS + ks + lq * 8];
#pragma unroll
        for (int c = 0; c < 4; ++c) {
          bf16x8 bfr = *(const bf16x8*)&Ws[(c * 16 + lm) * KS + ks + lq * 8];
          acc[ch * 4 + c] = __builtin_amdgcn_mfma_f32_16x16x32_bf16(af, bfr, acc[ch * 4 + c], 0, 0, 0);
        }
      }
    }
  }

  if (!isx) {
    // z epilogue: direct scatter stores
#pragma unroll
    for (int cg = 0; cg < 8; ++cg) {
      int col = cg * 16 + lm;
#pragma unroll
      for (int e = 0; e < 4; ++e) {
        int m = m0 + wave * 16 + lq * 4 + e;
        if (m < BL)
          Zbf[((size_t)rdir * BL + m) * 128 + col] = (__bf16)acc[cg][e];
      }
    }
    return;
  }

  // x epilogue: conv bias + silu -> scatter XCC store + xc bf16 into As (wave-private rows)
  __syncthreads();   // all MFMA reads of As/Ws done
#pragma unroll
  for (int cg = 0; cg < 8; ++cg) {
    int col = cg * 16 + lm;
    float cb = conv_b_l[rdir * 128 + col];
#pragma unroll
    for (int e = 0; e < 4; ++e) {
      int rl = wave * 16 + lq * 4 + e;
      int m = m0 + rl;
      float v = acc[cg][e] + cb;
      float o = v * sigmoidf_(v);
      __bf16 ob = (__bf16)o;
      if (m < BL) XCCbf[((size_t)rdir * BL + m) * 128 + col] = ob;
      As[rl * KS + col] = (short)__builtin_bit_cast(unsigned short, ob);
    }
  }
  // stage xpw (Ws safe: barrier above)
#pragma unroll
  for (int i = 0; i < 3; ++i) {
    int rr = rr0 + 16 * i;
    int4 v = make_int4(0, 0, 0, 0);
    if (rr < 40) v = *(const int4*)(xpw + ((size_t)rdir * 40 + rr) * 128 + gcol * 8);
    *(int4*)&Ws[rr * KS + gcol * 8] = v;
  }
  __syncthreads();
  // ---- xproj over LDS-resident xc ----
  f32x4 acc2[3];
#pragma unroll
  for (int c = 0; c < 3; ++c) acc2[c] = zero4;
  for (int ks = 0; ks < 128; ks += 32) {
    bf16x8 af = *(const bf16x8*)&As[(wave * 16 + lm) * KS + ks + lq * 8];
#pragma unroll
    for (int c = 0; c < 3; ++c) {
      bf16x8 bfr = *(const bf16x8*)&Ws[(c * 16 + lm) * KS + ks + lq * 8];
      acc2[c] = __builtin_amdgcn_mfma_f32_16x16x32_bf16(af, bfr, acc2[c], 0, 0, 0);
    }
  }
#pragma unroll
  for (int c = 0; c < 3; ++c) {
    int col = c * 16 + lm;
#pragma unroll
    for (int e = 0; e < 4; ++e) {
      int rl = wave * 16 + lq * 4 + e;
      int m = m0 + rl;
      float v = acc2[c][e];
      if (col < DTR) dbs[rl][col] = v;
      else if (col < DTR + 2 * DS && m < BL)
        BCb[((size_t)rdir * BL + m) * 32 + (col - DTR)] = v;
    }
  }
  __syncthreads();
  {
    int dloc = tid & 127;
    int rpar = tid >> 7;
    const float* dw = dt_w_l + ((size_t)rdir * 128 + dloc) * 8;
    float dwr[8];
#pragma unroll
    for (int j = 0; j < 8; ++j) dwr[j] = dw[j];
    float db = dt_b_l[rdir * 128 + dloc];
    for (int rr = rpar; rr < 64; rr += 2) {
      int m = m0 + rr;
      if (m >= BL) break;
      float a = db;
#pragma unroll
      for (int j = 0; j < 8; ++j) a = fmaf(dbs[rr][j], dwr[j], a);
      float dtv = (a > 20.f) ? a : log1pf(__expf(a));
      DTbf[((size_t)rdir * BL + m) * 128 + dloc] = (__bf16)dtv;
    }
  }
}

// ---------------- scan phase A: LDS-staged inputs (bf16 DT) ----------------
__global__ __launch_bounds__(128) void k_scanA(
    const __bf16* __restrict__ DTbf, const __bf16* __restrict__ XCCbf,
    const float* __restrict__ BCb, const float* __restrict__ Alog_l,
    float* __restrict__ HC, float* __restrict__ DTS)
{
  __shared__ float Bs[CT][DS];     // 2 KB
  __shared__ __bf16 DTs[CT][128];  // 8 KB
  __shared__ __bf16 XCs[CT][128];  // 8 KB
  int blk = blockIdx.x;
  int c  = blk % NC;
  int rb = blk / NC;
  int rdir = rb / B;
  int d = threadIdx.x;
  int s0 = c * CT;
  int cn = min(CT, L - s0);
  size_t rowbase = (size_t)rb * L + s0;
  for (int q = d; q < cn * DS; q += 128)
    Bs[q >> 4][q & 15] = BCb[(rowbase + (q >> 4)) * 32 + (q & 15)];
  for (int q = d; q < cn * 16; q += 128) {
    int row = q >> 4, c8 = (q & 15) * 8;
    *(int4*)&DTs[row][c8] = *(const int4*)(DTbf + (rowbase + row) * D + c8);
    *(int4*)&XCs[row][c8] = *(const int4*)(XCCbf + (rowbase + row) * D + c8);
  }
  float An[DS];
  const float* Ab = Alog_l + (size_t)rdir * D * DS + (size_t)d * DS;
#pragma unroll
  for (int n = 0; n < DS; ++n) An[n] = -__expf(Ab[n]);
  bool fast = an_is_linear(An);
  __syncthreads();
  float h[DS];
#pragma unroll
  for (int n = 0; n < DS; ++n) h[n] = 0.f;
  float dts = 0.f;
  if (fast) {
    for (int ss = 0; ss < cn; ++ss) {
      float dt = (float)DTs[ss][d];
      float xc = (float)XCs[ss][d];
      dts += dt;
      float e = dt * xc;
      float pw[DS];
      pow_tree(__expf(-dt), pw);
#pragma unroll
      for (int n = 0; n < DS; ++n)
        h[n] = fmaf(pw[n], h[n], e * Bs[ss][n]);
    }
  } else {
    for (int ss = 0; ss < cn; ++ss) {
      float dt = (float)DTs[ss][d];
      float xc = (float)XCs[ss][d];
      dts += dt;
      float e = dt * xc;
#pragma unroll
      for (int n = 0; n < DS; ++n)
        h[n] = __expf(dt * An[n]) * h[n] + e * Bs[ss][n];
    }
  }
  float* hp = HC + ((size_t)blk * D + d) * DS;
#pragma unroll
  for (int n = 0; n < DS; ++n) hp[n] = h[n];
  DTS[(size_t)blk * D + d] = dts;
}

// ---------------- scan phase B: boundary chain ----------------
__global__ __launch_bounds__(128) void k_scanB(
    const float* __restrict__ HC, const float* __restrict__ DTS,
    const float* __restrict__ Alog_l, float* __restrict__ HIN)
{
  int rb = blockIdx.x;
  int rdir = rb / B;
  int d = threadIdx.x;
  float An[DS];
  const float* Ab = Alog_l + (size_t)rdir * D * DS + (size_t)d * DS;
#pragma unroll
  for (int n = 0; n < DS; ++n) An[n] = -__expf(Ab[n]);
  bool fast = an_is_linear(An);
  float h[DS];
#pragma unroll
  for (int n = 0; n < DS; ++n) h[n] = 0.f;
  size_t i0 = ((size_t)(rb * NC) * D + d) * DS;
  float dts_nx = DTS[(size_t)(rb * NC) * D + d];
  float4 h0 = *(const float4*)(HC + i0);
  float4 h1 = *(const float4*)(HC + i0 + 4);
  float4 h2 = *(const float4*)(HC + i0 + 8);
  float4 h3 = *(const float4*)(HC + i0 + 12);
  for (int c = 0; c < NC; ++c) {
    float* hin = HIN + ((size_t)(rb * NC + c) * D + d) * DS;
    float hc[DS];
    hc[0]=h0.x; hc[1]=h0.y; hc[2]=h0.z; hc[3]=h0.w;
    hc[4]=h1.x; hc[5]=h1.y; hc[6]=h1.z; hc[7]=h1.w;
    hc[8]=h2.x; hc[9]=h2.y; hc[10]=h2.z; hc[11]=h2.w;
    hc[12]=h3.x; hc[13]=h3.y; hc[14]=h3.z; hc[15]=h3.w;
    float dts = dts_nx;
    if (c + 1 < NC) {
      size_t in2 = ((size_t)(rb * NC + c + 1) * D + d) * DS;
      dts_nx = DTS[(size_t)(rb * NC + c + 1) * D + d];
      h0 = *(const float4*)(HC + in2);
      h1 = *(const float4*)(HC + in2 + 4);
      h2 = *(const float4*)(HC + in2 + 8);
      h3 = *(const float4*)(HC + in2 + 12);
    }
#pragma unroll
    for (int n = 0; n < DS; ++n) hin[n] = h[n];
    if (fast) {
      float pw[DS];
      pow_tree(__expf(-dts), pw);
#pragma unroll
      for (int n = 0; n < DS; ++n)
        h[n] = fmaf(pw[n], h[n], hc[n]);
    } else {
#pragma unroll
      for (int n = 0; n < DS; ++n)
        h[n] = __expf(dts * An[n]) * h[n] + hc[n];
    }
  }
}

// ---------------- scan phase C: LDS-staged inputs, emit y bf16 ----------------
__global__ __launch_bounds__(128) void k_scanC(
    const __bf16* __restrict__ DTbf, const __bf16* __restrict__ XCCbf,
    const float* __restrict__ BCb, const __bf16* __restrict__ Zbf,
    const float* __restrict__ HIN, const float* __restrict__ Alog_l,
    const float* __restrict__ Dp_l, __bf16* __restrict__ YMbf)
{
  __shared__ float Bsm[CT][DS];
  __shared__ float Csm[CT][DS];
  __shared__ __bf16 DTs[CT][128];
  __shared__ __bf16 XCs[CT][128];
  __shared__ __bf16 Zs[CT][128];
  int blk = blockIdx.x;
  int c  = blk % NC;
  int rb = blk / NC;
  int rdir = rb / B;
  int b = rb % B;
  int d = threadIdx.x;
  int s0 = c * CT;
  int cn = min(CT, L - s0);
  size_t rowbase = (size_t)rb * L + s0;
  for (int q = d; q < cn * 2 * DS; q += 128) {
    int ss = q >> 5, j = q & 31;
    float vv = BCb[(rowbase + ss) * 32 + j];
    if (j < DS) Bsm[ss][j] = vv; else Csm[ss][j - DS] = vv;
  }
  for (int q = d; q < cn * 16; q += 128) {
    int row = q >> 4, c8 = (q & 15) * 8;
    *(int4*)&DTs[row][c8] = *(const int4*)(DTbf + (rowbase + row) * D + c8);
    *(int4*)&XCs[row][c8] = *(const int4*)(XCCbf + (rowbase + row) * D + c8);
    *(int4*)&Zs[row][c8]  = *(const int4*)(Zbf + (rowbase + row) * D + c8);
  }
  float An[DS];
  const float* Ab = Alog_l + (size_t)rdir * D * DS + (size_t)d * DS;
#pragma unroll
  for (int n = 0; n < DS; ++n) An[n] = -__expf(Ab[n]);
  bool fast = an_is_linear(An);
  float h[DS];
  const float* hin = HIN + ((size_t)blk * D + d) * DS;
#pragma unroll
  for (int n = 0; n < DS; ++n) h[n] = hin[n];
  float Dpv = Dp_l[rdir * D + d];
  __syncthreads();
  if (fast) {
    for (int ss = 0; ss < cn; ++ss) {
      float dt = (float)DTs[ss][d];
      float xc = (float)XCs[ss][d];
      float z  = (float)Zs[ss][d];
      float e = dt * xc;
      float pw[DS];
      pow_tree(__expf(-dt), pw);
      float y = xc * Dpv;
#pragma unroll
      for (int n = 0; n < DS; ++n) {
        h[n] = fmaf(pw[n], h[n], e * Bsm[ss][n]);
        y = fmaf(h[n], Csm[ss][n], y);
      }
      y *= z * sigmoidf_(z);
      int s = s0 + ss;
      int tt = rdir ? (L - 1 - s) : s;
      YMbf[((size_t)b * L + tt) * 256 + rdir * 128 + d] = (__bf16)y;
    }
  } else {
    for (int ss = 0; ss < cn; ++ss) {
      float dt = (float)DTs[ss][d];
      float xc = (float)XCs[ss][d];
      float z  = (float)Zs[ss][d];
      float e = dt * xc;
      float y = xc * Dpv;
#pragma unroll
      for (int n = 0; n < DS; ++n) {
        h[n] = __expf(dt * An[n]) * h[n] + e * Bsm[ss][n];
        y = fmaf(h[n], Csm[ss][n], y);
      }
      y *= z * sigmoidf_(z);
      int s = s0 + ss;
      int tt = rdir ? (L - 1 - s) : s;
      YMbf[((size_t)b * L + tt) * 256 + rdir * 128 + d] = (__bf16)y;
    }
  }
}

// ---------------- fused tail: outproj + LN1 + FFN1 + FFN2 + LN2 (+ final LN/out on last) ----------------
__global__ __launch_bounds__(256) void k_tail(
    const __bf16* __restrict__ YMbf, const __bf16* __restrict__ Wout,
    const float* __restrict__ g1, const float* __restrict__ be1,
    const __bf16* __restrict__ w1bf, const float* __restrict__ b1,
    const __bf16* __restrict__ w2bf, const float* __restrict__ b2,
    const float* __restrict__ g2, const float* __restrict__ be2,
    float* __restrict__ U, __bf16* __restrict__ Ubf,
    int last, const float* __restrict__ lnfg, const float* __restrict__ lnfb,
    float* __restrict__ outp)
{
  __shared__ short AX[64 * KS];
  __shared__ short BH[128 * KS];
  __shared__ short Ws[64 * KS];
  int m0 = blockIdx.x * 64;
  int tid = threadIdx.x;
  int wave = tid >> 6, lane = tid & 63, lm = lane & 15, lq = lane >> 4;
  int rr0 = tid >> 4, gcol = tid & 15;
  f32x4 zero4 = {0.f, 0.f, 0.f, 0.f};

  // ---- phase 1: outproj (K=256) ----
  f32x4 acc[8];
#pragma unroll
  for (int c = 0; c < 8; ++c) acc[c] = zero4;
  for (int kc = 0; kc < 2; ++kc) {
    if (kc) __syncthreads();
    for (int q = tid; q < 64 * 16; q += 256) {
      int rr = q >> 4, g = q & 15;
      int m = m0 + rr;
      int4 v = make_int4(0, 0, 0, 0);
      if (m < BL) v = *(const int4*)(YMbf + (size_t)m * 256 + kc * 128 + g * 8);
      *(int4*)&AX[rr * KS + g * 8] = v;
    }
    for (int q = tid; q < 128 * 16; q += 256) {
      int rr = q >> 4, g = q & 15;
      int4 v = *(const int4*)(Wout + (size_t)rr * 256 + kc * 128 + g * 8);
      *(int4*)&BH[rr * KS + g * 8] = v;
    }
    __syncthreads();
    for (int ks = 0; ks < 128; ks += 32) {
      bf16x8 af = *(const bf16x8*)&AX[(wave * 16 + lm) * KS + ks + lq * 8];
#pragma unroll
      for (int c = 0; c < 8; ++c) {
        bf16x8 bfr = *(const bf16x8*)&BH[(c * 16 + lm) * KS + ks + lq * 8];
        acc[c] = __builtin_amdgcn_mfma_f32_16x16x32_bf16(af, bfr, acc[c], 0, 0, 0);
      }
    }
  }
  __syncthreads();

  // ---- phase 2: residual + LN1 -> XRbf in AX ----
  {
    float g1c[8], be1c[8];
#pragma unroll
    for (int c = 0; c < 8; ++c) {
      int col = c * 16 + lm;
      g1c[c] = g1[col]; be1c[c] = be1[col];
    }
#pragma unroll
    for (int r = 0; r < 4; ++r) {
      int row = m0 + wave * 16 + lq * 4 + r;
      bool valid = row < BL;
      float os[8];
      float sum = 0.f;
#pragma unroll
      for (int c = 0; c < 8; ++c) {
        int col = c * 16 + lm;
        float uv = valid ? U[(size_t)row * 128 + col] : 0.f;
        os[c] = acc[c][r] + uv;
        sum += os[c];
      }
#pragma unroll
      for (int mm = 1; mm < 16; mm <<= 1) sum += __shfl_xor(sum, mm, 64);
      float mean = sum * (1.f / 128.f);
      float qv = 0.f;
#pragma unroll
      for (int c = 0; c < 8; ++c) { float dv = os[c] - mean; qv += dv * dv; }
#pragma unroll
      for (int mm = 1; mm < 16; mm <<= 1) qv += __shfl_xor(qv, mm, 64);
      float inv = rsqrtf(qv * (1.f / 128.f) + 1e-5f);
      int rl = wave * 16 + lq * 4 + r;
#pragma unroll
      for (int c = 0; c < 8; ++c) {
        int col = c * 16 + lm;
        float o = (os[c] - mean) * inv * g1c[c] + be1c[c];
        AX[rl * KS + col] = (short)__builtin_bit_cast(unsigned short, (__bf16)o);
      }
    }
  }

  // ---- phase 3: FFN1 (K=128), H -> BH ----
  for (int cc = 0; cc < 4; ++cc) {
    __syncthreads();
    for (int q = tid; q < 64 * 16; q += 256) {
      int rr = q >> 4, g = q & 15;
      int4 v = *(const int4*)(w1bf + (size_t)(cc * 64 + rr) * 128 + g * 8);
      *(int4*)&Ws[rr * KS + g * 8] = v;
    }
    __syncthreads();
    f32x4 a1[4];
#pragma unroll
    for (int c = 0; c < 4; ++c) a1[c] = zero4;
    for (int ks = 0; ks < 128; ks += 32) {
      bf16x8 af = *(const bf16x8*)&AX[(wave * 16 + lm) * KS + ks + lq * 8];
#pragma unroll
      for (int c = 0; c < 4; ++c) {
        bf16x8 bfr = *(const bf16x8*)&Ws[(c * 16 + lm) * KS + ks + lq * 8];
        a1[c] = __builtin_amdgcn_mfma_f32_16x16x32_bf16(af, bfr, a1[c], 0, 0, 0);
      }
    }
#pragma unroll
    for (int c = 0; c < 4; ++c) {
      int col = cc * 64 + c * 16 + lm;
      float bb = b1[col];
#pragma unroll
      for (int e = 0; e < 4; ++e) {
        int rl = wave * 16 + lq * 4 + e;
        float hv = fmaxf(a1[c][e] + bb, 0.f);
        BH[rl * HS + col] = (short)__builtin_bit_cast(unsigned short, (__bf16)hv);
      }
    }
  }

  // ---- phase 4: FFN2 (K=256) + residual + LN2 (+ lnf/out on last) ----
  f32x4 a2[2][4];
#pragma unroll
  for (int nc = 0; nc < 2; ++nc)
#pragma unroll
    for (int c = 0; c < 4; ++c) a2[nc][c] = zero4;
  for (int nc = 0; nc < 2; ++nc) {
    for (int kc = 0; kc < 2; ++kc) {
      __syncthreads();
      for (int q = tid; q < 64 * 16; q += 256) {
        int rr = q >> 4, g = q & 15;
        int4 v = *(const int4*)(w2bf + (size_t)(nc * 64 + rr) * 256 + kc * 128 + g * 8);
        *(int4*)&Ws[rr * KS + g * 8] = v;
      }
      __syncthreads();
      for (int ks = 0; ks < 128; ks += 32) {
        bf16x8 af = *(const bf16x8*)&BH[(wave * 16 + lm) * HS + kc * 128 + ks + lq * 8];
#pragma unroll
        for (int c = 0; c < 4; ++c) {
          bf16x8 bfr = *(const bf16x8*)&Ws[(c * 16 + lm) * KS + ks + lq * 8];
          a2[nc][c] = __builtin_amdgcn_mfma_f32_16x16x32_bf16(af, bfr, a2[nc][c], 0, 0, 0);
        }
      }
    }
  }
  {
    float b2c[8], g2c[8], be2c[8];
#pragma unroll
    for (int q = 0; q < 8; ++q) {
      int col = (q >> 2) * 64 + (q & 3) * 16 + lm;
      b2c[q] = b2[col]; g2c[q] = g2[col]; be2c[q] = be2[col];
    }
#pragma unroll
    for (int r = 0; r < 4; ++r) {
      int rl = wave * 16 + lq * 4 + r;
      int row = m0 + rl;
      bool valid = row < BL;
      float os[8];
      float sum = 0.f;
#pragma unroll
      for (int q = 0; q < 8; ++q) {
        int nc = q >> 2, c = q & 3;
        int col = nc * 64 + c * 16 + lm;
        __bf16 xb = __builtin_bit_cast(__bf16, (unsigned short)AX[rl * KS + col]);
        os[q] = a2[nc][c][r] + b2c[q] + (float)xb;
        sum += os[q];
      }
#pragma unroll
      for (int mm = 1; mm < 16; mm <<= 1) sum += __shfl_xor(sum, mm, 64);
      float mean = sum * (1.f / 128.f);
      float qv = 0.f;
#pragma unroll
      for (int q = 0; q < 8; ++q) { float dv = os[q] - mean; qv += dv * dv; }
#pragma unroll
      for (int mm = 1; mm < 16; mm <<= 1) qv += __shfl_xor(qv, mm, 64);
      float inv = rsqrtf(qv * (1.f / 128.f) + 1e-5f);
      float o[8];
#pragma unroll
      for (int q = 0; q < 8; ++q)
        o[q] = (os[q] - mean) * inv * g2c[q] + be2c[q];
      if (!last) {
        if (valid) {
#pragma unroll
          for (int q = 0; q < 8; ++q) {
            int col = (q >> 2) * 64 + (q & 3) * 16 + lm;
            U[(size_t)row * 128 + col] = o[q];
          }
        }
        // Ubf routed through AX (same elements this thread just read)
#pragma unroll
        for (int q = 0; q < 8; ++q) {
          int col = (q >> 2) * 64 + (q & 3) * 16 + lm;
          AX[rl * KS + col] = (short)__builtin_bit_cast(unsigned short, (__bf16)o[q]);
        }
      } else {
        float s2 = 0.f;
#pragma unroll
        for (int q = 0; q < 8; ++q) s2 += o[q];
#pragma unroll
        for (int mm = 1; mm < 16; mm <<= 1) s2 += __shfl_xor(s2, mm, 64);
        float mean2 = s2 * (1.f / 128.f);
        float qv2 = 0.f;
#pragma unroll
        for (int q = 0; q < 8; ++q) { float dv = o[q] - mean2; qv2 += dv * dv; }
#pragma unroll
        for (int mm = 1; mm < 16; mm <<= 1) qv2 += __shfl_xor(qv2, mm, 64);
        float inv2 = rsqrtf(qv2 * (1.f / 128.f) + 1e-5f);
        if (valid) {
          int bb = row / L;
          int t = row - bb * L;
          if (t < N * P) {
            int n = t >> 7, p = t & 127;
            size_t obase = (((size_t)bb * N + n) * D) * P + p;
#pragma unroll
            for (int q = 0; q < 8; ++q) {
              int col = (q >> 2) * 64 + (q & 3) * 16 + lm;
              float o2 = (o[q] - mean2) * inv2 * lnfg[col] + lnfb[col];
              outp[obase + (size_t)col * P] = o2;
            }
          }
        }
      }
    }
  }
  if (!last) {
    __syncthreads();
    // coalesced Ubf store from AX
#pragma unroll
    for (int i = 0; i < 4; ++i) {
      int rr = rr0 + 16 * i;
      int m = m0 + rr;
      if (m < BL)
        *(int4*)(Ubf + (size_t)m * 128 + gcol * 8) = *(const int4*)&AX[rr * KS + gcol * 8];
    }
  }
}

extern "C" void kernel_launch(void* const* d_in, const int* in_sizes, int n_in,
                              void* d_out, int out_size, void* d_ws, size_t ws_size,
                              hipStream_t stream)
{
  (void)in_sizes; (void)n_in; (void)out_size; (void)ws_size;
  const float* x       = (const float*)d_in[0];
  const float* view    = (const float*)d_in[1];
  const float* wp_w    = (const float*)d_in[2];
  const float* wp_b    = (const float*)d_in[3];
  const float* m_in_w  = (const float*)d_in[4];
  const float* m_conv_w= (const float*)d_in[5];
  const float* m_conv_b= (const float*)d_in[6];
  const float* m_xproj = (const float*)d_in[7];
  const float* m_dt_w  = (const float*)d_in[8];
  const float* m_dt_b  = (const float*)d_in[9];
  const float* m_Alog  = (const float*)d_in[10];
  const float* m_Dp    = (const float*)d_in[11];
  const float* m_out_w = (const float*)d_in[12];
  const float* ffn_w1  = (const float*)d_in[13];
  const float* ffn_b1  = (const float*)d_in[14];
  const float* ffn_w2  = (const float*)d_in[15];
  const float* ffn_b2  = (const float*)d_in[16];
  const float* ln1_g   = (const float*)d_in[17];
  const float* ln1_b   = (const float*)d_in[18];
  const float* ln2_g   = (const float*)d_in[19];
  const float* ln2_b   = (const float*)d_in[20];
  const float* lnf_g   = (const float*)d_in[21];
  const float* lnf_b   = (const float*)d_in[22];
  float* out = (float*)d_out;

  float* W = (float*)d_ws;
  size_t off = 0;
  auto alloc = [&](size_t nfl) { float* p = W + off; off += (nfl + 3) & ~(size_t)3; return p; };
  float* U      = alloc((size_t)BL * D);
  float* Ubf_f  = alloc((size_t)BL * D / 2);
  float* XCC_f  = alloc((size_t)BL * D);          // 2*BL*D bf16
  float* Zbf_f  = alloc((size_t)BL * D);          // 2*BL*D bf16
  float* DT_f   = alloc((size_t)BL * D);          // 2*BL*D bf16
  float* BCb    = alloc((size_t)2 * BL * 2 * DS);
  float* YM_f   = alloc((size_t)BL * 256 / 2);
  float* HC     = alloc((size_t)2 * B * NC * D * DS);
  float* DTS    = alloc((size_t)2 * B * NC * D);
  float* HIN    = alloc((size_t)2 * B * NC * D * DS);
  float* weff_f = alloc(262144 / 2);
  float* xpw_f  = alloc(20480 / 2);
  float* outw_f = alloc(65536 / 2);
  float* w1_f   = alloc(65536 / 2);
  float* w2_f   = alloc(65536 / 2);

  __bf16* Ubf    = (__bf16*)Ubf_f;
  __bf16* XCCbf  = (__bf16*)XCC_f;
  __bf16* Zbf    = (__bf16*)Zbf_f;
  __bf16* DTbf   = (__bf16*)DT_f;
  __bf16* YMbf   = (__bf16*)YM_f;
  __bf16* weff   = (__bf16*)weff_f;
  __bf16* xpw_bf = (__bf16*)xpw_f;
  __bf16* outw_bf= (__bf16*)outw_f;
  __bf16* w1_bf  = (__bf16*)w1_f;
  __bf16* w2_bf  = (__bf16*)w2_f;

  k_prep<<<1872, 256, 0, stream>>>(m_in_w, m_conv_w, m_xproj, m_out_w, ffn_w1, ffn_w2,
                                   weff, xpw_bf, outw_bf, w1_bf, w2_bf);
  k_embed<<<(BL * D + 255) / 256, 256, 0, stream>>>(x, view, wp_w, wp_b, U, Ubf);

  for (int l = 0; l < EL; ++l) {
    const float* conv_b_l = m_conv_b + (size_t)l * 2 * D;
    const float* dt_w_l   = m_dt_w   + (size_t)l * 2 * D * DTR;
    const float* dt_b_l   = m_dt_b   + (size_t)l * 2 * D;
    const float* Alog_l   = m_Alog   + (size_t)l * 2 * D * DS;
    const float* Dp_l     = m_Dp     + (size_t)l * 2 * D;

    k_front <<<dim3(2 * MT64, 2), 256, 0, stream>>>(
        Ubf, weff + (size_t)l * 2 * 256 * 256, conv_b_l,
        xpw_bf + (size_t)l * 2 * 40 * 128, dt_w_l, dt_b_l,
        XCCbf, Zbf, BCb, DTbf);
    k_scanA <<<2 * B * NC, 128, 0, stream>>>(DTbf, XCCbf, BCb, Alog_l, HC, DTS);
    k_scanB <<<2 * B, 128, 0, stream>>>(HC, DTS, Alog_l, HIN);
    k_scanC <<<2 * B * NC, 128, 0, stream>>>(DTbf, XCCbf, BCb, Zbf, HIN, Alog_l, Dp_l, YMbf);
    k_tail  <<<MT64, 256, 0, stream>>>(
        YMbf, outw_bf + (size_t)l * 128 * 256,
        ln1_g + l * D, ln1_b + l * D,
        w1_bf + (size_t)l * 256 * 128, ffn_b1 + l * DFF,
        w2_bf + (size_t)l * 128 * 256, ffn_b2 + l * D,
        ln2_g + l * D, ln2_b + l * D, U, Ubf,
        (l == EL - 1) ? 1 : 0, lnf_g, lnf_b, out);
  }
}